// Round 2
// baseline (5306.096 us; speedup 1.0000x reference)
//
#include <hip/hip_runtime.h>
#include <cstdint>
#include <cstddef>

typedef unsigned int uint;
typedef unsigned short ushort;

typedef __bf16 bf16x8 __attribute__((ext_vector_type(8)));
typedef float f32x4 __attribute__((ext_vector_type(4)));

// ---------- bf16 helpers (bit-level) ----------
__device__ __forceinline__ float bflo(uint u) { return __uint_as_float(u << 16); }
__device__ __forceinline__ float bfhi(uint u) { return __uint_as_float(u & 0xffff0000u); }
__device__ __forceinline__ float bf2f(ushort s) { return __uint_as_float(((uint)s) << 16); }
__device__ __forceinline__ ushort f2bf(float f) {
    uint u = __float_as_uint(f);
    u += 0x7fffu + ((u >> 16) & 1u);   // round-to-nearest-even
    return (ushort)(u >> 16);
}
__device__ __forceinline__ uint pk2(float lo, float hi) {
    return (uint)f2bf(lo) | ((uint)f2bf(hi) << 16);
}
__device__ __forceinline__ void unpack8(uint4 v, float* f) {
    f[0] = bflo(v.x); f[1] = bfhi(v.x); f[2] = bflo(v.y); f[3] = bfhi(v.y);
    f[4] = bflo(v.z); f[5] = bfhi(v.z); f[6] = bflo(v.w); f[7] = bfhi(v.w);
}

// ---------- constants ----------
#define LTOT 4096           // b*l tokens
#define DMODEL 2048
#define DINNER 4096
#define DSTATE 128
#define NHEADS 64
#define CONVDIM 6144
#define DPROJ 10304
#define CHUNK 256

// ============================================================
// bf16 MFMA GEMM: Out[M][N] = X[M][K] * W[N][K]^T
// XF32: X is fp32 (converted in staging) else bf16(ushort).
// MODE 0: scatter epilogue -> z(bf16), xBC(bf16), dt(fp32); MODE 1: fp32 out.
// W is always fp32 (converted in staging).
// 128x128 tile, BK=32, 256 threads (4 waves, each 64x64)
// ============================================================
template <int MODE, bool XF32>
__global__ __launch_bounds__(256) void gemm_kernel(
    const void* __restrict__ Xv, const float* __restrict__ W,
    ushort* __restrict__ zbuf, ushort* __restrict__ xbc, float* __restrict__ dtraw,
    float* __restrict__ outF, int M, int N, int K) {
    __shared__ ushort As[128 * 32];
    __shared__ ushort Bs[128 * 32];
    int bn = blockIdx.x, bm = blockIdx.y;
    int tid = threadIdx.x;
    int lane = tid & 63, wv = tid >> 6;
    int wr = wv >> 1, wc = wv & 1;
    int lr = lane & 15, lk = (lane >> 4) * 8;
    f32x4 acc[4][4] = {};
    for (int kk = 0; kk < K; kk += 32) {
        __syncthreads();
        #pragma unroll
        for (int i = 0; i < 2; i++) {
            int id = tid + i * 256;
            int r = id >> 2, c8 = (id & 3) * 8;
            uint4 pa;
            if (XF32) {
                const float* xp = &((const float*)Xv)[(size_t)(bm * 128 + r) * K + kk + c8];
                float4 a0 = *(const float4*)xp, a1 = *(const float4*)(xp + 4);
                pa.x = pk2(a0.x, a0.y); pa.y = pk2(a0.z, a0.w);
                pa.z = pk2(a1.x, a1.y); pa.w = pk2(a1.z, a1.w);
            } else {
                pa = *(const uint4*)&((const ushort*)Xv)[(size_t)(bm * 128 + r) * K + kk + c8];
            }
            *(uint4*)&As[r * 32 + c8] = pa;
            int gr = bn * 128 + r;
            uint4 pb = make_uint4(0u, 0u, 0u, 0u);
            if (gr < N) {
                const float* wp = &W[(size_t)gr * K + kk + c8];
                float4 b0 = *(const float4*)wp, b1 = *(const float4*)(wp + 4);
                pb.x = pk2(b0.x, b0.y); pb.y = pk2(b0.z, b0.w);
                pb.z = pk2(b1.x, b1.y); pb.w = pk2(b1.z, b1.w);
            }
            *(uint4*)&Bs[r * 32 + c8] = pb;
        }
        __syncthreads();
        bf16x8 af[4], bfr[4];
        #pragma unroll
        for (int m = 0; m < 4; m++) af[m] = *(const bf16x8*)&As[(wr * 64 + m * 16 + lr) * 32 + lk];
        #pragma unroll
        for (int n = 0; n < 4; n++) bfr[n] = *(const bf16x8*)&Bs[(wc * 64 + n * 16 + lr) * 32 + lk];
        #pragma unroll
        for (int m = 0; m < 4; m++)
            #pragma unroll
            for (int n = 0; n < 4; n++)
                acc[m][n] = __builtin_amdgcn_mfma_f32_16x16x32_bf16(af[m], bfr[n], acc[m][n], 0, 0, 0);
    }
    int rq = (lane >> 4) * 4;
    #pragma unroll
    for (int m = 0; m < 4; m++) {
        int row0 = bm * 128 + wr * 64 + m * 16 + rq;
        #pragma unroll
        for (int n = 0; n < 4; n++) {
            int col = bn * 128 + wc * 64 + n * 16 + lr;
            #pragma unroll
            for (int r = 0; r < 4; r++) {
                float v = acc[m][n][r];
                int row = row0 + r;
                if (MODE == 1) {
                    if (col < N) outF[(size_t)row * N + col] = v;
                } else {
                    if (col < 4096) {
                        zbuf[(size_t)row * DINNER + col] = f2bf(v);
                    } else if (col < 10240) {
                        xbc[(size_t)row * CONVDIM + (col - 4096)] = f2bf(v);
                    } else if (col < DPROJ) {
                        dtraw[(size_t)row * 64 + (col - 10240)] = v;
                    }
                }
            }
        }
    }
}

// ============================================================
// causal depthwise conv1d (K=4) + SiLU over xBC
// ============================================================
__global__ void conv_kernel(const ushort* __restrict__ xbc, const float* __restrict__ cw,
                            const float* __restrict__ cb, ushort* __restrict__ convout) {
    int c = blockIdx.x * 256 + threadIdx.x;   // channel 0..6143
    int row = blockIdx.y;                     // token 0..4095
    int t = row & 2047;                       // within-batch position
    float4 w = ((const float4*)cw)[c];
    float wk[4] = {w.x, w.y, w.z, w.w};
    float acc = cb[c];
    #pragma unroll
    for (int k = 0; k < 4; k++) {
        int tt = t - 3 + k;
        if (tt >= 0) acc += bf2f(xbc[(size_t)(row - 3 + k) * CONVDIM + c]) * wk[k];
    }
    float s = acc / (1.f + __expf(-acc));     // SiLU
    convout[(size_t)row * CONVDIM + c] = f2bf(s);
}

// ============================================================
// dt = softplus(dtraw + dt_bias)   (in place)
// ============================================================
__global__ void dtsp_kernel(float* __restrict__ dt, const float* __restrict__ dt_bias) {
    int i = blockIdx.x * 256 + threadIdx.x;   // 4096*64
    float x = dt[i] + dt_bias[i & 63];
    dt[i] = (x > 20.f) ? x : log1pf(__expf(x));
}

// ============================================================
// dAcs[(b,c,h)][t] = inclusive cumsum_t ( dtsp * (-exp(A_log[h])) )
// ============================================================
__global__ void cumsum_kernel(const float* __restrict__ dtsp, const float* __restrict__ A_log,
                              float* __restrict__ dAcs) {
    int bi = blockIdx.x;                      // (b*16+c)*64+h
    int h = bi & 63, c = (bi >> 6) & 15, b = bi >> 10;
    int t = threadIdx.x;
    float A = -expf(A_log[h]);
    float v = dtsp[(size_t)(b * 2048 + c * 256 + t) * 64 + h] * A;
    __shared__ float s[256];
    s[t] = v;
    __syncthreads();
    for (int off = 1; off < 256; off <<= 1) {
        float add = (t >= off) ? s[t - off] : 0.f;
        __syncthreads();
        s[t] += add;
        __syncthreads();
    }
    dAcs[(size_t)bi * 256 + t] = s[t];
}

// ============================================================
// per-chunk end states: states[(b,c,h)][p][n] = sum_s xdt[s,p]*ds[s]*B[s,n]
// ============================================================
__global__ __launch_bounds__(256) void states_kernel(
    const ushort* __restrict__ convout, const float* __restrict__ dtsp,
    const float* __restrict__ dAcs, float* __restrict__ states) {
    int bi = blockIdx.x;
    int h = bi & 63, c = (bi >> 6) & 15, b = bi >> 10;
    int tid = threadIdx.x;
    __shared__ float Bsh[64 * 128];
    __shared__ float Wx[64 * 64];
    int rowbase = b * 2048 + c * 256;
    int bcol = 1024 + ((h >> 3) << 7);
    int xcol = ((h >> 3) << 7) + ((h & 1) << 6);
    float dAlast = dAcs[(size_t)bi * 256 + 255];
    float acc[32];
    #pragma unroll
    for (int j = 0; j < 32; j++) acc[j] = 0.f;
    int p = tid >> 2, q = tid & 3;
    for (int T = 0; T < 4; T++) {
        __syncthreads();
        #pragma unroll
        for (int i = 0; i < 4; i++) {            // B tile 64x128
            int id = tid + i * 256; int r = id >> 4; int seg = id & 15;
            uint4 v = *(const uint4*)&convout[(size_t)(rowbase + T * 64 + r) * CONVDIM + bcol + seg * 8];
            float f[8]; unpack8(v, f);
            #pragma unroll
            for (int e = 0; e < 8; e++) Bsh[r * 128 + seg * 8 + e] = f[e];
        }
        #pragma unroll
        for (int i = 0; i < 2; i++) {            // xdt*decay tile 64x64
            int id = tid + i * 256; int r = id >> 3; int seg = id & 7;
            int srow = rowbase + T * 64 + r;
            float sc = dtsp[(size_t)srow * 64 + h] * __expf(dAlast - dAcs[(size_t)bi * 256 + T * 64 + r]);
            uint4 v = *(const uint4*)&convout[(size_t)srow * CONVDIM + xcol + seg * 8];
            float f[8]; unpack8(v, f);
            #pragma unroll
            for (int e = 0; e < 8; e++) Wx[r * 64 + seg * 8 + e] = f[e] * sc;
        }
        __syncthreads();
        for (int r = 0; r < 64; ++r) {
            float wvv = Wx[r * 64 + p];
            #pragma unroll
            for (int j = 0; j < 8; j++) {
                float4 bv = *(const float4*)&Bsh[r * 128 + q * 4 + j * 16];
                acc[j * 4 + 0] += wvv * bv.x; acc[j * 4 + 1] += wvv * bv.y;
                acc[j * 4 + 2] += wvv * bv.z; acc[j * 4 + 3] += wvv * bv.w;
            }
        }
    }
    size_t base = (size_t)bi * 8192 + (size_t)p * 128 + q * 4;
    #pragma unroll
    for (int j = 0; j < 8; j++) {
        float4 o; o.x = acc[j * 4]; o.y = acc[j * 4 + 1]; o.z = acc[j * 4 + 2]; o.w = acc[j * 4 + 3];
        *(float4*)&states[base + j * 16] = o;
    }
}

// ============================================================
// inter-chunk recurrence (in place: states[c] <- state entering chunk c)
// ============================================================
__global__ void recur_kernel(const float* __restrict__ dAcs, float* __restrict__ states) {
    int bh = blockIdx.x;                  // b*64+h
    int h = bh & 63, b = bh >> 6;
    int tid = threadIdx.x;
    float carry[32];
    #pragma unroll
    for (int i = 0; i < 32; i++) carry[i] = 0.f;
    for (int c = 0; c < 16; c++) {
        int bi = (b * 16 + c) * 64 + h;
        float decay = __expf(dAcs[(size_t)bi * 256 + 255]);
        size_t base = (size_t)bi * 8192;
        #pragma unroll
        for (int i = 0; i < 32; i++) {
            size_t idx = base + i * 256 + tid;
            float tmp = states[idx];
            states[idx] = carry[i];
            carry[i] = carry[i] * decay + tmp;
        }
    }
}

// ============================================================
// per-chunk output: Y = Y_off + Y_diag + D*x   (thread owns row l = tid)
// ============================================================
__global__ __launch_bounds__(256) void yscan_kernel(
    const ushort* __restrict__ convout, const float* __restrict__ dtsp,
    const float* __restrict__ dAcs, const float* __restrict__ prev,
    const float* __restrict__ Dvec, ushort* __restrict__ y) {
    int bi = blockIdx.x;
    int h = bi & 63, c = (bi >> 6) & 15, b = bi >> 10;
    int tid = threadIdx.x;
    __shared__ float SB[64 * 128];
    __shared__ float SX[64 * 64];
    __shared__ float SdA[64];
    int rowbase = b * 2048 + c * 256;
    int bcol = 1024 + ((h >> 3) << 7);
    int ccol = 2048 + ((h >> 1) << 7);
    int xcol = ((h >> 3) << 7) + ((h & 1) << 6);
    float dAl = dAcs[(size_t)bi * 256 + tid];
    float acc[64];
    uint cr[64];     // C row of this l, packed bf16 pairs, static-indexed only
    {
        const uint4* crp = (const uint4*)&convout[(size_t)(rowbase + tid) * CONVDIM + ccol];
        #pragma unroll
        for (int i = 0; i < 16; i++) {
            uint4 v = crp[i];
            cr[i * 4] = v.x; cr[i * 4 + 1] = v.y; cr[i * 4 + 2] = v.z; cr[i * 4 + 3] = v.w;
        }
    }
    // ---- Phase A: Y_off = exp(dAl) * sum_n C[l,n] prev[p,n]
    {
        size_t pb = (size_t)bi * 8192;
        #pragma unroll
        for (int i = 0; i < 32; i++) SB[tid + i * 256] = prev[pb + tid + i * 256];
        __syncthreads();
        #pragma unroll
        for (int p = 0; p < 64; p++) acc[p] = 0.f;
        const ushort* crow = &convout[(size_t)(rowbase + tid) * CONVDIM + ccol];
        for (int j = 0; j < 64; ++j) {                 // runtime j: C from global (cached)
            uint u = *(const uint*)&crow[2 * j];
            float c0 = bflo(u), c1 = bfhi(u);
            #pragma unroll
            for (int p = 0; p < 64; p++)
                acc[p] += c0 * SB[p * 128 + 2 * j] + c1 * SB[p * 128 + 2 * j + 1];
        }
        float edAl = __expf(dAl);
        #pragma unroll
        for (int p = 0; p < 64; p++) acc[p] *= edAl;
    }
    // ---- Phase B: Y_diag over 4 s-tiles of 64
    for (int T = 0; T < 4; T++) {
        __syncthreads();
        #pragma unroll
        for (int i = 0; i < 4; i++) {
            int id = tid + i * 256; int r = id >> 4; int seg = id & 15;
            uint4 v = *(const uint4*)&convout[(size_t)(rowbase + T * 64 + r) * CONVDIM + bcol + seg * 8];
            float f[8]; unpack8(v, f);
            #pragma unroll
            for (int e = 0; e < 8; e++) SB[r * 128 + seg * 8 + e] = f[e];
        }
        #pragma unroll
        for (int i = 0; i < 2; i++) {
            int id = tid + i * 256; int r = id >> 3; int seg = id & 7;
            int srow = rowbase + T * 64 + r;
            float dt = dtsp[(size_t)srow * 64 + h];
            uint4 v = *(const uint4*)&convout[(size_t)srow * CONVDIM + xcol + seg * 8];
            float f[8]; unpack8(v, f);
            #pragma unroll
            for (int e = 0; e < 8; e++) SX[r * 64 + seg * 8 + e] = f[e] * dt;
        }
        if (tid < 64) SdA[tid] = dAcs[(size_t)bi * 256 + T * 64 + tid];
        __syncthreads();
        int lim = tid - T * 64;
        if (lim >= 0) {
            int smax = lim < 63 ? lim : 63;
            for (int sl = 0; sl <= smax; ++sl) {
                float g = 0.f;
                #pragma unroll
                for (int j = 0; j < 64; j++) {
                    uint u = cr[j];
                    g += bflo(u) * SB[sl * 128 + 2 * j] + bfhi(u) * SB[sl * 128 + 2 * j + 1];
                }
                float w = g * __expf(dAl - SdA[sl]);
                #pragma unroll
                for (int p = 0; p < 64; p += 4) {
                    float4 xv = *(const float4*)&SX[sl * 64 + p];
                    acc[p] += w * xv.x; acc[p + 1] += w * xv.y;
                    acc[p + 2] += w * xv.z; acc[p + 3] += w * xv.w;
                }
            }
        }
    }
    // ---- Phase C: + D*x, pack & store
    {
        float Dh = Dvec[h];
        const uint4* xp = (const uint4*)&convout[(size_t)(rowbase + tid) * CONVDIM + xcol];
        ushort* yr = &y[(size_t)(rowbase + tid) * DINNER + h * 64];
        #pragma unroll
        for (int i = 0; i < 8; i++) {
            uint4 v = xp[i]; float f[8]; unpack8(v, f);
            float a[8];
            #pragma unroll
            for (int e = 0; e < 8; e++) a[e] = acc[i * 8 + e] + Dh * f[e];
            uint4 ov;
            ov.x = pk2(a[0], a[1]);
            ov.y = pk2(a[2], a[3]);
            ov.z = pk2(a[4], a[5]);
            ov.w = pk2(a[6], a[7]);
            *(uint4*)&yr[i * 8] = ov;
        }
    }
}

// ============================================================
// gated grouped RMSNorm (in place over y): one wave per 128-chan group
// ============================================================
__global__ void norm_kernel(ushort* __restrict__ y, const ushort* __restrict__ zbuf,
                            const float* __restrict__ nw) {
    int row = blockIdx.x;                         // token
    int g = blockIdx.y * 4 + (threadIdx.x >> 6);  // group 0..31
    int lane = threadIdx.x & 63;
    int cbase = g * 128 + lane * 2;
    uint yv = *(const uint*)&y[(size_t)row * DINNER + cbase];
    uint zv = *(const uint*)&zbuf[(size_t)row * DINNER + cbase];
    float y0 = bflo(yv), y1 = bfhi(yv);
    float z0 = bflo(zv), z1 = bfhi(zv);
    float v0 = y0 * (z0 / (1.f + __expf(-z0)));
    float v1 = y1 * (z1 / (1.f + __expf(-z1)));
    float ss = v0 * v0 + v1 * v1;
    #pragma unroll
    for (int off = 32; off; off >>= 1) ss += __shfl_xor(ss, off, 64);
    float rstd = rsqrtf(ss * (1.f / 128.f) + 1e-5f);
    v0 *= rstd * nw[cbase];
    v1 *= rstd * nw[cbase + 1];
    *(uint*)&y[(size_t)row * DINNER + cbase] = pk2(v0, v1);
}

// ============================================================
extern "C" void kernel_launch(void* const* d_in, const int* in_sizes, int n_in,
                              void* d_out, int out_size, void* d_ws, size_t ws_size,
                              hipStream_t stream) {
    const float* u       = (const float*)d_in[0];
    const float* W_in    = (const float*)d_in[1];
    const float* conv_w  = (const float*)d_in[2];
    const float* conv_b  = (const float*)d_in[3];
    const float* dt_bias = (const float*)d_in[4];
    const float* A_log   = (const float*)d_in[5];
    const float* Dvec    = (const float*)d_in[6];
    const float* nw      = (const float*)d_in[7];
    const float* W_out   = (const float*)d_in[8];

    // ---- workspace layout (≈179 MiB total) ----
    char* ws = (char*)d_ws;
    size_t off = 0;
    auto alloc = [&](size_t bytes) { void* p = ws + off; off += (bytes + 255) & ~(size_t)255; return p; };
    ushort* zbuf   = (ushort*)alloc((size_t)LTOT * DINNER * 2);          // 32 MiB, live till norm
    // shared region: xbc (48 MiB, dead after conv) aliased by states (64 MiB)
    void*   shreg  = alloc((size_t)2048 * 8192 * 4);                     // 64 MiB
    ushort* xbc    = (ushort*)shreg;
    float*  states = (float*)shreg;
    float*  dtbuf  = (float*) alloc((size_t)LTOT * 64 * 4);              // 1 MiB
    ushort* convout= (ushort*)alloc((size_t)LTOT * CONVDIM * 2);         // 48 MiB
    float*  dAcs   = (float*) alloc((size_t)2048 * 256 * 4);             // 2 MiB
    ushort* ybuf   = (ushort*)alloc((size_t)LTOT * DINNER * 2);          // 32 MiB (norm in place)

    // in_proj (fp32 X, scatter epilogue)
    gemm_kernel<0, true><<<dim3(81, 32), dim3(256), 0, stream>>>(
        u, W_in, zbuf, xbc, dtbuf, (float*)nullptr, LTOT, DPROJ, DMODEL);
    // conv + silu
    conv_kernel<<<dim3(24, 4096), dim3(256), 0, stream>>>(xbc, conv_w, conv_b, convout);
    // dt softplus (in place), cumsum
    dtsp_kernel<<<dim3(1024), dim3(256), 0, stream>>>(dtbuf, dt_bias);
    cumsum_kernel<<<dim3(2048), dim3(256), 0, stream>>>(dtbuf, A_log, dAcs);
    // chunked scan (states overwrites xbc region — xbc dead after conv)
    states_kernel<<<dim3(2048), dim3(256), 0, stream>>>(convout, dtbuf, dAcs, states);
    recur_kernel<<<dim3(128), dim3(256), 0, stream>>>(dAcs, states);
    yscan_kernel<<<dim3(2048), dim3(256), 0, stream>>>(convout, dtbuf, dAcs, states, Dvec, ybuf);
    // gated group RMSNorm (in place)
    norm_kernel<<<dim3(4096, 8), dim3(256), 0, stream>>>(ybuf, zbuf, nw);
    // out_proj (bf16 X = normalized y)
    gemm_kernel<1, false><<<dim3(16, 32), dim3(256), 0, stream>>>(
        ybuf, W_out, (ushort*)nullptr, (ushort*)nullptr, (float*)nullptr,
        (float*)d_out, LTOT, DMODEL, DINNER);
}

// Round 3
// 1244.784 us; speedup vs baseline: 4.2627x; 4.2627x over previous
//
#include <hip/hip_runtime.h>
#include <cstdint>
#include <cstddef>

typedef unsigned int uint;
typedef unsigned short ushort;

typedef __bf16 bf16x8 __attribute__((ext_vector_type(8)));
typedef float f32x4 __attribute__((ext_vector_type(4)));

// ---------- bf16 helpers (bit-level) ----------
__device__ __forceinline__ float bflo(uint u) { return __uint_as_float(u << 16); }
__device__ __forceinline__ float bfhi(uint u) { return __uint_as_float(u & 0xffff0000u); }
__device__ __forceinline__ float bf2f(ushort s) { return __uint_as_float(((uint)s) << 16); }
__device__ __forceinline__ ushort f2bf(float f) {
    uint u = __float_as_uint(f);
    u += 0x7fffu + ((u >> 16) & 1u);   // round-to-nearest-even
    return (ushort)(u >> 16);
}
__device__ __forceinline__ uint pk2(float lo, float hi) {
    return (uint)f2bf(lo) | ((uint)f2bf(hi) << 16);
}
__device__ __forceinline__ void unpack8(uint4 v, float* f) {
    f[0] = bflo(v.x); f[1] = bfhi(v.x); f[2] = bflo(v.y); f[3] = bfhi(v.y);
    f[4] = bflo(v.z); f[5] = bfhi(v.z); f[6] = bflo(v.w); f[7] = bfhi(v.w);
}

// ---------- constants ----------
#define LTOT 4096           // b*l tokens
#define DMODEL 2048
#define DINNER 4096
#define DSTATE 128
#define NHEADS 64
#define CONVDIM 6144
#define DPROJ 10304
#define CHUNK 256

// ============================================================
// bf16 MFMA GEMM: Out[M][N] = X[M][K] * W[N][K]^T
// XF32: X is fp32 (converted in staging) else bf16(ushort).
// MODE 0: scatter epilogue -> z(bf16), xBC(bf16), dt(fp32); MODE 1: fp32 out.
// W is always fp32 (converted in staging).
// 128x128 tile, BK=32, 256 threads (4 waves, each 64x64)
// ============================================================
template <int MODE, bool XF32>
__global__ __launch_bounds__(256) void gemm_kernel(
    const void* __restrict__ Xv, const float* __restrict__ W,
    ushort* __restrict__ zbuf, ushort* __restrict__ xbc, float* __restrict__ dtraw,
    float* __restrict__ outF, int M, int N, int K) {
    __shared__ ushort As[128 * 32];
    __shared__ ushort Bs[128 * 32];
    int bn = blockIdx.x, bm = blockIdx.y;
    int tid = threadIdx.x;
    int lane = tid & 63, wv = tid >> 6;
    int wr = wv >> 1, wc = wv & 1;
    int lr = lane & 15, lk = (lane >> 4) * 8;
    f32x4 acc[4][4] = {};
    for (int kk = 0; kk < K; kk += 32) {
        __syncthreads();
        #pragma unroll
        for (int i = 0; i < 2; i++) {
            int id = tid + i * 256;
            int r = id >> 2, c8 = (id & 3) * 8;
            uint4 pa;
            if (XF32) {
                const float* xp = &((const float*)Xv)[(size_t)(bm * 128 + r) * K + kk + c8];
                float4 a0 = *(const float4*)xp, a1 = *(const float4*)(xp + 4);
                pa.x = pk2(a0.x, a0.y); pa.y = pk2(a0.z, a0.w);
                pa.z = pk2(a1.x, a1.y); pa.w = pk2(a1.z, a1.w);
            } else {
                pa = *(const uint4*)&((const ushort*)Xv)[(size_t)(bm * 128 + r) * K + kk + c8];
            }
            *(uint4*)&As[r * 32 + c8] = pa;
            int gr = bn * 128 + r;
            uint4 pb = make_uint4(0u, 0u, 0u, 0u);
            if (gr < N) {
                const float* wp = &W[(size_t)gr * K + kk + c8];
                float4 b0 = *(const float4*)wp, b1 = *(const float4*)(wp + 4);
                pb.x = pk2(b0.x, b0.y); pb.y = pk2(b0.z, b0.w);
                pb.z = pk2(b1.x, b1.y); pb.w = pk2(b1.z, b1.w);
            }
            *(uint4*)&Bs[r * 32 + c8] = pb;
        }
        __syncthreads();
        bf16x8 af[4], bfr[4];
        #pragma unroll
        for (int m = 0; m < 4; m++) af[m] = *(const bf16x8*)&As[(wr * 64 + m * 16 + lr) * 32 + lk];
        #pragma unroll
        for (int n = 0; n < 4; n++) bfr[n] = *(const bf16x8*)&Bs[(wc * 64 + n * 16 + lr) * 32 + lk];
        #pragma unroll
        for (int m = 0; m < 4; m++)
            #pragma unroll
            for (int n = 0; n < 4; n++)
                acc[m][n] = __builtin_amdgcn_mfma_f32_16x16x32_bf16(af[m], bfr[n], acc[m][n], 0, 0, 0);
    }
    int rq = (lane >> 4) * 4;
    #pragma unroll
    for (int m = 0; m < 4; m++) {
        int row0 = bm * 128 + wr * 64 + m * 16 + rq;
        #pragma unroll
        for (int n = 0; n < 4; n++) {
            int col = bn * 128 + wc * 64 + n * 16 + lr;
            #pragma unroll
            for (int r = 0; r < 4; r++) {
                float v = acc[m][n][r];
                int row = row0 + r;
                if (MODE == 1) {
                    if (col < N) outF[(size_t)row * N + col] = v;
                } else {
                    if (col < 4096) {
                        zbuf[(size_t)row * DINNER + col] = f2bf(v);
                    } else if (col < 10240) {
                        xbc[(size_t)row * CONVDIM + (col - 4096)] = f2bf(v);
                    } else if (col < DPROJ) {
                        dtraw[(size_t)row * 64 + (col - 10240)] = v;
                    }
                }
            }
        }
    }
}

// ============================================================
// causal depthwise conv1d (K=4) + SiLU over xBC
// ============================================================
__global__ void conv_kernel(const ushort* __restrict__ xbc, const float* __restrict__ cw,
                            const float* __restrict__ cb, ushort* __restrict__ convout) {
    int c = blockIdx.x * 256 + threadIdx.x;   // channel 0..6143
    int row = blockIdx.y;                     // token 0..4095
    int t = row & 2047;                       // within-batch position
    float4 w = ((const float4*)cw)[c];
    float wk[4] = {w.x, w.y, w.z, w.w};
    float acc = cb[c];
    #pragma unroll
    for (int k = 0; k < 4; k++) {
        int tt = t - 3 + k;
        if (tt >= 0) acc += bf2f(xbc[(size_t)(row - 3 + k) * CONVDIM + c]) * wk[k];
    }
    float s = acc / (1.f + __expf(-acc));     // SiLU
    convout[(size_t)row * CONVDIM + c] = f2bf(s);
}

// ============================================================
// dt = softplus(dtraw + dt_bias)   (in place)
// ============================================================
__global__ void dtsp_kernel(float* __restrict__ dt, const float* __restrict__ dt_bias) {
    int i = blockIdx.x * 256 + threadIdx.x;   // 4096*64
    float x = dt[i] + dt_bias[i & 63];
    dt[i] = (x > 20.f) ? x : log1pf(__expf(x));
}

// ============================================================
// dAcs[(b,c,h)][t] = inclusive cumsum_t ( dtsp * (-exp(A_log[h])) )
// ============================================================
__global__ void cumsum_kernel(const float* __restrict__ dtsp, const float* __restrict__ A_log,
                              float* __restrict__ dAcs) {
    int bi = blockIdx.x;                      // (b*16+c)*64+h
    int h = bi & 63, c = (bi >> 6) & 15, b = bi >> 10;
    int t = threadIdx.x;
    float A = -expf(A_log[h]);
    float v = dtsp[(size_t)(b * 2048 + c * 256 + t) * 64 + h] * A;
    __shared__ float s[256];
    s[t] = v;
    __syncthreads();
    for (int off = 1; off < 256; off <<= 1) {
        float add = (t >= off) ? s[t - off] : 0.f;
        __syncthreads();
        s[t] += add;
        __syncthreads();
    }
    dAcs[(size_t)bi * 256 + t] = s[t];
}

// ============================================================
// per-chunk end states: states[(b,c,h)][p][n] = sum_s xdt[s,p]*ds[s]*B[s,n]
// ============================================================
__global__ __launch_bounds__(256) void states_kernel(
    const ushort* __restrict__ convout, const float* __restrict__ dtsp,
    const float* __restrict__ dAcs, float* __restrict__ states) {
    int bi = blockIdx.x;
    int h = bi & 63, c = (bi >> 6) & 15, b = bi >> 10;
    int tid = threadIdx.x;
    __shared__ float Bsh[64 * 128];
    __shared__ float Wx[64 * 64];
    int rowbase = b * 2048 + c * 256;
    int bcol = 1024 + ((h >> 3) << 7);
    int xcol = ((h >> 3) << 7) + ((h & 1) << 6);
    float dAlast = dAcs[(size_t)bi * 256 + 255];
    float acc[32];
    #pragma unroll
    for (int j = 0; j < 32; j++) acc[j] = 0.f;
    int p = tid >> 2, q = tid & 3;
    for (int T = 0; T < 4; T++) {
        __syncthreads();
        #pragma unroll
        for (int i = 0; i < 4; i++) {            // B tile 64x128
            int id = tid + i * 256; int r = id >> 4; int seg = id & 15;
            uint4 v = *(const uint4*)&convout[(size_t)(rowbase + T * 64 + r) * CONVDIM + bcol + seg * 8];
            float f[8]; unpack8(v, f);
            #pragma unroll
            for (int e = 0; e < 8; e++) Bsh[r * 128 + seg * 8 + e] = f[e];
        }
        #pragma unroll
        for (int i = 0; i < 2; i++) {            // xdt*decay tile 64x64
            int id = tid + i * 256; int r = id >> 3; int seg = id & 7;
            int srow = rowbase + T * 64 + r;
            float sc = dtsp[(size_t)srow * 64 + h] * __expf(dAlast - dAcs[(size_t)bi * 256 + T * 64 + r]);
            uint4 v = *(const uint4*)&convout[(size_t)srow * CONVDIM + xcol + seg * 8];
            float f[8]; unpack8(v, f);
            #pragma unroll
            for (int e = 0; e < 8; e++) Wx[r * 64 + seg * 8 + e] = f[e] * sc;
        }
        __syncthreads();
        for (int r = 0; r < 64; ++r) {
            float wvv = Wx[r * 64 + p];
            #pragma unroll
            for (int j = 0; j < 8; j++) {
                float4 bv = *(const float4*)&Bsh[r * 128 + q * 4 + j * 16];
                acc[j * 4 + 0] += wvv * bv.x; acc[j * 4 + 1] += wvv * bv.y;
                acc[j * 4 + 2] += wvv * bv.z; acc[j * 4 + 3] += wvv * bv.w;
            }
        }
    }
    size_t base = (size_t)bi * 8192 + (size_t)p * 128 + q * 4;
    #pragma unroll
    for (int j = 0; j < 8; j++) {
        float4 o; o.x = acc[j * 4]; o.y = acc[j * 4 + 1]; o.z = acc[j * 4 + 2]; o.w = acc[j * 4 + 3];
        *(float4*)&states[base + j * 16] = o;
    }
}

// ============================================================
// inter-chunk recurrence (in place: states[c] <- state entering chunk c)
// ============================================================
__global__ void recur_kernel(const float* __restrict__ dAcs, float* __restrict__ states) {
    int bh = blockIdx.x;                  // b*64+h
    int h = bh & 63, b = bh >> 6;
    int tid = threadIdx.x;
    float carry[32];
    #pragma unroll
    for (int i = 0; i < 32; i++) carry[i] = 0.f;
    for (int c = 0; c < 16; c++) {
        int bi = (b * 16 + c) * 64 + h;
        float decay = __expf(dAcs[(size_t)bi * 256 + 255]);
        size_t base = (size_t)bi * 8192;
        #pragma unroll
        for (int i = 0; i < 32; i++) {
            size_t idx = base + i * 256 + tid;
            float tmp = states[idx];
            states[idx] = carry[i];
            carry[i] = carry[i] * decay + tmp;
        }
    }
}

// ============================================================
// MFMA yscan: per (b,c,h) block, Y = Y_diag + Y_off (D*x added in norm).
// 4 waves, wave w owns l-rows [64w, 64w+64).
//   Y_off = exp(dA_l) * C . prev^T            (MFMA, prev bf16 in LDS)
//   per s-tile (64): S = C . B^T (MFMA, B frags from global)
//     P = S * exp(dA_l - dA_s) (safe 3-factor; masked on diag tile)
//     P -> per-wave LDS strip (bf16) -> A-frags -> Y += P . xdt (MFMA, XT in LDS)
// One __syncthreads total (after staging).
// ============================================================
__global__ __launch_bounds__(256, 2) void yscan_mfma(
    const ushort* __restrict__ convout, const float* __restrict__ dtsp,
    const float* __restrict__ dAcs, const float* __restrict__ states,
    ushort* __restrict__ y) {
    __shared__ ushort XT[64 * 264];   // xdt^T: XT[p][s], stride 264 (528B: 2-way banks, 16B aligned)
    __shared__ ushort PR[64 * 136];   // prev bf16 [p][n], stride 136 (272B)
    __shared__ ushort PV[4 * 16 * 72];// per-wave P strip [16 l][72] (144B stride)
    __shared__ float sdA[256];
    int bi = blockIdx.x;
    int h = bi & 63, cch = (bi >> 6) & 15, b = bi >> 10;
    int tid = threadIdx.x;
    int rowbase = b * 2048 + cch * 256;
    int bcol = 1024 + ((h >> 3) << 7);
    int ccol = 2048 + ((h >> 1) << 7);
    int xcol = ((h >> 3) << 7) + ((h & 1) << 6);

    sdA[tid] = dAcs[(size_t)bi * 256 + tid];
    // stage XT = (x*dt)^T in bf16
    #pragma unroll
    for (int i = 0; i < 4; i++) {
        int s = i * 64 + (tid & 63);
        float dtv = dtsp[(size_t)(rowbase + s) * 64 + h];
        #pragma unroll
        for (int j = 0; j < 2; j++) {
            int p0 = (((tid >> 6) << 1) + j) << 3;
            uint4 v = *(const uint4*)&convout[(size_t)(rowbase + s) * CONVDIM + xcol + p0];
            float f[8]; unpack8(v, f);
            #pragma unroll
            for (int e = 0; e < 8; e++) XT[(p0 + e) * 264 + s] = f2bf(f[e] * dtv);
        }
    }
    // stage prev (bf16)
    {
        const float* pv = &states[(size_t)bi * 8192];
        #pragma unroll
        for (int i = 0; i < 8; i++) {
            int flat = i * 1024 + tid * 4;
            float4 v = *(const float4*)&pv[flat];
            int p = flat >> 7, n = flat & 127;
            *(uint*)&PR[p * 136 + n]     = pk2(v.x, v.y);
            *(uint*)&PR[p * 136 + n + 2] = pk2(v.z, v.w);
        }
    }
    __syncthreads();

    int w = tid >> 6, lane = tid & 63, g = lane >> 4, c = lane & 15;
    int wbase = w * 64;
    const ushort* Crow0 = &convout[(size_t)(rowbase + wbase + c) * CONVDIM + ccol + 8 * g];

    // ---- Y_off = C . prev^T ----
    f32x4 yac[4][4] = {};
    #pragma unroll
    for (int kb = 0; kb < 4; kb++) {
        bf16x8 pb[4];
        #pragma unroll
        for (int np = 0; np < 4; np++)
            pb[np] = *(const bf16x8*)&PR[(16 * np + c) * 136 + kb * 32 + 8 * g];
        #pragma unroll
        for (int m = 0; m < 4; m++) {
            bf16x8 cf = *(const bf16x8*)&Crow0[(size_t)(m * 16) * CONVDIM + kb * 32];
            #pragma unroll
            for (int np = 0; np < 4; np++)
                yac[m][np] = __builtin_amdgcn_mfma_f32_16x16x32_bf16(cf, pb[np], yac[m][np], 0, 0, 0);
        }
    }
    // scale by exp(dA_l) = a_l * exp(Sw)  (both factors <= 1: safe)
    float al[4][4];
    float Sw = sdA[wbase];
    float eSw = __expf(Sw);
    #pragma unroll
    for (int m = 0; m < 4; m++)
        #pragma unroll
        for (int r = 0; r < 4; r++) {
            float dAl = sdA[wbase + m * 16 + 4 * g + r];
            al[m][r] = __expf(dAl - Sw);
            float el = al[m][r] * eSw;
            #pragma unroll
            for (int np = 0; np < 4; np++) yac[m][np][r] *= el;
        }

    // ---- s-tiles ----
    ushort* pvs = &PV[w * 1152];
    for (int T = 0; T <= w; T++) {
        // S = C . B^T
        f32x4 sac[4][4] = {};
        #pragma unroll
        for (int kb = 0; kb < 4; kb++) {
            bf16x8 bb[4];
            #pragma unroll
            for (int np = 0; np < 4; np++)
                bb[np] = *(const bf16x8*)&convout[(size_t)(rowbase + T * 64 + 16 * np + c) * CONVDIM + bcol + kb * 32 + 8 * g];
            #pragma unroll
            for (int m = 0; m < 4; m++) {
                bf16x8 cf = *(const bf16x8*)&Crow0[(size_t)(m * 16) * CONVDIM + kb * 32];
                #pragma unroll
                for (int np = 0; np < 4; np++)
                    sac[m][np] = __builtin_amdgcn_mfma_f32_16x16x32_bf16(cf, bb[np], sac[m][np], 0, 0, 0);
            }
        }
        // xdt B-frags from XT
        bf16x8 xb[4][2];
        #pragma unroll
        for (int np = 0; np < 4; np++)
            #pragma unroll
            for (int k2 = 0; k2 < 2; k2++)
                xb[np][k2] = *(const bf16x8*)&XT[(16 * np + c) * 264 + T * 64 + k2 * 32 + 8 * g];
        if (T < w) {
            // safe 3-factor decay: exp(dA_l-dA_s) = al * exp(ET-dA_s) * exp(Sw-ET)
            float ET = sdA[T * 64 + 63];
            float cT = __expf(Sw - ET);
            float bc[4];
            #pragma unroll
            for (int np = 0; np < 4; np++)
                bc[np] = __expf(ET - sdA[T * 64 + 16 * np + c]) * cT;
            #pragma unroll
            for (int m = 0; m < 4; m++) {
                #pragma unroll
                for (int np = 0; np < 4; np++) {
                    float s0 = bc[np];
                    #pragma unroll
                    for (int r = 0; r < 4; r++)
                        pvs[(4 * g + r) * 72 + 16 * np + c] = f2bf(sac[m][np][r] * (al[m][r] * s0));
                }
                bf16x8 pa0 = *(const bf16x8*)&pvs[c * 72 + 8 * g];
                bf16x8 pa1 = *(const bf16x8*)&pvs[c * 72 + 32 + 8 * g];
                #pragma unroll
                for (int np = 0; np < 4; np++) {
                    yac[m][np] = __builtin_amdgcn_mfma_f32_16x16x32_bf16(pa0, xb[np][0], yac[m][np], 0, 0, 0);
                    yac[m][np] = __builtin_amdgcn_mfma_f32_16x16x32_bf16(pa1, xb[np][1], yac[m][np], 0, 0, 0);
                }
            }
        } else {
            // diagonal tile: direct per-element exp (arg <= 0 where kept), mask s>l
            #pragma unroll
            for (int m = 0; m < 4; m++) {
                float dal[4];
                #pragma unroll
                for (int r = 0; r < 4; r++) dal[r] = sdA[wbase + m * 16 + 4 * g + r];
                #pragma unroll
                for (int np = 0; np < 4; np++) {
                    int s_loc = w * 64 + 16 * np + c;
                    float dAs = sdA[s_loc];
                    #pragma unroll
                    for (int r = 0; r < 4; r++) {
                        int l_loc = wbase + m * 16 + 4 * g + r;
                        float v = (s_loc <= l_loc) ? sac[m][np][r] * __expf(dal[r] - dAs) : 0.f;
                        pvs[(4 * g + r) * 72 + 16 * np + c] = f2bf(v);
                    }
                }
                bf16x8 pa0 = *(const bf16x8*)&pvs[c * 72 + 8 * g];
                bf16x8 pa1 = *(const bf16x8*)&pvs[c * 72 + 32 + 8 * g];
                #pragma unroll
                for (int np = 0; np < 4; np++) {
                    yac[m][np] = __builtin_amdgcn_mfma_f32_16x16x32_bf16(pa0, xb[np][0], yac[m][np], 0, 0, 0);
                    yac[m][np] = __builtin_amdgcn_mfma_f32_16x16x32_bf16(pa1, xb[np][1], yac[m][np], 0, 0, 0);
                }
            }
        }
    }
    // ---- store (C-layout scatter, bf16) ----
    #pragma unroll
    for (int m = 0; m < 4; m++)
        #pragma unroll
        for (int np = 0; np < 4; np++)
            #pragma unroll
            for (int r = 0; r < 4; r++) {
                int l = wbase + m * 16 + 4 * g + r;
                y[(size_t)(rowbase + l) * DINNER + h * 64 + 16 * np + c] = f2bf(yac[m][np][r]);
            }
}

// ============================================================
// gated grouped RMSNorm (in place over y), now also adds D*x first.
// ============================================================
__global__ void norm_kernel(ushort* __restrict__ y, const ushort* __restrict__ zbuf,
                            const ushort* __restrict__ convout, const float* __restrict__ Dvec,
                            const float* __restrict__ nw) {
    int row = blockIdx.x;                         // token
    int g = blockIdx.y * 4 + (threadIdx.x >> 6);  // group 0..31
    int lane = threadIdx.x & 63;
    int cbase = g * 128 + lane * 2;
    int h = cbase >> 6;                           // head (uniform per lane pair)
    int p = cbase & 63;
    int xc = ((h >> 3) << 7) + ((h & 1) << 6) + p;
    uint yv = *(const uint*)&y[(size_t)row * DINNER + cbase];
    uint zv = *(const uint*)&zbuf[(size_t)row * DINNER + cbase];
    uint xv = *(const uint*)&convout[(size_t)row * CONVDIM + xc];
    float Dh = Dvec[h];
    float y0 = bflo(yv) + Dh * bflo(xv), y1 = bfhi(yv) + Dh * bfhi(xv);
    float z0 = bflo(zv), z1 = bfhi(zv);
    float v0 = y0 * (z0 / (1.f + __expf(-z0)));
    float v1 = y1 * (z1 / (1.f + __expf(-z1)));
    float ss = v0 * v0 + v1 * v1;
    #pragma unroll
    for (int off = 32; off; off >>= 1) ss += __shfl_xor(ss, off, 64);
    float rstd = rsqrtf(ss * (1.f / 128.f) + 1e-5f);
    v0 *= rstd * nw[cbase];
    v1 *= rstd * nw[cbase + 1];
    *(uint*)&y[(size_t)row * DINNER + cbase] = pk2(v0, v1);
}

// ============================================================
extern "C" void kernel_launch(void* const* d_in, const int* in_sizes, int n_in,
                              void* d_out, int out_size, void* d_ws, size_t ws_size,
                              hipStream_t stream) {
    const float* u       = (const float*)d_in[0];
    const float* W_in    = (const float*)d_in[1];
    const float* conv_w  = (const float*)d_in[2];
    const float* conv_b  = (const float*)d_in[3];
    const float* dt_bias = (const float*)d_in[4];
    const float* A_log   = (const float*)d_in[5];
    const float* Dvec    = (const float*)d_in[6];
    const float* nw      = (const float*)d_in[7];
    const float* W_out   = (const float*)d_in[8];

    // ---- workspace layout (≈179 MiB total) ----
    char* ws = (char*)d_ws;
    size_t off = 0;
    auto alloc = [&](size_t bytes) { void* p = ws + off; off += (bytes + 255) & ~(size_t)255; return p; };
    ushort* zbuf   = (ushort*)alloc((size_t)LTOT * DINNER * 2);          // 32 MiB, live till norm
    // shared region: xbc (48 MiB, dead after conv) aliased by states (64 MiB)
    void*   shreg  = alloc((size_t)2048 * 8192 * 4);                     // 64 MiB
    ushort* xbc    = (ushort*)shreg;
    float*  states = (float*)shreg;
    float*  dtbuf  = (float*) alloc((size_t)LTOT * 64 * 4);              // 1 MiB
    ushort* convout= (ushort*)alloc((size_t)LTOT * CONVDIM * 2);         // 48 MiB
    float*  dAcs   = (float*) alloc((size_t)2048 * 256 * 4);             // 2 MiB
    ushort* ybuf   = (ushort*)alloc((size_t)LTOT * DINNER * 2);          // 32 MiB (norm in place)

    // in_proj (fp32 X, scatter epilogue)
    gemm_kernel<0, true><<<dim3(81, 32), dim3(256), 0, stream>>>(
        u, W_in, zbuf, xbc, dtbuf, (float*)nullptr, LTOT, DPROJ, DMODEL);
    // conv + silu
    conv_kernel<<<dim3(24, 4096), dim3(256), 0, stream>>>(xbc, conv_w, conv_b, convout);
    // dt softplus (in place), cumsum
    dtsp_kernel<<<dim3(1024), dim3(256), 0, stream>>>(dtbuf, dt_bias);
    cumsum_kernel<<<dim3(2048), dim3(256), 0, stream>>>(dtbuf, A_log, dAcs);
    // chunked scan (states overwrites xbc region — xbc dead after conv)
    states_kernel<<<dim3(2048), dim3(256), 0, stream>>>(convout, dtbuf, dAcs, states);
    recur_kernel<<<dim3(128), dim3(256), 0, stream>>>(dAcs, states);
    yscan_mfma<<<dim3(2048), dim3(256), 0, stream>>>(convout, dtbuf, dAcs, states, ybuf);
    // gated group RMSNorm (in place, adds D*x)
    norm_kernel<<<dim3(4096, 8), dim3(256), 0, stream>>>(ybuf, zbuf, convout, Dvec, nw);
    // out_proj (bf16 X = normalized y)
    gemm_kernel<1, false><<<dim3(16, 32), dim3(256), 0, stream>>>(
        ybuf, W_out, (ushort*)nullptr, (ushort*)nullptr, (float*)nullptr,
        (float*)d_out, LTOT, DMODEL, DINNER);
}

// Round 4
// 825.238 us; speedup vs baseline: 6.4298x; 1.5084x over previous
//
#include <hip/hip_runtime.h>
#include <cstdint>
#include <cstddef>

typedef unsigned int uint;
typedef unsigned short ushort;

typedef __bf16 bf16x8 __attribute__((ext_vector_type(8)));
typedef float f32x4 __attribute__((ext_vector_type(4)));

// ---------- bf16 helpers (bit-level) ----------
__device__ __forceinline__ float bflo(uint u) { return __uint_as_float(u << 16); }
__device__ __forceinline__ float bfhi(uint u) { return __uint_as_float(u & 0xffff0000u); }
__device__ __forceinline__ float bf2f(ushort s) { return __uint_as_float(((uint)s) << 16); }
__device__ __forceinline__ ushort f2bf(float f) {
    uint u = __float_as_uint(f);
    u += 0x7fffu + ((u >> 16) & 1u);   // round-to-nearest-even
    return (ushort)(u >> 16);
}
__device__ __forceinline__ uint pk2(float lo, float hi) {
    return (uint)f2bf(lo) | ((uint)f2bf(hi) << 16);
}
__device__ __forceinline__ void unpack8(uint4 v, float* f) {
    f[0] = bflo(v.x); f[1] = bfhi(v.x); f[2] = bflo(v.y); f[3] = bfhi(v.y);
    f[4] = bflo(v.z); f[5] = bfhi(v.z); f[6] = bflo(v.w); f[7] = bfhi(v.w);
}

// async global->LDS, 16B per lane, wave-uniform LDS base (linear dest)
typedef __attribute__((address_space(1))) const unsigned int* as1_cuptr;
typedef __attribute__((address_space(3))) unsigned int* as3_uptr;
__device__ __forceinline__ void gload_lds16(const void* g, void* l) {
    __builtin_amdgcn_global_load_lds((as1_cuptr)g, (as3_uptr)l, 16, 0, 0);
}

// ---------- constants ----------
#define LTOT 4096           // b*l tokens
#define DMODEL 2048
#define DINNER 4096
#define DSTATE 128
#define NHEADS 64
#define CONVDIM 6144
#define DPROJ 10304
#define CHUNK 256

// ============================================================
// fp32 -> bf16 conversion (vectorized)
// ============================================================
__global__ void cvt_kernel(const float* __restrict__ in, ushort* __restrict__ out, int n4) {
    int i = blockIdx.x * 256 + threadIdx.x;
    if (i < n4) {
        float4 v = ((const float4*)in)[i];
        ushort4 o;
        o.x = f2bf(v.x); o.y = f2bf(v.y); o.z = f2bf(v.z); o.w = f2bf(v.w);
        ((ushort4*)out)[i] = o;
    }
}

// ============================================================
// pure-bf16 MFMA GEMM (m97 structure): Out[M][N] = X[M][K] * W[N][K]^T
// global_load_lds width-16 staging, 128x128 tile, BK=32, 4 waves.
// 1D grid with bijective XCD swizzle (requires gridDim.x % 8 == 0).
// MODE 0: scatter epilogue -> z(bf16), xBC(bf16), dt(fp32); MODE 1: fp32 out.
// ============================================================
template <int MODE>
__global__ __launch_bounds__(256) void gemm_bf16(
    const ushort* __restrict__ X, const ushort* __restrict__ W,
    ushort* __restrict__ zbuf, ushort* __restrict__ xbc, float* __restrict__ dtraw,
    float* __restrict__ outF, int M, int N, int K, int NB) {
    __shared__ ushort As[128 * 32];
    __shared__ ushort Bs[128 * 32];
    int q = gridDim.x >> 3;
    int wg = blockIdx.x;
    int swz = (wg & 7) * q + (wg >> 3);
    int bn = swz % NB, bm = swz / NB;
    int tid = threadIdx.x;
    int lane = tid & 63, w = tid >> 6;
    int wr = w >> 1, wc = w & 1;
    int lr = lane & 15, lk = (lane >> 4) * 8;
    // staging geometry: seg = w*2+j covers rows seg*16..seg*16+15 of the tile
    int r0 = lane >> 2;          // 0..15
    int ce = (lane & 3) * 8;     // k-elem 0,8,16,24
    const ushort* gA0 = &X[(size_t)(bm * 128 + (w * 2 + 0) * 16 + r0) * K + ce];
    const ushort* gA1 = &X[(size_t)(bm * 128 + (w * 2 + 1) * 16 + r0) * K + ce];
    const ushort* gB0 = &W[(size_t)(bn * 128 + (w * 2 + 0) * 16 + r0) * K + ce];
    const ushort* gB1 = &W[(size_t)(bn * 128 + (w * 2 + 1) * 16 + r0) * K + ce];
    ushort* lA0 = &As[(w * 2 + 0) * 512];   // wave-uniform bases
    ushort* lA1 = &As[(w * 2 + 1) * 512];
    ushort* lB0 = &Bs[(w * 2 + 0) * 512];
    ushort* lB1 = &Bs[(w * 2 + 1) * 512];
    f32x4 acc[4][4] = {};
    for (int kk = 0; kk < K; kk += 32) {
        __syncthreads();                       // previous iter's LDS reads done
        gload_lds16(gA0, lA0); gload_lds16(gA1, lA1);
        gload_lds16(gB0, lB0); gload_lds16(gB1, lB1);
        gA0 += 32; gA1 += 32; gB0 += 32; gB1 += 32;
        __syncthreads();                       // drains vmcnt before barrier
        bf16x8 af[4], bfr[4];
        #pragma unroll
        for (int m = 0; m < 4; m++) af[m] = *(const bf16x8*)&As[(wr * 64 + m * 16 + lr) * 32 + lk];
        #pragma unroll
        for (int n = 0; n < 4; n++) bfr[n] = *(const bf16x8*)&Bs[(wc * 64 + n * 16 + lr) * 32 + lk];
        #pragma unroll
        for (int m = 0; m < 4; m++)
            #pragma unroll
            for (int n = 0; n < 4; n++)
                acc[m][n] = __builtin_amdgcn_mfma_f32_16x16x32_bf16(af[m], bfr[n], acc[m][n], 0, 0, 0);
    }
    int rq = (lane >> 4) * 4;
    #pragma unroll
    for (int m = 0; m < 4; m++) {
        int row0 = bm * 128 + wr * 64 + m * 16 + rq;
        #pragma unroll
        for (int n = 0; n < 4; n++) {
            int col = bn * 128 + wc * 64 + n * 16 + lr;
            #pragma unroll
            for (int r = 0; r < 4; r++) {
                float v = acc[m][n][r];
                int row = row0 + r;
                if (MODE == 1) {
                    outF[(size_t)row * N + col] = v;
                } else {
                    if (col < 4096) {
                        zbuf[(size_t)row * DINNER + col] = f2bf(v);
                    } else if (col < 10240) {
                        xbc[(size_t)row * CONVDIM + (col - 4096)] = f2bf(v);
                    } else if (col < DPROJ) {
                        dtraw[(size_t)row * 64 + (col - 10240)] = v;
                    }
                }
            }
        }
    }
}

// ============================================================
// causal depthwise conv1d (K=4) + SiLU over xBC
// ============================================================
__global__ void conv_kernel(const ushort* __restrict__ xbc, const float* __restrict__ cw,
                            const float* __restrict__ cb, ushort* __restrict__ convout) {
    int c = blockIdx.x * 256 + threadIdx.x;   // channel 0..6143
    int row = blockIdx.y;                     // token 0..4095
    int t = row & 2047;                       // within-batch position
    float4 w = ((const float4*)cw)[c];
    float wk[4] = {w.x, w.y, w.z, w.w};
    float acc = cb[c];
    #pragma unroll
    for (int k = 0; k < 4; k++) {
        int tt = t - 3 + k;
        if (tt >= 0) acc += bf2f(xbc[(size_t)(row - 3 + k) * CONVDIM + c]) * wk[k];
    }
    float s = acc / (1.f + __expf(-acc));     // SiLU
    convout[(size_t)row * CONVDIM + c] = f2bf(s);
}

// ============================================================
// dt = softplus(dtraw + dt_bias)   (in place)
// ============================================================
__global__ void dtsp_kernel(float* __restrict__ dt, const float* __restrict__ dt_bias) {
    int i = blockIdx.x * 256 + threadIdx.x;   // 4096*64
    float x = dt[i] + dt_bias[i & 63];
    dt[i] = (x > 20.f) ? x : log1pf(__expf(x));
}

// ============================================================
// dAcs[(b,c,h)][t] = inclusive cumsum_t ( dtsp * (-exp(A_log[h])) )
// ============================================================
__global__ void cumsum_kernel(const float* __restrict__ dtsp, const float* __restrict__ A_log,
                              float* __restrict__ dAcs) {
    int bi = blockIdx.x;                      // (b*16+c)*64+h
    int h = bi & 63, c = (bi >> 6) & 15, b = bi >> 10;
    int t = threadIdx.x;
    float A = -expf(A_log[h]);
    float v = dtsp[(size_t)(b * 2048 + c * 256 + t) * 64 + h] * A;
    __shared__ float s[256];
    s[t] = v;
    __syncthreads();
    for (int off = 1; off < 256; off <<= 1) {
        float add = (t >= off) ? s[t - off] : 0.f;
        __syncthreads();
        s[t] += add;
        __syncthreads();
    }
    dAcs[(size_t)bi * 256 + t] = s[t];
}

// ============================================================
// per-chunk end states: states[(b,c,h)][p][n] = sum_s xdt[s,p]*ds[s]*B[s,n]
// ============================================================
__global__ __launch_bounds__(256) void states_kernel(
    const ushort* __restrict__ convout, const float* __restrict__ dtsp,
    const float* __restrict__ dAcs, float* __restrict__ states) {
    int bi = blockIdx.x;
    int h = bi & 63, c = (bi >> 6) & 15, b = bi >> 10;
    int tid = threadIdx.x;
    __shared__ float Bsh[64 * 128];
    __shared__ float Wx[64 * 64];
    int rowbase = b * 2048 + c * 256;
    int bcol = 1024 + ((h >> 3) << 7);
    int xcol = ((h >> 3) << 7) + ((h & 1) << 6);
    float dAlast = dAcs[(size_t)bi * 256 + 255];
    float acc[32];
    #pragma unroll
    for (int j = 0; j < 32; j++) acc[j] = 0.f;
    int p = tid >> 2, q = tid & 3;
    for (int T = 0; T < 4; T++) {
        __syncthreads();
        #pragma unroll
        for (int i = 0; i < 4; i++) {            // B tile 64x128
            int id = tid + i * 256; int r = id >> 4; int seg = id & 15;
            uint4 v = *(const uint4*)&convout[(size_t)(rowbase + T * 64 + r) * CONVDIM + bcol + seg * 8];
            float f[8]; unpack8(v, f);
            #pragma unroll
            for (int e = 0; e < 8; e++) Bsh[r * 128 + seg * 8 + e] = f[e];
        }
        #pragma unroll
        for (int i = 0; i < 2; i++) {            // xdt*decay tile 64x64
            int id = tid + i * 256; int r = id >> 3; int seg = id & 7;
            int srow = rowbase + T * 64 + r;
            float sc = dtsp[(size_t)srow * 64 + h] * __expf(dAlast - dAcs[(size_t)bi * 256 + T * 64 + r]);
            uint4 v = *(const uint4*)&convout[(size_t)srow * CONVDIM + xcol + seg * 8];
            float f[8]; unpack8(v, f);
            #pragma unroll
            for (int e = 0; e < 8; e++) Wx[r * 64 + seg * 8 + e] = f[e] * sc;
        }
        __syncthreads();
        for (int r = 0; r < 64; ++r) {
            float wvv = Wx[r * 64 + p];
            #pragma unroll
            for (int j = 0; j < 8; j++) {
                float4 bv = *(const float4*)&Bsh[r * 128 + q * 4 + j * 16];
                acc[j * 4 + 0] += wvv * bv.x; acc[j * 4 + 1] += wvv * bv.y;
                acc[j * 4 + 2] += wvv * bv.z; acc[j * 4 + 3] += wvv * bv.w;
            }
        }
    }
    size_t base = (size_t)bi * 8192 + (size_t)p * 128 + q * 4;
    #pragma unroll
    for (int j = 0; j < 8; j++) {
        float4 o; o.x = acc[j * 4]; o.y = acc[j * 4 + 1]; o.z = acc[j * 4 + 2]; o.w = acc[j * 4 + 3];
        *(float4*)&states[base + j * 16] = o;
    }
}

// ============================================================
// inter-chunk recurrence (in place: states[c] <- state entering chunk c)
// ============================================================
__global__ void recur_kernel(const float* __restrict__ dAcs, float* __restrict__ states) {
    int bh = blockIdx.x;                  // b*64+h
    int h = bh & 63, b = bh >> 6;
    int tid = threadIdx.x;
    float carry[32];
    #pragma unroll
    for (int i = 0; i < 32; i++) carry[i] = 0.f;
    for (int c = 0; c < 16; c++) {
        int bi = (b * 16 + c) * 64 + h;
        float decay = __expf(dAcs[(size_t)bi * 256 + 255]);
        size_t base = (size_t)bi * 8192;
        #pragma unroll
        for (int i = 0; i < 32; i++) {
            size_t idx = base + i * 256 + tid;
            float tmp = states[idx];
            states[idx] = carry[i];
            carry[i] = carry[i] * decay + tmp;
        }
    }
}

// ============================================================
// MFMA yscan: per (b,c,h) block, Y = Y_diag + Y_off (D*x added in norm).
// ============================================================
__global__ __launch_bounds__(256, 2) void yscan_mfma(
    const ushort* __restrict__ convout, const float* __restrict__ dtsp,
    const float* __restrict__ dAcs, const float* __restrict__ states,
    ushort* __restrict__ y) {
    __shared__ ushort XT[64 * 264];   // xdt^T: XT[p][s], stride 264
    __shared__ ushort PR[64 * 136];   // prev bf16 [p][n], stride 136
    __shared__ ushort PV[4 * 16 * 72];// per-wave P strip
    __shared__ float sdA[256];
    int bi = blockIdx.x;
    int h = bi & 63, cch = (bi >> 6) & 15, b = bi >> 10;
    int tid = threadIdx.x;
    int rowbase = b * 2048 + cch * 256;
    int bcol = 1024 + ((h >> 3) << 7);
    int ccol = 2048 + ((h >> 1) << 7);
    int xcol = ((h >> 3) << 7) + ((h & 1) << 6);

    sdA[tid] = dAcs[(size_t)bi * 256 + tid];
    #pragma unroll
    for (int i = 0; i < 4; i++) {
        int s = i * 64 + (tid & 63);
        float dtv = dtsp[(size_t)(rowbase + s) * 64 + h];
        #pragma unroll
        for (int j = 0; j < 2; j++) {
            int p0 = (((tid >> 6) << 1) + j) << 3;
            uint4 v = *(const uint4*)&convout[(size_t)(rowbase + s) * CONVDIM + xcol + p0];
            float f[8]; unpack8(v, f);
            #pragma unroll
            for (int e = 0; e < 8; e++) XT[(p0 + e) * 264 + s] = f2bf(f[e] * dtv);
        }
    }
    {
        const float* pv = &states[(size_t)bi * 8192];
        #pragma unroll
        for (int i = 0; i < 8; i++) {
            int flat = i * 1024 + tid * 4;
            float4 v = *(const float4*)&pv[flat];
            int p = flat >> 7, n = flat & 127;
            *(uint*)&PR[p * 136 + n]     = pk2(v.x, v.y);
            *(uint*)&PR[p * 136 + n + 2] = pk2(v.z, v.w);
        }
    }
    __syncthreads();

    int w = tid >> 6, lane = tid & 63, g = lane >> 4, c = lane & 15;
    int wbase = w * 64;
    const ushort* Crow0 = &convout[(size_t)(rowbase + wbase + c) * CONVDIM + ccol + 8 * g];

    // ---- Y_off = C . prev^T ----
    f32x4 yac[4][4] = {};
    #pragma unroll
    for (int kb = 0; kb < 4; kb++) {
        bf16x8 pb[4];
        #pragma unroll
        for (int np = 0; np < 4; np++)
            pb[np] = *(const bf16x8*)&PR[(16 * np + c) * 136 + kb * 32 + 8 * g];
        #pragma unroll
        for (int m = 0; m < 4; m++) {
            bf16x8 cf = *(const bf16x8*)&Crow0[(size_t)(m * 16) * CONVDIM + kb * 32];
            #pragma unroll
            for (int np = 0; np < 4; np++)
                yac[m][np] = __builtin_amdgcn_mfma_f32_16x16x32_bf16(cf, pb[np], yac[m][np], 0, 0, 0);
        }
    }
    float al[4][4];
    float Sw = sdA[wbase];
    float eSw = __expf(Sw);
    #pragma unroll
    for (int m = 0; m < 4; m++)
        #pragma unroll
        for (int r = 0; r < 4; r++) {
            float dAl = sdA[wbase + m * 16 + 4 * g + r];
            al[m][r] = __expf(dAl - Sw);
            float el = al[m][r] * eSw;
            #pragma unroll
            for (int np = 0; np < 4; np++) yac[m][np][r] *= el;
        }

    // ---- s-tiles ----
    ushort* pvs = &PV[w * 1152];
    for (int T = 0; T <= w; T++) {
        f32x4 sac[4][4] = {};
        #pragma unroll
        for (int kb = 0; kb < 4; kb++) {
            bf16x8 bb[4];
            #pragma unroll
            for (int np = 0; np < 4; np++)
                bb[np] = *(const bf16x8*)&convout[(size_t)(rowbase + T * 64 + 16 * np + c) * CONVDIM + bcol + kb * 32 + 8 * g];
            #pragma unroll
            for (int m = 0; m < 4; m++) {
                bf16x8 cf = *(const bf16x8*)&Crow0[(size_t)(m * 16) * CONVDIM + kb * 32];
                #pragma unroll
                for (int np = 0; np < 4; np++)
                    sac[m][np] = __builtin_amdgcn_mfma_f32_16x16x32_bf16(cf, bb[np], sac[m][np], 0, 0, 0);
            }
        }
        bf16x8 xb[4][2];
        #pragma unroll
        for (int np = 0; np < 4; np++)
            #pragma unroll
            for (int k2 = 0; k2 < 2; k2++)
                xb[np][k2] = *(const bf16x8*)&XT[(16 * np + c) * 264 + T * 64 + k2 * 32 + 8 * g];
        if (T < w) {
            float ET = sdA[T * 64 + 63];
            float cT = __expf(Sw - ET);
            float bc[4];
            #pragma unroll
            for (int np = 0; np < 4; np++)
                bc[np] = __expf(ET - sdA[T * 64 + 16 * np + c]) * cT;
            #pragma unroll
            for (int m = 0; m < 4; m++) {
                #pragma unroll
                for (int np = 0; np < 4; np++) {
                    float s0 = bc[np];
                    #pragma unroll
                    for (int r = 0; r < 4; r++)
                        pvs[(4 * g + r) * 72 + 16 * np + c] = f2bf(sac[m][np][r] * (al[m][r] * s0));
                }
                bf16x8 pa0 = *(const bf16x8*)&pvs[c * 72 + 8 * g];
                bf16x8 pa1 = *(const bf16x8*)&pvs[c * 72 + 32 + 8 * g];
                #pragma unroll
                for (int np = 0; np < 4; np++) {
                    yac[m][np] = __builtin_amdgcn_mfma_f32_16x16x32_bf16(pa0, xb[np][0], yac[m][np], 0, 0, 0);
                    yac[m][np] = __builtin_amdgcn_mfma_f32_16x16x32_bf16(pa1, xb[np][1], yac[m][np], 0, 0, 0);
                }
            }
        } else {
            #pragma unroll
            for (int m = 0; m < 4; m++) {
                float dal[4];
                #pragma unroll
                for (int r = 0; r < 4; r++) dal[r] = sdA[wbase + m * 16 + 4 * g + r];
                #pragma unroll
                for (int np = 0; np < 4; np++) {
                    int s_loc = w * 64 + 16 * np + c;
                    float dAs = sdA[s_loc];
                    #pragma unroll
                    for (int r = 0; r < 4; r++) {
                        int l_loc = wbase + m * 16 + 4 * g + r;
                        float v = (s_loc <= l_loc) ? sac[m][np][r] * __expf(dal[r] - dAs) : 0.f;
                        pvs[(4 * g + r) * 72 + 16 * np + c] = f2bf(v);
                    }
                }
                bf16x8 pa0 = *(const bf16x8*)&pvs[c * 72 + 8 * g];
                bf16x8 pa1 = *(const bf16x8*)&pvs[c * 72 + 32 + 8 * g];
                #pragma unroll
                for (int np = 0; np < 4; np++) {
                    yac[m][np] = __builtin_amdgcn_mfma_f32_16x16x32_bf16(pa0, xb[np][0], yac[m][np], 0, 0, 0);
                    yac[m][np] = __builtin_amdgcn_mfma_f32_16x16x32_bf16(pa1, xb[np][1], yac[m][np], 0, 0, 0);
                }
            }
        }
    }
    #pragma unroll
    for (int m = 0; m < 4; m++)
        #pragma unroll
        for (int np = 0; np < 4; np++)
            #pragma unroll
            for (int r = 0; r < 4; r++) {
                int l = wbase + m * 16 + 4 * g + r;
                y[(size_t)(rowbase + l) * DINNER + h * 64 + 16 * np + c] = f2bf(yac[m][np][r]);
            }
}

// ============================================================
// gated grouped RMSNorm (in place over y), adds D*x first.
// ============================================================
__global__ void norm_kernel(ushort* __restrict__ y, const ushort* __restrict__ zbuf,
                            const ushort* __restrict__ convout, const float* __restrict__ Dvec,
                            const float* __restrict__ nw) {
    int row = blockIdx.x;                         // token
    int g = blockIdx.y * 4 + (threadIdx.x >> 6);  // group 0..31
    int lane = threadIdx.x & 63;
    int cbase = g * 128 + lane * 2;
    int h = cbase >> 6;
    int p = cbase & 63;
    int xc = ((h >> 3) << 7) + ((h & 1) << 6) + p;
    uint yv = *(const uint*)&y[(size_t)row * DINNER + cbase];
    uint zv = *(const uint*)&zbuf[(size_t)row * DINNER + cbase];
    uint xv = *(const uint*)&convout[(size_t)row * CONVDIM + xc];
    float Dh = Dvec[h];
    float y0 = bflo(yv) + Dh * bflo(xv), y1 = bfhi(yv) + Dh * bfhi(xv);
    float z0 = bflo(zv), z1 = bfhi(zv);
    float v0 = y0 * (z0 / (1.f + __expf(-z0)));
    float v1 = y1 * (z1 / (1.f + __expf(-z1)));
    float ss = v0 * v0 + v1 * v1;
    #pragma unroll
    for (int off = 32; off; off >>= 1) ss += __shfl_xor(ss, off, 64);
    float rstd = rsqrtf(ss * (1.f / 128.f) + 1e-5f);
    v0 *= rstd * nw[cbase];
    v1 *= rstd * nw[cbase + 1];
    *(uint*)&y[(size_t)row * DINNER + cbase] = pk2(v0, v1);
}

// ============================================================
extern "C" void kernel_launch(void* const* d_in, const int* in_sizes, int n_in,
                              void* d_out, int out_size, void* d_ws, size_t ws_size,
                              hipStream_t stream) {
    const float* u       = (const float*)d_in[0];
    const float* W_in    = (const float*)d_in[1];
    const float* conv_w  = (const float*)d_in[2];
    const float* conv_b  = (const float*)d_in[3];
    const float* dt_bias = (const float*)d_in[4];
    const float* A_log   = (const float*)d_in[5];
    const float* Dvec    = (const float*)d_in[6];
    const float* nw      = (const float*)d_in[7];
    const float* W_out   = (const float*)d_in[8];

    // ---- workspace layout (≈179 MiB, aliased bf16 staging) ----
    char* ws = (char*)d_ws;
    size_t off = 0;
    auto alloc = [&](size_t bytes) { void* p = ws + off; off += (bytes + 255) & ~(size_t)255; return p; };
    ushort* zbuf    = (ushort*)alloc((size_t)LTOT * DINNER * 2);          // 32 MiB
    // shreg: xbc (48 MiB) -> states (64 MiB) -> Wout_bf (16.8 MiB)
    void*   shreg   = alloc((size_t)2048 * 8192 * 4);                     // 64 MiB
    ushort* xbc     = (ushort*)shreg;
    float*  states  = (float*)shreg;
    ushort* Wout_bf = (ushort*)shreg;
    float*  dtbuf   = (float*) alloc((size_t)LTOT * 64 * 4);              // 1 MiB
    // conv region: Win_bf (padded to 10368 rows, 42.5 MiB) -> convout (48 MiB)
    void*   convreg = alloc((size_t)LTOT * CONVDIM * 2);                  // 48 MiB
    ushort* Win_bf  = (ushort*)convreg;
    ushort* convout = (ushort*)convreg;
    float*  dAcs    = (float*) alloc((size_t)2048 * 256 * 4);             // 2 MiB
    // ybuf region: u_bf (16.8 MiB) -> ybuf (32 MiB)
    void*   ybreg   = alloc((size_t)LTOT * DINNER * 2);                   // 32 MiB
    ushort* u_bf    = (ushort*)ybreg;
    ushort* ybuf    = (ushort*)ybreg;

    // bf16 conversions (aliased into dead regions)
    cvt_kernel<<<dim3(8192),  dim3(256), 0, stream>>>(u, u_bf, 2097152);
    cvt_kernel<<<dim3(20608), dim3(256), 0, stream>>>(W_in, Win_bf, 5275648);
    // in_proj (m97-style bf16 GEMM, XCD swizzle; grid 81*32=2592, %8==0)
    gemm_bf16<0><<<dim3(2592), dim3(256), 0, stream>>>(
        u_bf, Win_bf, zbuf, xbc, dtbuf, (float*)nullptr, LTOT, DPROJ, DMODEL, 81);
    // conv + silu (overwrites Win_bf region — dead)
    conv_kernel<<<dim3(24, 4096), dim3(256), 0, stream>>>(xbc, conv_w, conv_b, convout);
    // dt softplus (in place), cumsum
    dtsp_kernel<<<dim3(1024), dim3(256), 0, stream>>>(dtbuf, dt_bias);
    cumsum_kernel<<<dim3(2048), dim3(256), 0, stream>>>(dtbuf, A_log, dAcs);
    // chunked scan (states overwrites xbc region — dead after conv)
    states_kernel<<<dim3(2048), dim3(256), 0, stream>>>(convout, dtbuf, dAcs, states);
    recur_kernel<<<dim3(128), dim3(256), 0, stream>>>(dAcs, states);
    yscan_mfma<<<dim3(2048), dim3(256), 0, stream>>>(convout, dtbuf, dAcs, states, ybuf);
    // W_out -> bf16 (states dead after yscan)
    cvt_kernel<<<dim3(8192), dim3(256), 0, stream>>>(W_out, Wout_bf, 2097152);
    // gated group RMSNorm (in place, adds D*x)
    norm_kernel<<<dim3(4096, 8), dim3(256), 0, stream>>>(ybuf, zbuf, convout, Dvec, nw);
    // out_proj (grid 16*32=512, %8==0)
    gemm_bf16<1><<<dim3(512), dim3(256), 0, stream>>>(
        ybuf, Wout_bf, (ushort*)nullptr, (ushort*)nullptr, (float*)nullptr,
        (float*)d_out, LTOT, DMODEL, DINNER, 16);
}

// Round 6
// 647.588 us; speedup vs baseline: 8.1936x; 1.2743x over previous
//
#include <hip/hip_runtime.h>
#include <cstdint>
#include <cstddef>

typedef unsigned int uint;
typedef unsigned short ushort;

typedef __bf16 bf16x8 __attribute__((ext_vector_type(8)));
typedef float f32x4 __attribute__((ext_vector_type(4)));

// ---------- bf16 helpers (bit-level) ----------
__device__ __forceinline__ float bflo(uint u) { return __uint_as_float(u << 16); }
__device__ __forceinline__ float bfhi(uint u) { return __uint_as_float(u & 0xffff0000u); }
__device__ __forceinline__ float bf2f(ushort s) { return __uint_as_float(((uint)s) << 16); }
__device__ __forceinline__ ushort f2bf(float f) {
    uint u = __float_as_uint(f);
    u += 0x7fffu + ((u >> 16) & 1u);   // round-to-nearest-even
    return (ushort)(u >> 16);
}
__device__ __forceinline__ uint pk2(float lo, float hi) {
    return (uint)f2bf(lo) | ((uint)f2bf(hi) << 16);
}
__device__ __forceinline__ void unpack8(uint4 v, float* f) {
    f[0] = bflo(v.x); f[1] = bfhi(v.x); f[2] = bflo(v.y); f[3] = bfhi(v.y);
    f[4] = bflo(v.z); f[5] = bfhi(v.z); f[6] = bflo(v.w); f[7] = bfhi(v.w);
}

// async global->LDS, 16B per lane, wave-uniform LDS base (linear dest)
typedef __attribute__((address_space(1))) const unsigned int* as1_cuptr;
typedef __attribute__((address_space(3))) unsigned int* as3_uptr;
__device__ __forceinline__ void gload_lds16(const void* g, void* l) {
    __builtin_amdgcn_global_load_lds((as1_cuptr)g, (as3_uptr)l, 16, 0, 0);
}

// ---------- constants ----------
#define LTOT 4096           // b*l tokens (2 batches x 2048)
#define DMODEL 2048
#define DINNER 4096
#define DSTATE 128
#define NHEADS 64
#define CONVDIM 6144
#define DPROJ 10304
#define CHUNK 256
#define NCHUNK 16           // GLOBAL chunks (8 per batch x 2 batches)

// ============================================================
// fp32 -> bf16 conversion (vectorized)
// ============================================================
__global__ void cvt_kernel(const float* __restrict__ in, ushort* __restrict__ out, int n4) {
    int i = blockIdx.x * 256 + threadIdx.x;
    if (i < n4) {
        float4 v = ((const float4*)in)[i];
        ushort4 o;
        o.x = f2bf(v.x); o.y = f2bf(v.y); o.z = f2bf(v.z); o.w = f2bf(v.w);
        ((ushort4*)out)[i] = o;
    }
}

// ============================================================
// pure-bf16 MFMA GEMM (m97 structure): Out[M][N] = X[M][K] * W[N][K]^T
// ============================================================
template <int MODE>
__global__ __launch_bounds__(256) void gemm_bf16(
    const ushort* __restrict__ X, const ushort* __restrict__ W,
    ushort* __restrict__ zbuf, ushort* __restrict__ xbc, float* __restrict__ dtraw,
    float* __restrict__ outF, int M, int N, int K, int NB) {
    __shared__ ushort As[128 * 32];
    __shared__ ushort Bs[128 * 32];
    int q = gridDim.x >> 3;
    int wg = blockIdx.x;
    int swz = (wg & 7) * q + (wg >> 3);
    int bn = swz % NB, bm = swz / NB;
    int tid = threadIdx.x;
    int lane = tid & 63, w = tid >> 6;
    int wr = w >> 1, wc = w & 1;
    int lr = lane & 15, lk = (lane >> 4) * 8;
    int r0 = lane >> 2;          // 0..15
    int ce = (lane & 3) * 8;     // k-elem 0,8,16,24
    const ushort* gA0 = &X[(size_t)(bm * 128 + (w * 2 + 0) * 16 + r0) * K + ce];
    const ushort* gA1 = &X[(size_t)(bm * 128 + (w * 2 + 1) * 16 + r0) * K + ce];
    const ushort* gB0 = &W[(size_t)(bn * 128 + (w * 2 + 0) * 16 + r0) * K + ce];
    const ushort* gB1 = &W[(size_t)(bn * 128 + (w * 2 + 1) * 16 + r0) * K + ce];
    ushort* lA0 = &As[(w * 2 + 0) * 512];
    ushort* lA1 = &As[(w * 2 + 1) * 512];
    ushort* lB0 = &Bs[(w * 2 + 0) * 512];
    ushort* lB1 = &Bs[(w * 2 + 1) * 512];
    f32x4 acc[4][4] = {};
    for (int kk = 0; kk < K; kk += 32) {
        __syncthreads();
        gload_lds16(gA0, lA0); gload_lds16(gA1, lA1);
        gload_lds16(gB0, lB0); gload_lds16(gB1, lB1);
        gA0 += 32; gA1 += 32; gB0 += 32; gB1 += 32;
        __syncthreads();
        bf16x8 af[4], bfr[4];
        #pragma unroll
        for (int m = 0; m < 4; m++) af[m] = *(const bf16x8*)&As[(wr * 64 + m * 16 + lr) * 32 + lk];
        #pragma unroll
        for (int n = 0; n < 4; n++) bfr[n] = *(const bf16x8*)&Bs[(wc * 64 + n * 16 + lr) * 32 + lk];
        #pragma unroll
        for (int m = 0; m < 4; m++)
            #pragma unroll
            for (int n = 0; n < 4; n++)
                acc[m][n] = __builtin_amdgcn_mfma_f32_16x16x32_bf16(af[m], bfr[n], acc[m][n], 0, 0, 0);
    }
    int rq = (lane >> 4) * 4;
    #pragma unroll
    for (int m = 0; m < 4; m++) {
        int row0 = bm * 128 + wr * 64 + m * 16 + rq;
        #pragma unroll
        for (int n = 0; n < 4; n++) {
            int col = bn * 128 + wc * 64 + n * 16 + lr;
            #pragma unroll
            for (int r = 0; r < 4; r++) {
                float v = acc[m][n][r];
                int row = row0 + r;
                if (MODE == 1) {
                    outF[(size_t)row * N + col] = v;
                } else {
                    if (col < 4096) {
                        zbuf[(size_t)row * DINNER + col] = f2bf(v);
                    } else if (col < 10240) {
                        xbc[(size_t)row * CONVDIM + (col - 4096)] = f2bf(v);
                    } else if (col < DPROJ) {
                        dtraw[(size_t)row * 64 + (col - 10240)] = v;
                    }
                }
            }
        }
    }
}

// ============================================================
// causal depthwise conv1d (K=4) + SiLU, vectorized 8 ch/thread
// ============================================================
__global__ void conv_kernel(const ushort* __restrict__ xbc, const float* __restrict__ cw,
                            const float* __restrict__ cb, ushort* __restrict__ convout) {
    int c8 = (blockIdx.x * 256 + threadIdx.x) * 8;   // channel base 0..6136
    int row = blockIdx.y;                            // token 0..4095
    int t = row & 2047;                              // within-batch position
    float av[8];
    {
        float4 b0 = ((const float4*)cb)[c8 / 4];
        float4 b1 = ((const float4*)cb)[c8 / 4 + 1];
        av[0] = b0.x; av[1] = b0.y; av[2] = b0.z; av[3] = b0.w;
        av[4] = b1.x; av[5] = b1.y; av[6] = b1.z; av[7] = b1.w;
    }
    float wk[8][4];
    #pragma unroll
    for (int e = 0; e < 8; e++) {
        float4 wv = ((const float4*)cw)[c8 + e];
        wk[e][0] = wv.x; wk[e][1] = wv.y; wk[e][2] = wv.z; wk[e][3] = wv.w;
    }
    #pragma unroll
    for (int k = 0; k < 4; k++) {
        int tt = t - 3 + k;
        if (tt >= 0) {                                // block-uniform branch
            uint4 v = *(const uint4*)&xbc[(size_t)(row - 3 + k) * CONVDIM + c8];
            float f[8]; unpack8(v, f);
            #pragma unroll
            for (int e = 0; e < 8; e++) av[e] += f[e] * wk[e][k];
        }
    }
    uint4 o;
    float s[8];
    #pragma unroll
    for (int e = 0; e < 8; e++) s[e] = av[e] / (1.f + __expf(-av[e]));
    o.x = pk2(s[0], s[1]); o.y = pk2(s[2], s[3]);
    o.z = pk2(s[4], s[5]); o.w = pk2(s[6], s[7]);
    *(uint4*)&convout[(size_t)row * CONVDIM + c8] = o;
}

// ============================================================
// fused: softplus(dtraw+bias) (in place) + per-chunk cumsum of dt*A
// grid = NCHUNK*64 = 1024 blocks: bi = cg*64 + h (cg = global chunk)
// ============================================================
__global__ void cumsum_kernel(float* __restrict__ dtbuf, const float* __restrict__ dt_bias,
                              const float* __restrict__ A_log, float* __restrict__ dAcs) {
    int bi = blockIdx.x;
    int h = bi & 63, cg = bi >> 6;            // cg in [0,16)
    int t = threadIdx.x;
    size_t didx = (size_t)(cg * 256 + t) * 64 + h;
    float x = dtbuf[didx] + dt_bias[h];
    float sp = (x > 20.f) ? x : log1pf(__expf(x));
    dtbuf[didx] = sp;
    float A = -expf(A_log[h]);
    float v = sp * A;
    __shared__ float s[256];
    s[t] = v;
    __syncthreads();
    for (int off = 1; off < 256; off <<= 1) {
        float add = (t >= off) ? s[t - off] : 0.f;
        __syncthreads();
        s[t] += add;
        __syncthreads();
    }
    dAcs[(size_t)bi * 256 + t] = s[t];
}

// ============================================================
// MFMA states: per (cg,h), states[p][n] = sum_s xdt'[s,p] * B[s,n]
// grid 1024: bi = cg*64 + h
// ============================================================
__global__ __launch_bounds__(256) void states_mfma(
    const ushort* __restrict__ convout, const float* __restrict__ dtsp,
    const float* __restrict__ dAcs, float* __restrict__ states) {
    __shared__ ushort BT[128 * 72];   // 18 KB, stride 72 elems
    __shared__ ushort XT[64 * 72];    // 9 KB
    int bi = blockIdx.x;
    int h = bi & 63, cg = bi >> 6;
    int tid = threadIdx.x;
    int rowbase = cg * 256;
    int bcol = 1024 + ((h >> 3) << 7);
    int xcol = ((h >> 3) << 7) + ((h & 1) << 6);
    float dAlast = dAcs[(size_t)bi * 256 + 255];
    int w = tid >> 6, lane = tid & 63, g = lane >> 4, cc = lane & 15;
    f32x4 acc[4][2] = {};
    for (int T = 0; T < 4; T++) {
        __syncthreads();   // previous tile's reads done
        int s = lane;
        int srow = rowbase + T * 64 + s;
        #pragma unroll
        for (int i = 0; i < 4; i++) {
            int n0 = (w + i * 4) * 8;
            uint4 v = *(const uint4*)&convout[(size_t)srow * CONVDIM + bcol + n0];
            ushort us[8];
            us[0] = (ushort)v.x; us[1] = (ushort)(v.x >> 16);
            us[2] = (ushort)v.y; us[3] = (ushort)(v.y >> 16);
            us[4] = (ushort)v.z; us[5] = (ushort)(v.z >> 16);
            us[6] = (ushort)v.w; us[7] = (ushort)(v.w >> 16);
            #pragma unroll
            for (int e = 0; e < 8; e++) BT[(n0 + e) * 72 + s] = us[e];
        }
        float wgt = dtsp[(size_t)srow * 64 + h] * __expf(dAlast - dAcs[(size_t)bi * 256 + T * 64 + s]);
        #pragma unroll
        for (int j = 0; j < 2; j++) {
            int p0 = (w * 2 + j) * 8;
            uint4 v = *(const uint4*)&convout[(size_t)srow * CONVDIM + xcol + p0];
            float f[8]; unpack8(v, f);
            #pragma unroll
            for (int e = 0; e < 8; e++) XT[(p0 + e) * 72 + s] = f2bf(f[e] * wgt);
        }
        __syncthreads();
        bf16x8 af[4][2], bw[2][2];
        #pragma unroll
        for (int m = 0; m < 4; m++)
            #pragma unroll
            for (int kb = 0; kb < 2; kb++)
                af[m][kb] = *(const bf16x8*)&XT[(m * 16 + cc) * 72 + kb * 32 + 8 * g];
        #pragma unroll
        for (int np = 0; np < 2; np++)
            #pragma unroll
            for (int kb = 0; kb < 2; kb++)
                bw[np][kb] = *(const bf16x8*)&BT[(w * 32 + np * 16 + cc) * 72 + kb * 32 + 8 * g];
        #pragma unroll
        for (int m = 0; m < 4; m++)
            #pragma unroll
            for (int np = 0; np < 2; np++) {
                acc[m][np] = __builtin_amdgcn_mfma_f32_16x16x32_bf16(af[m][0], bw[np][0], acc[m][np], 0, 0, 0);
                acc[m][np] = __builtin_amdgcn_mfma_f32_16x16x32_bf16(af[m][1], bw[np][1], acc[m][np], 0, 0, 0);
            }
    }
    size_t base = (size_t)bi * 8192;
    #pragma unroll
    for (int m = 0; m < 4; m++)
        #pragma unroll
        for (int np = 0; np < 2; np++)
            #pragma unroll
            for (int r = 0; r < 4; r++) {
                int p = m * 16 + 4 * g + r;
                int n = w * 32 + np * 16 + cc;
                states[base + (size_t)p * 128 + n] = acc[m][np][r];
            }
}

// ============================================================
// inter-chunk recurrence: 8 chunks PER BATCH, carry resets per batch
// ============================================================
__global__ void recur_kernel(const float* __restrict__ dAcs, float* __restrict__ states) {
    int bh = blockIdx.x;                  // b*64+h
    int h = bh & 63, b = bh >> 6;
    int tid = threadIdx.x;
    float carry[32];
    #pragma unroll
    for (int i = 0; i < 32; i++) carry[i] = 0.f;
    for (int c = 0; c < 8; c++) {
        int bi = (b * 8 + c) * 64 + h;
        float decay = __expf(dAcs[(size_t)bi * 256 + 255]);
        size_t base = (size_t)bi * 8192;
        #pragma unroll
        for (int i = 0; i < 32; i++) {
            size_t idx = base + i * 256 + tid;
            float tmp = states[idx];
            states[idx] = carry[i];
            carry[i] = carry[i] * decay + tmp;
        }
    }
}

// ============================================================
// MFMA yscan: per (cg,h) block, Y = Y_diag + Y_off (D*x added in norm).
// grid 1024: bi = cg*64 + h
// ============================================================
__global__ __launch_bounds__(256, 2) void yscan_mfma(
    const ushort* __restrict__ convout, const float* __restrict__ dtsp,
    const float* __restrict__ dAcs, const float* __restrict__ states,
    ushort* __restrict__ y) {
    __shared__ ushort XT[64 * 264];   // xdt^T: XT[p][s], stride 264
    __shared__ ushort PR[64 * 136];   // prev bf16 [p][n], stride 136
    __shared__ ushort PV[4 * 16 * 72];// per-wave P strip
    __shared__ float sdA[256];
    int bi = blockIdx.x;
    int h = bi & 63, cg = bi >> 6;
    int tid = threadIdx.x;
    int rowbase = cg * 256;
    int bcol = 1024 + ((h >> 3) << 7);
    int ccol = 2048 + ((h >> 1) << 7);
    int xcol = ((h >> 3) << 7) + ((h & 1) << 6);

    sdA[tid] = dAcs[(size_t)bi * 256 + tid];
    #pragma unroll
    for (int i = 0; i < 4; i++) {
        int s = i * 64 + (tid & 63);
        float dtv = dtsp[(size_t)(rowbase + s) * 64 + h];
        #pragma unroll
        for (int j = 0; j < 2; j++) {
            int p0 = (((tid >> 6) << 1) + j) << 3;
            uint4 v = *(const uint4*)&convout[(size_t)(rowbase + s) * CONVDIM + xcol + p0];
            float f[8]; unpack8(v, f);
            #pragma unroll
            for (int e = 0; e < 8; e++) XT[(p0 + e) * 264 + s] = f2bf(f[e] * dtv);
        }
    }
    {
        const float* pv = &states[(size_t)bi * 8192];
        #pragma unroll
        for (int i = 0; i < 8; i++) {
            int flat = i * 1024 + tid * 4;
            float4 v = *(const float4*)&pv[flat];
            int p = flat >> 7, n = flat & 127;
            *(uint*)&PR[p * 136 + n]     = pk2(v.x, v.y);
            *(uint*)&PR[p * 136 + n + 2] = pk2(v.z, v.w);
        }
    }
    __syncthreads();

    int w = tid >> 6, lane = tid & 63, g = lane >> 4, c = lane & 15;
    int wbase = w * 64;
    const ushort* Crow0 = &convout[(size_t)(rowbase + wbase + c) * CONVDIM + ccol + 8 * g];

    // ---- Y_off = C . prev^T ----
    f32x4 yac[4][4] = {};
    #pragma unroll
    for (int kb = 0; kb < 4; kb++) {
        bf16x8 pb[4];
        #pragma unroll
        for (int np = 0; np < 4; np++)
            pb[np] = *(const bf16x8*)&PR[(16 * np + c) * 136 + kb * 32 + 8 * g];
        #pragma unroll
        for (int m = 0; m < 4; m++) {
            bf16x8 cf = *(const bf16x8*)&Crow0[(size_t)(m * 16) * CONVDIM + kb * 32];
            #pragma unroll
            for (int np = 0; np < 4; np++)
                yac[m][np] = __builtin_amdgcn_mfma_f32_16x16x32_bf16(cf, pb[np], yac[m][np], 0, 0, 0);
        }
    }
    float al[4][4];
    float Sw = sdA[wbase];
    float eSw = __expf(Sw);
    #pragma unroll
    for (int m = 0; m < 4; m++)
        #pragma unroll
        for (int r = 0; r < 4; r++) {
            float dAl = sdA[wbase + m * 16 + 4 * g + r];
            al[m][r] = __expf(dAl - Sw);
            float el = al[m][r] * eSw;
            #pragma unroll
            for (int np = 0; np < 4; np++) yac[m][np][r] *= el;
        }

    // ---- s-tiles ----
    ushort* pvs = &PV[w * 1152];
    for (int T = 0; T <= w; T++) {
        f32x4 sac[4][4] = {};
        #pragma unroll
        for (int kb = 0; kb < 4; kb++) {
            bf16x8 bb[4];
            #pragma unroll
            for (int np = 0; np < 4; np++)
                bb[np] = *(const bf16x8*)&convout[(size_t)(rowbase + T * 64 + 16 * np + c) * CONVDIM + bcol + kb * 32 + 8 * g];
            #pragma unroll
            for (int m = 0; m < 4; m++) {
                bf16x8 cf = *(const bf16x8*)&Crow0[(size_t)(m * 16) * CONVDIM + kb * 32];
                #pragma unroll
                for (int np = 0; np < 4; np++)
                    sac[m][np] = __builtin_amdgcn_mfma_f32_16x16x32_bf16(cf, bb[np], sac[m][np], 0, 0, 0);
            }
        }
        bf16x8 xb[4][2];
        #pragma unroll
        for (int np = 0; np < 4; np++)
            #pragma unroll
            for (int k2 = 0; k2 < 2; k2++)
                xb[np][k2] = *(const bf16x8*)&XT[(16 * np + c) * 264 + T * 64 + k2 * 32 + 8 * g];
        if (T < w) {
            float ET = sdA[T * 64 + 63];
            float cT = __expf(Sw - ET);
            float bc[4];
            #pragma unroll
            for (int np = 0; np < 4; np++)
                bc[np] = __expf(ET - sdA[T * 64 + 16 * np + c]) * cT;
            #pragma unroll
            for (int m = 0; m < 4; m++) {
                #pragma unroll
                for (int np = 0; np < 4; np++) {
                    float s0 = bc[np];
                    #pragma unroll
                    for (int r = 0; r < 4; r++)
                        pvs[(4 * g + r) * 72 + 16 * np + c] = f2bf(sac[m][np][r] * (al[m][r] * s0));
                }
                bf16x8 pa0 = *(const bf16x8*)&pvs[c * 72 + 8 * g];
                bf16x8 pa1 = *(const bf16x8*)&pvs[c * 72 + 32 + 8 * g];
                #pragma unroll
                for (int np = 0; np < 4; np++) {
                    yac[m][np] = __builtin_amdgcn_mfma_f32_16x16x32_bf16(pa0, xb[np][0], yac[m][np], 0, 0, 0);
                    yac[m][np] = __builtin_amdgcn_mfma_f32_16x16x32_bf16(pa1, xb[np][1], yac[m][np], 0, 0, 0);
                }
            }
        } else {
            #pragma unroll
            for (int m = 0; m < 4; m++) {
                float dal[4];
                #pragma unroll
                for (int r = 0; r < 4; r++) dal[r] = sdA[wbase + m * 16 + 4 * g + r];
                #pragma unroll
                for (int np = 0; np < 4; np++) {
                    int s_loc = w * 64 + 16 * np + c;
                    float dAs = sdA[s_loc];
                    #pragma unroll
                    for (int r = 0; r < 4; r++) {
                        int l_loc = wbase + m * 16 + 4 * g + r;
                        float v = (s_loc <= l_loc) ? sac[m][np][r] * __expf(dal[r] - dAs) : 0.f;
                        pvs[(4 * g + r) * 72 + 16 * np + c] = f2bf(v);
                    }
                }
                bf16x8 pa0 = *(const bf16x8*)&pvs[c * 72 + 8 * g];
                bf16x8 pa1 = *(const bf16x8*)&pvs[c * 72 + 32 + 8 * g];
                #pragma unroll
                for (int np = 0; np < 4; np++) {
                    yac[m][np] = __builtin_amdgcn_mfma_f32_16x16x32_bf16(pa0, xb[np][0], yac[m][np], 0, 0, 0);
                    yac[m][np] = __builtin_amdgcn_mfma_f32_16x16x32_bf16(pa1, xb[np][1], yac[m][np], 0, 0, 0);
                }
            }
        }
    }
    #pragma unroll
    for (int m = 0; m < 4; m++)
        #pragma unroll
        for (int np = 0; np < 4; np++)
            #pragma unroll
            for (int r = 0; r < 4; r++) {
                int l = wbase + m * 16 + 4 * g + r;
                y[(size_t)(rowbase + l) * DINNER + h * 64 + 16 * np + c] = f2bf(yac[m][np][r]);
            }
}

// ============================================================
// gated grouped RMSNorm (in place over y), adds D*x first.
// ============================================================
__global__ void norm_kernel(ushort* __restrict__ y, const ushort* __restrict__ zbuf,
                            const ushort* __restrict__ convout, const float* __restrict__ Dvec,
                            const float* __restrict__ nw) {
    int row = blockIdx.x;                         // token
    int g = blockIdx.y * 4 + (threadIdx.x >> 6);  // group 0..31
    int lane = threadIdx.x & 63;
    int cbase = g * 128 + lane * 2;
    int h = cbase >> 6;
    int p = cbase & 63;
    int xc = ((h >> 3) << 7) + ((h & 1) << 6) + p;
    uint yv = *(const uint*)&y[(size_t)row * DINNER + cbase];
    uint zv = *(const uint*)&zbuf[(size_t)row * DINNER + cbase];
    uint xv = *(const uint*)&convout[(size_t)row * CONVDIM + xc];
    float Dh = Dvec[h];
    float y0 = bflo(yv) + Dh * bflo(xv), y1 = bfhi(yv) + Dh * bfhi(xv);
    float z0 = bflo(zv), z1 = bfhi(zv);
    float v0 = y0 * (z0 / (1.f + __expf(-z0)));
    float v1 = y1 * (z1 / (1.f + __expf(-z1)));
    float ss = v0 * v0 + v1 * v1;
    #pragma unroll
    for (int off = 32; off; off >>= 1) ss += __shfl_xor(ss, off, 64);
    float rstd = rsqrtf(ss * (1.f / 128.f) + 1e-5f);
    v0 *= rstd * nw[cbase];
    v1 *= rstd * nw[cbase + 1];
    *(uint*)&y[(size_t)row * DINNER + cbase] = pk2(v0, v1);
}

// ============================================================
extern "C" void kernel_launch(void* const* d_in, const int* in_sizes, int n_in,
                              void* d_out, int out_size, void* d_ws, size_t ws_size,
                              hipStream_t stream) {
    const float* u       = (const float*)d_in[0];
    const float* W_in    = (const float*)d_in[1];
    const float* conv_w  = (const float*)d_in[2];
    const float* conv_b  = (const float*)d_in[3];
    const float* dt_bias = (const float*)d_in[4];
    const float* A_log   = (const float*)d_in[5];
    const float* Dvec    = (const float*)d_in[6];
    const float* nw      = (const float*)d_in[7];
    const float* W_out   = (const float*)d_in[8];

    // ---- workspace layout (aliased bf16 staging) ----
    char* ws = (char*)d_ws;
    size_t off = 0;
    auto alloc = [&](size_t bytes) { void* p = ws + off; off += (bytes + 255) & ~(size_t)255; return p; };
    ushort* zbuf    = (ushort*)alloc((size_t)LTOT * DINNER * 2);          // 32 MiB
    // shreg: xbc (48 MiB) -> states (32 MiB) -> Wout_bf (16.8 MiB)
    void*   shreg   = alloc((size_t)LTOT * CONVDIM * 2);                  // 48 MiB
    ushort* xbc     = (ushort*)shreg;
    float*  states  = (float*)shreg;
    ushort* Wout_bf = (ushort*)shreg;
    float*  dtbuf   = (float*) alloc((size_t)LTOT * 64 * 4);              // 1 MiB
    // conv region: Win_bf (padded to 10368 rows, 42.5 MiB) -> convout (48 MiB)
    void*   convreg = alloc((size_t)LTOT * CONVDIM * 2);                  // 48 MiB
    ushort* Win_bf  = (ushort*)convreg;
    ushort* convout = (ushort*)convreg;
    float*  dAcs    = (float*) alloc((size_t)1024 * 256 * 4);             // 1 MiB
    // ybuf region: u_bf (16.8 MiB) -> ybuf (32 MiB)
    void*   ybreg   = alloc((size_t)LTOT * DINNER * 2);                   // 32 MiB
    ushort* u_bf    = (ushort*)ybreg;
    ushort* ybuf    = (ushort*)ybreg;

    // bf16 conversions (aliased into dead regions)
    cvt_kernel<<<dim3(8192),  dim3(256), 0, stream>>>(u, u_bf, 2097152);
    cvt_kernel<<<dim3(20608), dim3(256), 0, stream>>>(W_in, Win_bf, 5275648);
    // in_proj (bf16 GEMM, XCD swizzle; grid 81*32=2592)
    gemm_bf16<0><<<dim3(2592), dim3(256), 0, stream>>>(
        u_bf, Win_bf, zbuf, xbc, dtbuf, (float*)nullptr, LTOT, DPROJ, DMODEL, 81);
    // conv + silu (vectorized; overwrites Win_bf region — dead)
    conv_kernel<<<dim3(3, 4096), dim3(256), 0, stream>>>(xbc, conv_w, conv_b, convout);
    // fused softplus + cumsum (grid 16 chunks x 64 heads = 1024)
    cumsum_kernel<<<dim3(1024), dim3(256), 0, stream>>>(dtbuf, dt_bias, A_log, dAcs);
    // chunked scan (states overwrites xbc region — dead after conv)
    states_mfma<<<dim3(1024), dim3(256), 0, stream>>>(convout, dtbuf, dAcs, states);
    recur_kernel<<<dim3(128), dim3(256), 0, stream>>>(dAcs, states);
    yscan_mfma<<<dim3(1024), dim3(256), 0, stream>>>(convout, dtbuf, dAcs, states, ybuf);
    // W_out -> bf16 (states dead after yscan)
    cvt_kernel<<<dim3(8192), dim3(256), 0, stream>>>(W_out, Wout_bf, 2097152);
    // gated group RMSNorm (in place, adds D*x)
    norm_kernel<<<dim3(4096, 8), dim3(256), 0, stream>>>(ybuf, zbuf, convout, Dvec, nw);
    // out_proj (grid 16*32=512)
    gemm_bf16<1><<<dim3(512), dim3(256), 0, stream>>>(
        ybuf, Wout_bf, (ushort*)nullptr, (ushort*)nullptr, (float*)nullptr,
        (float*)d_out, LTOT, DMODEL, DINNER, 16);
}

// Round 8
// 566.815 us; speedup vs baseline: 9.3612x; 1.1425x over previous
//
#include <hip/hip_runtime.h>
#include <cstdint>
#include <cstddef>

typedef unsigned int uint;
typedef unsigned short ushort;

typedef __bf16 bf16x8 __attribute__((ext_vector_type(8)));
typedef float f32x4 __attribute__((ext_vector_type(4)));

// ---------- bf16 helpers (bit-level) ----------
__device__ __forceinline__ float bflo(uint u) { return __uint_as_float(u << 16); }
__device__ __forceinline__ float bfhi(uint u) { return __uint_as_float(u & 0xffff0000u); }
__device__ __forceinline__ float bf2f(ushort s) { return __uint_as_float(((uint)s) << 16); }
__device__ __forceinline__ ushort f2bf(float f) {
    uint u = __float_as_uint(f);
    u += 0x7fffu + ((u >> 16) & 1u);   // round-to-nearest-even
    return (ushort)(u >> 16);
}
__device__ __forceinline__ uint pk2(float lo, float hi) {
    return (uint)f2bf(lo) | ((uint)f2bf(hi) << 16);
}
__device__ __forceinline__ void unpack8(uint4 v, float* f) {
    f[0] = bflo(v.x); f[1] = bfhi(v.x); f[2] = bflo(v.y); f[3] = bfhi(v.y);
    f[4] = bflo(v.z); f[5] = bfhi(v.z); f[6] = bflo(v.w); f[7] = bfhi(v.w);
}

// async global->LDS, 16B per lane, wave-uniform LDS base (linear dest)
typedef __attribute__((address_space(1))) const unsigned int* as1_cuptr;
typedef __attribute__((address_space(3))) unsigned int* as3_uptr;
__device__ __forceinline__ void gload_lds16(const void* g, void* l) {
    __builtin_amdgcn_global_load_lds((as1_cuptr)g, (as3_uptr)l, 16, 0, 0);
}

// ---------- constants ----------
#define LTOT 4096           // b*l tokens (2 batches x 2048)
#define DMODEL 2048
#define DINNER 4096
#define DSTATE 128
#define NHEADS 64
#define CONVDIM 6144
#define DPROJ 10304
#define CHUNK 256
#define NCHUNK 16           // GLOBAL chunks (8 per batch x 2 batches)

// ============================================================
// fp32 -> bf16 conversion (vectorized)
// ============================================================
__global__ void cvt_kernel(const float* __restrict__ in, ushort* __restrict__ out, int n4) {
    int i = blockIdx.x * 256 + threadIdx.x;
    if (i < n4) {
        float4 v = ((const float4*)in)[i];
        ushort4 o;
        o.x = f2bf(v.x); o.y = f2bf(v.y); o.z = f2bf(v.z); o.w = f2bf(v.w);
        ((ushort4*)out)[i] = o;
    }
}

// ============================================================
// pure-bf16 MFMA GEMM (m97 structure): Out[M][N] = X[M][K] * W[N][K]^T
// Supertile swizzle: XCD x owns bm in [4x,4x+4) (A L2-resident),
// walks bn with bm innermost (B single-stream per XCD).
// ============================================================
template <int MODE>
__global__ __launch_bounds__(256) void gemm_bf16(
    const ushort* __restrict__ X, const ushort* __restrict__ W,
    ushort* __restrict__ zbuf, ushort* __restrict__ xbc, float* __restrict__ dtraw,
    float* __restrict__ outF, int M, int N, int K, int NB) {
    __shared__ ushort As[128 * 32];
    __shared__ ushort Bs[128 * 32];
    int q = gridDim.x >> 3;
    int wg = blockIdx.x;
    int swz = (wg & 7) * q + (wg >> 3);        // XCD-contiguous chunks
    int per = NB * 4;
    int sg = swz / per, rr = swz % per;
    int bm = sg * 4 + (rr & 3);
    int bn = rr >> 2;
    int tid = threadIdx.x;
    int lane = tid & 63, w = tid >> 6;
    int wr = w >> 1, wc = w & 1;
    int lr = lane & 15, lk = (lane >> 4) * 8;
    int r0 = lane >> 2;          // 0..15
    int ce = (lane & 3) * 8;     // k-elem 0,8,16,24
    const ushort* gA0 = &X[(size_t)(bm * 128 + (w * 2 + 0) * 16 + r0) * K + ce];
    const ushort* gA1 = &X[(size_t)(bm * 128 + (w * 2 + 1) * 16 + r0) * K + ce];
    const ushort* gB0 = &W[(size_t)(bn * 128 + (w * 2 + 0) * 16 + r0) * K + ce];
    const ushort* gB1 = &W[(size_t)(bn * 128 + (w * 2 + 1) * 16 + r0) * K + ce];
    ushort* lA0 = &As[(w * 2 + 0) * 512];
    ushort* lA1 = &As[(w * 2 + 1) * 512];
    ushort* lB0 = &Bs[(w * 2 + 0) * 512];
    ushort* lB1 = &Bs[(w * 2 + 1) * 512];
    f32x4 acc[4][4] = {};
    for (int kk = 0; kk < K; kk += 32) {
        __syncthreads();
        gload_lds16(gA0, lA0); gload_lds16(gA1, lA1);
        gload_lds16(gB0, lB0); gload_lds16(gB1, lB1);
        gA0 += 32; gA1 += 32; gB0 += 32; gB1 += 32;
        __syncthreads();
        bf16x8 af[4], bfr[4];
        #pragma unroll
        for (int m = 0; m < 4; m++) af[m] = *(const bf16x8*)&As[(wr * 64 + m * 16 + lr) * 32 + lk];
        #pragma unroll
        for (int n = 0; n < 4; n++) bfr[n] = *(const bf16x8*)&Bs[(wc * 64 + n * 16 + lr) * 32 + lk];
        #pragma unroll
        for (int m = 0; m < 4; m++)
            #pragma unroll
            for (int n = 0; n < 4; n++)
                acc[m][n] = __builtin_amdgcn_mfma_f32_16x16x32_bf16(af[m], bfr[n], acc[m][n], 0, 0, 0);
    }
    int rq = (lane >> 4) * 4;
    #pragma unroll
    for (int m = 0; m < 4; m++) {
        int row0 = bm * 128 + wr * 64 + m * 16 + rq;
        #pragma unroll
        for (int n = 0; n < 4; n++) {
            int cb0 = bn * 128 + wc * 64 + n * 16;   // fragment col base (uniform; %16==0)
            int col = cb0 + lr;
            if (MODE == 1) {
                #pragma unroll
                for (int r = 0; r < 4; r++)
                    outF[(size_t)(row0 + r) * N + col] = acc[m][n][r];
            } else if (cb0 < 4096) {
                #pragma unroll
                for (int r = 0; r < 4; r++)
                    zbuf[(size_t)(row0 + r) * DINNER + col] = f2bf(acc[m][n][r]);
            } else if (cb0 < 10240) {
                #pragma unroll
                for (int r = 0; r < 4; r++)
                    xbc[(size_t)(row0 + r) * CONVDIM + (col - 4096)] = f2bf(acc[m][n][r]);
            } else if (cb0 < 10304) {
                #pragma unroll
                for (int r = 0; r < 4; r++)
                    dtraw[(size_t)(row0 + r) * 64 + (col - 10240)] = acc[m][n][r];
            }
        }
    }
}

// ============================================================
// causal depthwise conv1d (K=4) + SiLU: 4 rows x 8 ch per thread
// ============================================================
__global__ void conv_kernel(const ushort* __restrict__ xbc, const float* __restrict__ cw,
                            const float* __restrict__ cb, ushort* __restrict__ convout) {
    int c8 = (blockIdx.x * 256 + threadIdx.x) * 8;   // channel base (grid.x=3 -> 6144 ch)
    int row0 = blockIdx.y * 4;                       // token base (grid.y=1024)
    int t0 = row0 & 2047;                            // within-batch position
    float bias[8];
    {
        float4 b0 = ((const float4*)cb)[c8 / 4];
        float4 b1 = ((const float4*)cb)[c8 / 4 + 1];
        bias[0] = b0.x; bias[1] = b0.y; bias[2] = b0.z; bias[3] = b0.w;
        bias[4] = b1.x; bias[5] = b1.y; bias[6] = b1.z; bias[7] = b1.w;
    }
    float wk[8][4];
    #pragma unroll
    for (int e = 0; e < 8; e++) {
        float4 wv = ((const float4*)cw)[c8 + e];
        wk[e][0] = wv.x; wk[e][1] = wv.y; wk[e][2] = wv.z; wk[e][3] = wv.w;
    }
    float f[7][8];
    #pragma unroll
    for (int j = 0; j < 7; j++) {
        int tt = t0 - 3 + j;
        if (tt >= 0) {
            uint4 v = *(const uint4*)&xbc[(size_t)(row0 - 3 + j) * CONVDIM + c8];
            unpack8(v, f[j]);
        } else {
            #pragma unroll
            for (int e = 0; e < 8; e++) f[j][e] = 0.f;
        }
    }
    #pragma unroll
    for (int r = 0; r < 4; r++) {
        float a[8];
        #pragma unroll
        for (int e = 0; e < 8; e++) {
            a[e] = bias[e];
            #pragma unroll
            for (int k = 0; k < 4; k++) a[e] += f[r + k][e] * wk[e][k];
        }
        uint4 o;
        float s[8];
        #pragma unroll
        for (int e = 0; e < 8; e++) s[e] = a[e] / (1.f + __expf(-a[e]));
        o.x = pk2(s[0], s[1]); o.y = pk2(s[2], s[3]);
        o.z = pk2(s[4], s[5]); o.w = pk2(s[6], s[7]);
        *(uint4*)&convout[(size_t)(row0 + r) * CONVDIM + c8] = o;
    }
}

// ============================================================
// fused: softplus(dtraw+bias) (in place) + per-chunk cumsum of dt*A
// ============================================================
__global__ void cumsum_kernel(float* __restrict__ dtbuf, const float* __restrict__ dt_bias,
                              const float* __restrict__ A_log, float* __restrict__ dAcs) {
    int bi = blockIdx.x;
    int h = bi & 63, cg = bi >> 6;            // cg in [0,16)
    int t = threadIdx.x;
    size_t didx = (size_t)(cg * 256 + t) * 64 + h;
    float x = dtbuf[didx] + dt_bias[h];
    float sp = (x > 20.f) ? x : log1pf(__expf(x));
    dtbuf[didx] = sp;
    float A = -expf(A_log[h]);
    float v = sp * A;
    __shared__ float s[256];
    s[t] = v;
    __syncthreads();
    for (int off = 1; off < 256; off <<= 1) {
        float add = (t >= off) ? s[t - off] : 0.f;
        __syncthreads();
        s[t] += add;
        __syncthreads();
    }
    dAcs[(size_t)bi * 256 + t] = s[t];
}

// ============================================================
// MFMA states: per (cg,h), states[p][n] = sum_s xdt'[s,p] * B[s,n]
// ============================================================
__global__ __launch_bounds__(256) void states_mfma(
    const ushort* __restrict__ convout, const float* __restrict__ dtsp,
    const float* __restrict__ dAcs, float* __restrict__ states) {
    __shared__ ushort BT[128 * 72];   // 18 KB, stride 72 elems
    __shared__ ushort XT[64 * 72];    // 9 KB
    int bi = blockIdx.x;
    int h = bi & 63, cg = bi >> 6;
    int tid = threadIdx.x;
    int rowbase = cg * 256;
    int bcol = 1024 + ((h >> 3) << 7);
    int xcol = ((h >> 3) << 7) + ((h & 1) << 6);
    float dAlast = dAcs[(size_t)bi * 256 + 255];
    int w = tid >> 6, lane = tid & 63, g = lane >> 4, cc = lane & 15;
    f32x4 acc[4][2] = {};
    for (int T = 0; T < 4; T++) {
        __syncthreads();   // previous tile's reads done
        int s = lane;
        int srow = rowbase + T * 64 + s;
        #pragma unroll
        for (int i = 0; i < 4; i++) {
            int n0 = (w + i * 4) * 8;
            uint4 v = *(const uint4*)&convout[(size_t)srow * CONVDIM + bcol + n0];
            ushort us[8];
            us[0] = (ushort)v.x; us[1] = (ushort)(v.x >> 16);
            us[2] = (ushort)v.y; us[3] = (ushort)(v.y >> 16);
            us[4] = (ushort)v.z; us[5] = (ushort)(v.z >> 16);
            us[6] = (ushort)v.w; us[7] = (ushort)(v.w >> 16);
            #pragma unroll
            for (int e = 0; e < 8; e++) BT[(n0 + e) * 72 + s] = us[e];
        }
        float wgt = dtsp[(size_t)srow * 64 + h] * __expf(dAlast - dAcs[(size_t)bi * 256 + T * 64 + s]);
        #pragma unroll
        for (int j = 0; j < 2; j++) {
            int p0 = (w * 2 + j) * 8;
            uint4 v = *(const uint4*)&convout[(size_t)srow * CONVDIM + xcol + p0];
            float f[8]; unpack8(v, f);
            #pragma unroll
            for (int e = 0; e < 8; e++) XT[(p0 + e) * 72 + s] = f2bf(f[e] * wgt);
        }
        __syncthreads();
        bf16x8 af[4][2], bw[2][2];
        #pragma unroll
        for (int m = 0; m < 4; m++)
            #pragma unroll
            for (int kb = 0; kb < 2; kb++)
                af[m][kb] = *(const bf16x8*)&XT[(m * 16 + cc) * 72 + kb * 32 + 8 * g];
        #pragma unroll
        for (int np = 0; np < 2; np++)
            #pragma unroll
            for (int kb = 0; kb < 2; kb++)
                bw[np][kb] = *(const bf16x8*)&BT[(w * 32 + np * 16 + cc) * 72 + kb * 32 + 8 * g];
        #pragma unroll
        for (int m = 0; m < 4; m++)
            #pragma unroll
            for (int np = 0; np < 2; np++) {
                acc[m][np] = __builtin_amdgcn_mfma_f32_16x16x32_bf16(af[m][0], bw[np][0], acc[m][np], 0, 0, 0);
                acc[m][np] = __builtin_amdgcn_mfma_f32_16x16x32_bf16(af[m][1], bw[np][1], acc[m][np], 0, 0, 0);
            }
    }
    size_t base = (size_t)bi * 8192;
    #pragma unroll
    for (int m = 0; m < 4; m++)
        #pragma unroll
        for (int np = 0; np < 2; np++)
            #pragma unroll
            for (int r = 0; r < 4; r++) {
                int p = m * 16 + 4 * g + r;
                int n = w * 32 + np * 16 + cc;
                states[base + (size_t)p * 128 + n] = acc[m][np][r];
            }
}

// ============================================================
// inter-chunk recurrence: 8 chunks PER BATCH, carry resets per batch
// grid 1024 = 128 bh x 8 p-slices; 8x256x4 = 8192 floats (FULL state)
// ============================================================
__global__ void recur_kernel(const float* __restrict__ dAcs, float* __restrict__ states) {
    int blk = blockIdx.x;                 // (b*64+h)*8 + pq
    int pq = blk & 7, bh = blk >> 3;
    int h = bh & 63, b = bh >> 6;
    int tid = threadIdx.x;
    int p = pq * 8 + (tid >> 5);          // [0,64)
    int n0 = (tid & 31) * 4;              // [0,128)
    float4 carry = make_float4(0.f, 0.f, 0.f, 0.f);
    for (int c = 0; c < 8; c++) {
        int bi = (b * 8 + c) * 64 + h;
        float decay = __expf(dAcs[(size_t)bi * 256 + 255]);
        size_t idx = (size_t)bi * 8192 + (size_t)p * 128 + n0;
        float4 tmp = *(const float4*)&states[idx];
        *(float4*)&states[idx] = carry;
        carry.x = carry.x * decay + tmp.x;
        carry.y = carry.y * decay + tmp.y;
        carry.z = carry.z * decay + tmp.z;
        carry.w = carry.w * decay + tmp.w;
    }
}

// ============================================================
// MFMA yscan: per (cg,h) block, Y = Y_diag + Y_off (D*x added in norm).
// ============================================================
__global__ __launch_bounds__(256, 2) void yscan_mfma(
    const ushort* __restrict__ convout, const float* __restrict__ dtsp,
    const float* __restrict__ dAcs, const float* __restrict__ states,
    ushort* __restrict__ y) {
    __shared__ ushort XT[64 * 264];   // xdt^T: XT[p][s], stride 264
    __shared__ ushort PR[64 * 136];   // prev bf16 [p][n], stride 136
    __shared__ ushort PV[4 * 16 * 72];// per-wave P strip
    __shared__ float sdA[256];
    int bi = blockIdx.x;
    int h = bi & 63, cg = bi >> 6;
    int tid = threadIdx.x;
    int rowbase = cg * 256;
    int bcol = 1024 + ((h >> 3) << 7);
    int ccol = 2048 + ((h >> 1) << 7);
    int xcol = ((h >> 3) << 7) + ((h & 1) << 6);

    sdA[tid] = dAcs[(size_t)bi * 256 + tid];
    #pragma unroll
    for (int i = 0; i < 4; i++) {
        int s = i * 64 + (tid & 63);
        float dtv = dtsp[(size_t)(rowbase + s) * 64 + h];
        #pragma unroll
        for (int j = 0; j < 2; j++) {
            int p0 = (((tid >> 6) << 1) + j) << 3;
            uint4 v = *(const uint4*)&convout[(size_t)(rowbase + s) * CONVDIM + xcol + p0];
            float f[8]; unpack8(v, f);
            #pragma unroll
            for (int e = 0; e < 8; e++) XT[(p0 + e) * 264 + s] = f2bf(f[e] * dtv);
        }
    }
    {
        const float* pv = &states[(size_t)bi * 8192];
        #pragma unroll
        for (int i = 0; i < 8; i++) {
            int flat = i * 1024 + tid * 4;
            float4 v = *(const float4*)&pv[flat];
            int p = flat >> 7, n = flat & 127;
            *(uint*)&PR[p * 136 + n]     = pk2(v.x, v.y);
            *(uint*)&PR[p * 136 + n + 2] = pk2(v.z, v.w);
        }
    }
    __syncthreads();

    int w = tid >> 6, lane = tid & 63, g = lane >> 4, c = lane & 15;
    int wbase = w * 64;
    const ushort* Crow0 = &convout[(size_t)(rowbase + wbase + c) * CONVDIM + ccol + 8 * g];

    // ---- Y_off = C . prev^T ----
    f32x4 yac[4][4] = {};
    #pragma unroll
    for (int kb = 0; kb < 4; kb++) {
        bf16x8 pb[4];
        #pragma unroll
        for (int np = 0; np < 4; np++)
            pb[np] = *(const bf16x8*)&PR[(16 * np + c) * 136 + kb * 32 + 8 * g];
        #pragma unroll
        for (int m = 0; m < 4; m++) {
            bf16x8 cf = *(const bf16x8*)&Crow0[(size_t)(m * 16) * CONVDIM + kb * 32];
            #pragma unroll
            for (int np = 0; np < 4; np++)
                yac[m][np] = __builtin_amdgcn_mfma_f32_16x16x32_bf16(cf, pb[np], yac[m][np], 0, 0, 0);
        }
    }
    float al[4][4];
    float Sw = sdA[wbase];
    float eSw = __expf(Sw);
    #pragma unroll
    for (int m = 0; m < 4; m++)
        #pragma unroll
        for (int r = 0; r < 4; r++) {
            float dAl = sdA[wbase + m * 16 + 4 * g + r];
            al[m][r] = __expf(dAl - Sw);
            float el = al[m][r] * eSw;
            #pragma unroll
            for (int np = 0; np < 4; np++) yac[m][np][r] *= el;
        }

    // ---- s-tiles ----
    ushort* pvs = &PV[w * 1152];
    for (int T = 0; T <= w; T++) {
        f32x4 sac[4][4] = {};
        #pragma unroll
        for (int kb = 0; kb < 4; kb++) {
            bf16x8 bb[4];
            #pragma unroll
            for (int np = 0; np < 4; np++)
                bb[np] = *(const bf16x8*)&convout[(size_t)(rowbase + T * 64 + 16 * np + c) * CONVDIM + bcol + kb * 32 + 8 * g];
            #pragma unroll
            for (int m = 0; m < 4; m++) {
                bf16x8 cf = *(const bf16x8*)&Crow0[(size_t)(m * 16) * CONVDIM + kb * 32];
                #pragma unroll
                for (int np = 0; np < 4; np++)
                    sac[m][np] = __builtin_amdgcn_mfma_f32_16x16x32_bf16(cf, bb[np], sac[m][np], 0, 0, 0);
            }
        }
        bf16x8 xb[4][2];
        #pragma unroll
        for (int np = 0; np < 4; np++)
            #pragma unroll
            for (int k2 = 0; k2 < 2; k2++)
                xb[np][k2] = *(const bf16x8*)&XT[(16 * np + c) * 264 + T * 64 + k2 * 32 + 8 * g];
        if (T < w) {
            float ET = sdA[T * 64 + 63];
            float cT = __expf(Sw - ET);
            float bc[4];
            #pragma unroll
            for (int np = 0; np < 4; np++)
                bc[np] = __expf(ET - sdA[T * 64 + 16 * np + c]) * cT;
            #pragma unroll
            for (int m = 0; m < 4; m++) {
                #pragma unroll
                for (int np = 0; np < 4; np++) {
                    float s0 = bc[np];
                    #pragma unroll
                    for (int r = 0; r < 4; r++)
                        pvs[(4 * g + r) * 72 + 16 * np + c] = f2bf(sac[m][np][r] * (al[m][r] * s0));
                }
                bf16x8 pa0 = *(const bf16x8*)&pvs[c * 72 + 8 * g];
                bf16x8 pa1 = *(const bf16x8*)&pvs[c * 72 + 32 + 8 * g];
                #pragma unroll
                for (int np = 0; np < 4; np++) {
                    yac[m][np] = __builtin_amdgcn_mfma_f32_16x16x32_bf16(pa0, xb[np][0], yac[m][np], 0, 0, 0);
                    yac[m][np] = __builtin_amdgcn_mfma_f32_16x16x32_bf16(pa1, xb[np][1], yac[m][np], 0, 0, 0);
                }
            }
        } else {
            #pragma unroll
            for (int m = 0; m < 4; m++) {
                float dal[4];
                #pragma unroll
                for (int r = 0; r < 4; r++) dal[r] = sdA[wbase + m * 16 + 4 * g + r];
                #pragma unroll
                for (int np = 0; np < 4; np++) {
                    int s_loc = w * 64 + 16 * np + c;
                    float dAs = sdA[s_loc];
                    #pragma unroll
                    for (int r = 0; r < 4; r++) {
                        int l_loc = wbase + m * 16 + 4 * g + r;
                        float v = (s_loc <= l_loc) ? sac[m][np][r] * __expf(dal[r] - dAs) : 0.f;
                        pvs[(4 * g + r) * 72 + 16 * np + c] = f2bf(v);
                    }
                }
                bf16x8 pa0 = *(const bf16x8*)&pvs[c * 72 + 8 * g];
                bf16x8 pa1 = *(const bf16x8*)&pvs[c * 72 + 32 + 8 * g];
                #pragma unroll
                for (int np = 0; np < 4; np++) {
                    yac[m][np] = __builtin_amdgcn_mfma_f32_16x16x32_bf16(pa0, xb[np][0], yac[m][np], 0, 0, 0);
                    yac[m][np] = __builtin_amdgcn_mfma_f32_16x16x32_bf16(pa1, xb[np][1], yac[m][np], 0, 0, 0);
                }
            }
        }
    }
    #pragma unroll
    for (int m = 0; m < 4; m++)
        #pragma unroll
        for (int np = 0; np < 4; np++)
            #pragma unroll
            for (int r = 0; r < 4; r++) {
                int l = wbase + m * 16 + 4 * g + r;
                y[(size_t)(rowbase + l) * DINNER + h * 64 + 16 * np + c] = f2bf(yac[m][np][r]);
            }
}

// ============================================================
// gated grouped RMSNorm (in place over y), adds D*x first.
// ============================================================
__global__ void norm_kernel(ushort* __restrict__ y, const ushort* __restrict__ zbuf,
                            const ushort* __restrict__ convout, const float* __restrict__ Dvec,
                            const float* __restrict__ nw) {
    int row = blockIdx.x;                         // token
    int g = blockIdx.y * 4 + (threadIdx.x >> 6);  // group 0..31
    int lane = threadIdx.x & 63;
    int cbase = g * 128 + lane * 2;
    int h = cbase >> 6;
    int p = cbase & 63;
    int xc = ((h >> 3) << 7) + ((h & 1) << 6) + p;
    uint yv = *(const uint*)&y[(size_t)row * DINNER + cbase];
    uint zv = *(const uint*)&zbuf[(size_t)row * DINNER + cbase];
    uint xv = *(const uint*)&convout[(size_t)row * CONVDIM + xc];
    float Dh = Dvec[h];
    float y0 = bflo(yv) + Dh * bflo(xv), y1 = bfhi(yv) + Dh * bfhi(xv);
    float z0 = bflo(zv), z1 = bfhi(zv);
    float v0 = y0 * (z0 / (1.f + __expf(-z0)));
    float v1 = y1 * (z1 / (1.f + __expf(-z1)));
    float ss = v0 * v0 + v1 * v1;
    #pragma unroll
    for (int off = 32; off; off >>= 1) ss += __shfl_xor(ss, off, 64);
    float rstd = rsqrtf(ss * (1.f / 128.f) + 1e-5f);
    v0 *= rstd * nw[cbase];
    v1 *= rstd * nw[cbase + 1];
    *(uint*)&y[(size_t)row * DINNER + cbase] = pk2(v0, v1);
}

// ============================================================
extern "C" void kernel_launch(void* const* d_in, const int* in_sizes, int n_in,
                              void* d_out, int out_size, void* d_ws, size_t ws_size,
                              hipStream_t stream) {
    const float* u       = (const float*)d_in[0];
    const float* W_in    = (const float*)d_in[1];
    const float* conv_w  = (const float*)d_in[2];
    const float* conv_b  = (const float*)d_in[3];
    const float* dt_bias = (const float*)d_in[4];
    const float* A_log   = (const float*)d_in[5];
    const float* Dvec    = (const float*)d_in[6];
    const float* nw      = (const float*)d_in[7];
    const float* W_out   = (const float*)d_in[8];

    // ---- workspace layout (aliased bf16 staging) ----
    char* ws = (char*)d_ws;
    size_t off = 0;
    auto alloc = [&](size_t bytes) { void* p = ws + off; off += (bytes + 255) & ~(size_t)255; return p; };
    ushort* zbuf    = (ushort*)alloc((size_t)LTOT * DINNER * 2);          // 32 MiB
    // shreg: xbc (48 MiB) -> states (32 MiB) -> Wout_bf (16.8 MiB)
    void*   shreg   = alloc((size_t)LTOT * CONVDIM * 2);                  // 48 MiB
    ushort* xbc     = (ushort*)shreg;
    float*  states  = (float*)shreg;
    ushort* Wout_bf = (ushort*)shreg;
    float*  dtbuf   = (float*) alloc((size_t)LTOT * 64 * 4);              // 1 MiB
    // conv region: Win_bf (padded to 10368 rows, 42.5 MiB) -> convout (48 MiB)
    void*   convreg = alloc((size_t)LTOT * CONVDIM * 2);                  // 48 MiB
    ushort* Win_bf  = (ushort*)convreg;
    ushort* convout = (ushort*)convreg;
    float*  dAcs    = (float*) alloc((size_t)1024 * 256 * 4);             // 1 MiB
    // ybuf region: u_bf (16.8 MiB) -> ybuf (32 MiB)
    void*   ybreg   = alloc((size_t)LTOT * DINNER * 2);                   // 32 MiB
    ushort* u_bf    = (ushort*)ybreg;
    ushort* ybuf    = (ushort*)ybreg;

    // bf16 conversions (aliased into dead regions)
    cvt_kernel<<<dim3(8192),  dim3(256), 0, stream>>>(u, u_bf, 2097152);
    cvt_kernel<<<dim3(20608), dim3(256), 0, stream>>>(W_in, Win_bf, 5275648);
    // in_proj (bf16 GEMM, supertile swizzle; grid 81*32=2592)
    gemm_bf16<0><<<dim3(2592), dim3(256), 0, stream>>>(
        u_bf, Win_bf, zbuf, xbc, dtbuf, (float*)nullptr, LTOT, DPROJ, DMODEL, 81);
    // conv + silu (4 rows/thread; overwrites Win_bf region — dead)
    conv_kernel<<<dim3(3, 1024), dim3(256), 0, stream>>>(xbc, conv_w, conv_b, convout);
    // fused softplus + cumsum (grid 16 chunks x 64 heads = 1024)
    cumsum_kernel<<<dim3(1024), dim3(256), 0, stream>>>(dtbuf, dt_bias, A_log, dAcs);
    // chunked scan (states overwrites xbc region — dead after conv)
    states_mfma<<<dim3(1024), dim3(256), 0, stream>>>(convout, dtbuf, dAcs, states);
    recur_kernel<<<dim3(1024), dim3(256), 0, stream>>>(dAcs, states);
    yscan_mfma<<<dim3(1024), dim3(256), 0, stream>>>(convout, dtbuf, dAcs, states, ybuf);
    // W_out -> bf16 (states dead after yscan)
    cvt_kernel<<<dim3(8192), dim3(256), 0, stream>>>(W_out, Wout_bf, 2097152);
    // gated group RMSNorm (in place, adds D*x)
    norm_kernel<<<dim3(4096, 8), dim3(256), 0, stream>>>(ybuf, zbuf, convout, Dvec, nw);
    // out_proj (grid 16*32=512)
    gemm_bf16<1><<<dim3(512), dim3(256), 0, stream>>>(
        ybuf, Wout_bf, (ushort*)nullptr, (ushort*)nullptr, (float*)nullptr,
        (float*)d_out, LTOT, DMODEL, DINNER, 16);
}

// Round 9
// 518.604 us; speedup vs baseline: 10.2315x; 1.0930x over previous
//
#include <hip/hip_runtime.h>
#include <cstdint>
#include <cstddef>

typedef unsigned int uint;
typedef unsigned short ushort;

typedef __bf16 bf16x8 __attribute__((ext_vector_type(8)));
typedef float f32x4 __attribute__((ext_vector_type(4)));

// ---------- bf16 helpers (bit-level) ----------
__device__ __forceinline__ float bflo(uint u) { return __uint_as_float(u << 16); }
__device__ __forceinline__ float bfhi(uint u) { return __uint_as_float(u & 0xffff0000u); }
__device__ __forceinline__ float bf2f(ushort s) { return __uint_as_float(((uint)s) << 16); }
__device__ __forceinline__ ushort f2bf(float f) {
    uint u = __float_as_uint(f);
    u += 0x7fffu + ((u >> 16) & 1u);   // round-to-nearest-even
    return (ushort)(u >> 16);
}
__device__ __forceinline__ uint pk2(float lo, float hi) {
    return (uint)f2bf(lo) | ((uint)f2bf(hi) << 16);
}
__device__ __forceinline__ void unpack8(uint4 v, float* f) {
    f[0] = bflo(v.x); f[1] = bfhi(v.x); f[2] = bflo(v.y); f[3] = bfhi(v.y);
    f[4] = bflo(v.z); f[5] = bfhi(v.z); f[6] = bflo(v.w); f[7] = bfhi(v.w);
}

// async global->LDS, 16B per lane, wave-uniform LDS base (linear dest)
typedef __attribute__((address_space(1))) const unsigned int* as1_cuptr;
typedef __attribute__((address_space(3))) unsigned int* as3_uptr;
__device__ __forceinline__ void gload_lds16(const void* g, void* l) {
    __builtin_amdgcn_global_load_lds((as1_cuptr)g, (as3_uptr)l, 16, 0, 0);
}

// ---------- constants ----------
#define LTOT 4096           // b*l tokens (2 batches x 2048)
#define DMODEL 2048
#define DINNER 4096
#define DSTATE 128
#define NHEADS 64
#define CONVDIM 6144
#define DPROJ 10304
#define CHUNK 256
#define NCHUNK 16           // GLOBAL chunks (8 per batch x 2 batches)

// ============================================================
// fp32 -> bf16 conversion (vectorized)
// ============================================================
__global__ void cvt_kernel(const float* __restrict__ in, ushort* __restrict__ out, int n4) {
    int i = blockIdx.x * 256 + threadIdx.x;
    if (i < n4) {
        float4 v = ((const float4*)in)[i];
        ushort4 o;
        o.x = f2bf(v.x); o.y = f2bf(v.y); o.z = f2bf(v.z); o.w = f2bf(v.w);
        ((ushort4*)out)[i] = o;
    }
}

// ============================================================
// in_proj: 256x256-tile 8-phase GEMM (T2+T3+T4+T5), BK=64 (2 k-panels).
// Out[M=4096][N<=10496] = X[4096][2048] * W[N][2048]^T, scatter epilogue.
// 512 threads = 8 waves (2 wr x 4 wc), wave output 128x64.
// LDS: 2 ring bufs x 2 k-panels x (A 16KB + B 16KB) = 128 KiB.
// Swizzle: y(row,kb)=(row>>1)*128+(row&1)*64+kb ; z = y ^ (((y>>7)&7)<<4)
// applied identically on staging (global-source side) and ds_read side.
// Pipeline: per phase stage 1 panel of tile t+1; vmcnt(4)+barrier at
// phase 0/2 entries only (counted vmcnt — never 0 in loop).
// ============================================================
#define MFMA_OP __builtin_amdgcn_mfma_f32_16x16x32_bf16
#define MM16(MB) do { \
  acc[(MB)+0][0]=MFMA_OP(a0,b0,acc[(MB)+0][0],0,0,0); acc[(MB)+0][1]=MFMA_OP(a0,b1,acc[(MB)+0][1],0,0,0); \
  acc[(MB)+0][2]=MFMA_OP(a0,b2,acc[(MB)+0][2],0,0,0); acc[(MB)+0][3]=MFMA_OP(a0,b3,acc[(MB)+0][3],0,0,0); \
  acc[(MB)+1][0]=MFMA_OP(a1,b0,acc[(MB)+1][0],0,0,0); acc[(MB)+1][1]=MFMA_OP(a1,b1,acc[(MB)+1][1],0,0,0); \
  acc[(MB)+1][2]=MFMA_OP(a1,b2,acc[(MB)+1][2],0,0,0); acc[(MB)+1][3]=MFMA_OP(a1,b3,acc[(MB)+1][3],0,0,0); \
  acc[(MB)+2][0]=MFMA_OP(a2,b0,acc[(MB)+2][0],0,0,0); acc[(MB)+2][1]=MFMA_OP(a2,b1,acc[(MB)+2][1],0,0,0); \
  acc[(MB)+2][2]=MFMA_OP(a2,b2,acc[(MB)+2][2],0,0,0); acc[(MB)+2][3]=MFMA_OP(a2,b3,acc[(MB)+2][3],0,0,0); \
  acc[(MB)+3][0]=MFMA_OP(a3,b0,acc[(MB)+3][0],0,0,0); acc[(MB)+3][1]=MFMA_OP(a3,b1,acc[(MB)+3][1],0,0,0); \
  acc[(MB)+3][2]=MFMA_OP(a3,b2,acc[(MB)+3][2],0,0,0); acc[(MB)+3][3]=MFMA_OP(a3,b3,acc[(MB)+3][3],0,0,0); \
} while (0)

#define RD8(BASE, OFF) (*(const bf16x8*)((BASE) + (OFF)))

__global__ __launch_bounds__(512, 2) void gemm256_in(
    const ushort* __restrict__ X, const ushort* __restrict__ W,
    ushort* __restrict__ zbuf, ushort* __restrict__ xbc, float* __restrict__ dtraw) {
    __shared__ ushort AL[2][16384];   // [buf][2 panels x 8192 elems]
    __shared__ ushort BL[2][16384];
    const int NBN = 41;
    int q = gridDim.x >> 3;                 // 82
    int wg = blockIdx.x;
    int swz = (wg & 7) * q + (wg >> 3);
    int per = NBN * 4;                      // 164
    int sg = swz / per, rr = swz % per;
    int bm = sg * 4 + (rr & 3);
    int bn = rr >> 2;
    int tid = threadIdx.x;
    int lane = tid & 63, w = tid >> 6;
    int wr = w >> 2, wc = w & 3;
    int lr = lane & 15, g = lane >> 4;
    // ds_read base (bytes, swizzled); fragment offsets are all multiples of
    // 1024 so the swizzle bits are offset-invariant.
    int y00 = ((lr >> 1) << 7) | ((lr & 1) << 6) | (g << 4);
    int z00 = y00 ^ (((y00 >> 7) & 7) << 4);
    int aBase = wr * 8192 + z00;            // + kh*16384 + mh*4096 + m*1024
    int bBase = wc * 4096 + z00;            // + kh*16384 + n*1024
    // staging decode: this thread's two 16B slices (issue 0: z=tid*16, issue 1: +8192)
    int z0 = tid * 16, z1 = z0 + 8192;
    int y0 = z0 ^ (((z0 >> 7) & 7) << 4);
    int y1 = z1 ^ (((z1 >> 7) & 7) << 4);
    int row0s = ((y0 >> 7) << 1) | ((y0 >> 6) & 1), kbe0 = (y0 & 63) >> 1;
    int row1s = ((y1 >> 7) << 1) | ((y1 >> 6) & 1), kbe1 = (y1 & 63) >> 1;
    const ushort* gA0 = &X[(size_t)(bm * 256 + row0s) * 2048 + kbe0];
    const ushort* gA1 = &X[(size_t)(bm * 256 + row1s) * 2048 + kbe1];
    const ushort* gB0 = &W[(size_t)(bn * 256 + row0s) * 2048 + kbe0];
    const ushort* gB1 = &W[(size_t)(bn * 256 + row1s) * 2048 + kbe1];
    int wOff = w * 1024;                    // wave-uniform LDS slice (bytes)

#define STAGE(DB, ARR, KP, P0, P1, KO) do { \
    gload_lds16((P0) + (KO) + (KP) * 32, (char*)(ARR) + (DB) * 32768 + (KP) * 16384 + wOff); \
    gload_lds16((P1) + (KO) + (KP) * 32, (char*)(ARR) + (DB) * 32768 + (KP) * 16384 + wOff + 8192); \
} while (0)

    f32x4 acc[8][4] = {};
    // prologue: tile 0's four panels (order fixes vmcnt ages: Ak0,Bk0,Ak1,Bk1)
    STAGE(0, AL, 0, gA0, gA1, 0);
    STAGE(0, BL, 0, gB0, gB1, 0);
    STAGE(0, AL, 1, gA0, gA1, 0);
    STAGE(0, BL, 1, gB0, gB1, 0);

    for (int t = 0; t < 32; ++t) {
        int buf = t & 1, nb = buf ^ 1;
        int ko = ((t + 1) & 31) * 64;       // tail: dummy re-stage of tile 0
        const char* Ab = (const char*)AL + buf * 32768;
        const char* Bb = (const char*)BL + buf * 32768;
        bf16x8 a0, a1, a2, a3, b0, b1, b2, b3;
        // ---- phase (kh0, mh0) ----
        asm volatile("s_waitcnt vmcnt(4)" ::: "memory");
        __builtin_amdgcn_s_barrier();
        __builtin_amdgcn_sched_barrier(0);
        b0 = RD8(Bb, bBase);        b1 = RD8(Bb, bBase + 1024);
        b2 = RD8(Bb, bBase + 2048); b3 = RD8(Bb, bBase + 3072);
        a0 = RD8(Ab, aBase);        a1 = RD8(Ab, aBase + 1024);
        a2 = RD8(Ab, aBase + 2048); a3 = RD8(Ab, aBase + 3072);
        STAGE(nb, AL, 0, gA0, gA1, ko);
        __builtin_amdgcn_s_setprio(1);
        MM16(0);
        __builtin_amdgcn_s_setprio(0);
        __builtin_amdgcn_sched_barrier(0);
        __builtin_amdgcn_s_barrier();
        __builtin_amdgcn_sched_barrier(0);
        // ---- phase (kh0, mh1) ----
        a0 = RD8(Ab, aBase + 4096);        a1 = RD8(Ab, aBase + 4096 + 1024);
        a2 = RD8(Ab, aBase + 4096 + 2048); a3 = RD8(Ab, aBase + 4096 + 3072);
        STAGE(nb, BL, 0, gB0, gB1, ko);
        __builtin_amdgcn_s_setprio(1);
        MM16(4);
        __builtin_amdgcn_s_setprio(0);
        // ---- phase (kh1, mh0) ----
        asm volatile("s_waitcnt vmcnt(4)" ::: "memory");
        __builtin_amdgcn_s_barrier();
        __builtin_amdgcn_sched_barrier(0);
        b0 = RD8(Bb, bBase + 16384);        b1 = RD8(Bb, bBase + 16384 + 1024);
        b2 = RD8(Bb, bBase + 16384 + 2048); b3 = RD8(Bb, bBase + 16384 + 3072);
        a0 = RD8(Ab, aBase + 16384);        a1 = RD8(Ab, aBase + 16384 + 1024);
        a2 = RD8(Ab, aBase + 16384 + 2048); a3 = RD8(Ab, aBase + 16384 + 3072);
        STAGE(nb, AL, 1, gA0, gA1, ko);
        __builtin_amdgcn_s_setprio(1);
        MM16(0);
        __builtin_amdgcn_s_setprio(0);
        __builtin_amdgcn_sched_barrier(0);
        __builtin_amdgcn_s_barrier();
        __builtin_amdgcn_sched_barrier(0);
        // ---- phase (kh1, mh1) ----
        a0 = RD8(Ab, aBase + 16384 + 4096);        a1 = RD8(Ab, aBase + 16384 + 4096 + 1024);
        a2 = RD8(Ab, aBase + 16384 + 4096 + 2048); a3 = RD8(Ab, aBase + 16384 + 4096 + 3072);
        STAGE(nb, BL, 1, gB0, gB1, ko);
        __builtin_amdgcn_s_setprio(1);
        MM16(4);
        __builtin_amdgcn_s_setprio(0);
    }
    asm volatile("s_waitcnt vmcnt(0)" ::: "memory");

    // ---- scatter epilogue (C-layout: row = mf*16 + g*4 + r, col = n*16 + lr) ----
    int rq = g * 4;
    #pragma unroll
    for (int mf = 0; mf < 8; mf++) {
        int row0 = bm * 256 + wr * 128 + mf * 16 + rq;
        #pragma unroll
        for (int n = 0; n < 4; n++) {
            int cb0 = bn * 256 + wc * 64 + n * 16;   // uniform; %16==0
            int col = cb0 + lr;
            if (cb0 < 4096) {
                #pragma unroll
                for (int r = 0; r < 4; r++)
                    zbuf[(size_t)(row0 + r) * DINNER + col] = f2bf(acc[mf][n][r]);
            } else if (cb0 < 10240) {
                #pragma unroll
                for (int r = 0; r < 4; r++)
                    xbc[(size_t)(row0 + r) * CONVDIM + (col - 4096)] = f2bf(acc[mf][n][r]);
            } else if (cb0 < 10304) {
                #pragma unroll
                for (int r = 0; r < 4; r++)
                    dtraw[(size_t)(row0 + r) * 64 + (col - 10240)] = acc[mf][n][r];
            }
        }
    }
}
#undef STAGE

// ============================================================
// out_proj: 128x128-tile 2-phase GEMM (proven path; 512 blocks = 2/CU)
// ============================================================
__global__ __launch_bounds__(256) void gemm_bf16_out(
    const ushort* __restrict__ X, const ushort* __restrict__ W,
    float* __restrict__ outF, int M, int N, int K, int NB) {
    __shared__ ushort As[128 * 32];
    __shared__ ushort Bs[128 * 32];
    int q = gridDim.x >> 3;
    int wg = blockIdx.x;
    int swz = (wg & 7) * q + (wg >> 3);
    int per = NB * 4;
    int sg = swz / per, rr = swz % per;
    int bm = sg * 4 + (rr & 3);
    int bn = rr >> 2;
    int tid = threadIdx.x;
    int lane = tid & 63, w = tid >> 6;
    int wr = w >> 1, wc = w & 1;
    int lr = lane & 15, lk = (lane >> 4) * 8;
    int r0 = lane >> 2;
    int ce = (lane & 3) * 8;
    const ushort* gA0 = &X[(size_t)(bm * 128 + (w * 2 + 0) * 16 + r0) * K + ce];
    const ushort* gA1 = &X[(size_t)(bm * 128 + (w * 2 + 1) * 16 + r0) * K + ce];
    const ushort* gB0 = &W[(size_t)(bn * 128 + (w * 2 + 0) * 16 + r0) * K + ce];
    const ushort* gB1 = &W[(size_t)(bn * 128 + (w * 2 + 1) * 16 + r0) * K + ce];
    ushort* lA0 = &As[(w * 2 + 0) * 512];
    ushort* lA1 = &As[(w * 2 + 1) * 512];
    ushort* lB0 = &Bs[(w * 2 + 0) * 512];
    ushort* lB1 = &Bs[(w * 2 + 1) * 512];
    f32x4 acc[4][4] = {};
    for (int kk = 0; kk < K; kk += 32) {
        __syncthreads();
        gload_lds16(gA0, lA0); gload_lds16(gA1, lA1);
        gload_lds16(gB0, lB0); gload_lds16(gB1, lB1);
        gA0 += 32; gA1 += 32; gB0 += 32; gB1 += 32;
        __syncthreads();
        bf16x8 af[4], bfr[4];
        #pragma unroll
        for (int m = 0; m < 4; m++) af[m] = *(const bf16x8*)&As[(wr * 64 + m * 16 + lr) * 32 + lk];
        #pragma unroll
        for (int n = 0; n < 4; n++) bfr[n] = *(const bf16x8*)&Bs[(wc * 64 + n * 16 + lr) * 32 + lk];
        #pragma unroll
        for (int m = 0; m < 4; m++)
            #pragma unroll
            for (int n = 0; n < 4; n++)
                acc[m][n] = MFMA_OP(af[m], bfr[n], acc[m][n], 0, 0, 0);
    }
    int rq = (lane >> 4) * 4;
    #pragma unroll
    for (int m = 0; m < 4; m++) {
        int row0 = bm * 128 + wr * 64 + m * 16 + rq;
        #pragma unroll
        for (int n = 0; n < 4; n++) {
            int col = bn * 128 + wc * 64 + n * 16 + lr;
            #pragma unroll
            for (int r = 0; r < 4; r++)
                outF[(size_t)(row0 + r) * N + col] = acc[m][n][r];
        }
    }
}

// ============================================================
// causal depthwise conv1d (K=4) + SiLU: 4 rows x 8 ch per thread
// ============================================================
__global__ void conv_kernel(const ushort* __restrict__ xbc, const float* __restrict__ cw,
                            const float* __restrict__ cb, ushort* __restrict__ convout) {
    int c8 = (blockIdx.x * 256 + threadIdx.x) * 8;   // channel base (grid.x=3 -> 6144 ch)
    int row0 = blockIdx.y * 4;                       // token base (grid.y=1024)
    int t0 = row0 & 2047;                            // within-batch position
    float bias[8];
    {
        float4 b0 = ((const float4*)cb)[c8 / 4];
        float4 b1 = ((const float4*)cb)[c8 / 4 + 1];
        bias[0] = b0.x; bias[1] = b0.y; bias[2] = b0.z; bias[3] = b0.w;
        bias[4] = b1.x; bias[5] = b1.y; bias[6] = b1.z; bias[7] = b1.w;
    }
    float wk[8][4];
    #pragma unroll
    for (int e = 0; e < 8; e++) {
        float4 wv = ((const float4*)cw)[c8 + e];
        wk[e][0] = wv.x; wk[e][1] = wv.y; wk[e][2] = wv.z; wk[e][3] = wv.w;
    }
    float f[7][8];
    #pragma unroll
    for (int j = 0; j < 7; j++) {
        int tt = t0 - 3 + j;
        if (tt >= 0) {
            uint4 v = *(const uint4*)&xbc[(size_t)(row0 - 3 + j) * CONVDIM + c8];
            unpack8(v, f[j]);
        } else {
            #pragma unroll
            for (int e = 0; e < 8; e++) f[j][e] = 0.f;
        }
    }
    #pragma unroll
    for (int r = 0; r < 4; r++) {
        float a[8];
        #pragma unroll
        for (int e = 0; e < 8; e++) {
            a[e] = bias[e];
            #pragma unroll
            for (int k = 0; k < 4; k++) a[e] += f[r + k][e] * wk[e][k];
        }
        uint4 o;
        float s[8];
        #pragma unroll
        for (int e = 0; e < 8; e++) s[e] = a[e] / (1.f + __expf(-a[e]));
        o.x = pk2(s[0], s[1]); o.y = pk2(s[2], s[3]);
        o.z = pk2(s[4], s[5]); o.w = pk2(s[6], s[7]);
        *(uint4*)&convout[(size_t)(row0 + r) * CONVDIM + c8] = o;
    }
}

// ============================================================
// fused: softplus(dtraw+bias) (in place) + per-chunk cumsum of dt*A
// ============================================================
__global__ void cumsum_kernel(float* __restrict__ dtbuf, const float* __restrict__ dt_bias,
                              const float* __restrict__ A_log, float* __restrict__ dAcs) {
    int bi = blockIdx.x;
    int h = bi & 63, cg = bi >> 6;            // cg in [0,16)
    int t = threadIdx.x;
    size_t didx = (size_t)(cg * 256 + t) * 64 + h;
    float x = dtbuf[didx] + dt_bias[h];
    float sp = (x > 20.f) ? x : log1pf(__expf(x));
    dtbuf[didx] = sp;
    float A = -expf(A_log[h]);
    float v = sp * A;
    __shared__ float s[256];
    s[t] = v;
    __syncthreads();
    for (int off = 1; off < 256; off <<= 1) {
        float add = (t >= off) ? s[t - off] : 0.f;
        __syncthreads();
        s[t] += add;
        __syncthreads();
    }
    dAcs[(size_t)bi * 256 + t] = s[t];
}

// ============================================================
// MFMA states: per (cg,h), states[p][n] = sum_s xdt'[s,p] * B[s,n]
// ============================================================
__global__ __launch_bounds__(256) void states_mfma(
    const ushort* __restrict__ convout, const float* __restrict__ dtsp,
    const float* __restrict__ dAcs, float* __restrict__ states) {
    __shared__ ushort BT[128 * 72];   // 18 KB, stride 72 elems
    __shared__ ushort XT[64 * 72];    // 9 KB
    int bi = blockIdx.x;
    int h = bi & 63, cg = bi >> 6;
    int tid = threadIdx.x;
    int rowbase = cg * 256;
    int bcol = 1024 + ((h >> 3) << 7);
    int xcol = ((h >> 3) << 7) + ((h & 1) << 6);
    float dAlast = dAcs[(size_t)bi * 256 + 255];
    int w = tid >> 6, lane = tid & 63, g = lane >> 4, cc = lane & 15;
    f32x4 acc[4][2] = {};
    for (int T = 0; T < 4; T++) {
        __syncthreads();   // previous tile's reads done
        int s = lane;
        int srow = rowbase + T * 64 + s;
        #pragma unroll
        for (int i = 0; i < 4; i++) {
            int n0 = (w + i * 4) * 8;
            uint4 v = *(const uint4*)&convout[(size_t)srow * CONVDIM + bcol + n0];
            ushort us[8];
            us[0] = (ushort)v.x; us[1] = (ushort)(v.x >> 16);
            us[2] = (ushort)v.y; us[3] = (ushort)(v.y >> 16);
            us[4] = (ushort)v.z; us[5] = (ushort)(v.z >> 16);
            us[6] = (ushort)v.w; us[7] = (ushort)(v.w >> 16);
            #pragma unroll
            for (int e = 0; e < 8; e++) BT[(n0 + e) * 72 + s] = us[e];
        }
        float wgt = dtsp[(size_t)srow * 64 + h] * __expf(dAlast - dAcs[(size_t)bi * 256 + T * 64 + s]);
        #pragma unroll
        for (int j = 0; j < 2; j++) {
            int p0 = (w * 2 + j) * 8;
            uint4 v = *(const uint4*)&convout[(size_t)srow * CONVDIM + xcol + p0];
            float f[8]; unpack8(v, f);
            #pragma unroll
            for (int e = 0; e < 8; e++) XT[(p0 + e) * 72 + s] = f2bf(f[e] * wgt);
        }
        __syncthreads();
        bf16x8 af[4][2], bw[2][2];
        #pragma unroll
        for (int m = 0; m < 4; m++)
            #pragma unroll
            for (int kb = 0; kb < 2; kb++)
                af[m][kb] = *(const bf16x8*)&XT[(m * 16 + cc) * 72 + kb * 32 + 8 * g];
        #pragma unroll
        for (int np = 0; np < 2; np++)
            #pragma unroll
            for (int kb = 0; kb < 2; kb++)
                bw[np][kb] = *(const bf16x8*)&BT[(w * 32 + np * 16 + cc) * 72 + kb * 32 + 8 * g];
        #pragma unroll
        for (int m = 0; m < 4; m++)
            #pragma unroll
            for (int np = 0; np < 2; np++) {
                acc[m][np] = MFMA_OP(af[m][0], bw[np][0], acc[m][np], 0, 0, 0);
                acc[m][np] = MFMA_OP(af[m][1], bw[np][1], acc[m][np], 0, 0, 0);
            }
    }
    size_t base = (size_t)bi * 8192;
    #pragma unroll
    for (int m = 0; m < 4; m++)
        #pragma unroll
        for (int np = 0; np < 2; np++)
            #pragma unroll
            for (int r = 0; r < 4; r++) {
                int p = m * 16 + 4 * g + r;
                int n = w * 32 + np * 16 + cc;
                states[base + (size_t)p * 128 + n] = acc[m][np][r];
            }
}

// ============================================================
// inter-chunk recurrence: 8 chunks PER BATCH, carry resets per batch
// grid 1024 = 128 bh x 8 p-slices; 8x256x4 = 8192 floats (FULL state)
// ============================================================
__global__ void recur_kernel(const float* __restrict__ dAcs, float* __restrict__ states) {
    int blk = blockIdx.x;                 // (b*64+h)*8 + pq
    int pq = blk & 7, bh = blk >> 3;
    int h = bh & 63, b = bh >> 6;
    int tid = threadIdx.x;
    int p = pq * 8 + (tid >> 5);          // [0,64)
    int n0 = (tid & 31) * 4;              // [0,128)
    float4 carry = make_float4(0.f, 0.f, 0.f, 0.f);
    for (int c = 0; c < 8; c++) {
        int bi = (b * 8 + c) * 64 + h;
        float decay = __expf(dAcs[(size_t)bi * 256 + 255]);
        size_t idx = (size_t)bi * 8192 + (size_t)p * 128 + n0;
        float4 tmp = *(const float4*)&states[idx];
        *(float4*)&states[idx] = carry;
        carry.x = carry.x * decay + tmp.x;
        carry.y = carry.y * decay + tmp.y;
        carry.z = carry.z * decay + tmp.z;
        carry.w = carry.w * decay + tmp.w;
    }
}

// ============================================================
// MFMA yscan: per (cg,h) block, Y = Y_diag + Y_off (D*x added in norm).
// ============================================================
__global__ __launch_bounds__(256, 2) void yscan_mfma(
    const ushort* __restrict__ convout, const float* __restrict__ dtsp,
    const float* __restrict__ dAcs, const float* __restrict__ states,
    ushort* __restrict__ y) {
    __shared__ ushort XT[64 * 264];   // xdt^T: XT[p][s], stride 264
    __shared__ ushort PR[64 * 136];   // prev bf16 [p][n], stride 136
    __shared__ ushort PV[4 * 16 * 72];// per-wave P strip
    __shared__ float sdA[256];
    int bi = blockIdx.x;
    int h = bi & 63, cg = bi >> 6;
    int tid = threadIdx.x;
    int rowbase = cg * 256;
    int bcol = 1024 + ((h >> 3) << 7);
    int ccol = 2048 + ((h >> 1) << 7);
    int xcol = ((h >> 3) << 7) + ((h & 1) << 6);

    sdA[tid] = dAcs[(size_t)bi * 256 + tid];
    #pragma unroll
    for (int i = 0; i < 4; i++) {
        int s = i * 64 + (tid & 63);
        float dtv = dtsp[(size_t)(rowbase + s) * 64 + h];
        #pragma unroll
        for (int j = 0; j < 2; j++) {
            int p0 = (((tid >> 6) << 1) + j) << 3;
            uint4 v = *(const uint4*)&convout[(size_t)(rowbase + s) * CONVDIM + xcol + p0];
            float f[8]; unpack8(v, f);
            #pragma unroll
            for (int e = 0; e < 8; e++) XT[(p0 + e) * 264 + s] = f2bf(f[e] * dtv);
        }
    }
    {
        const float* pv = &states[(size_t)bi * 8192];
        #pragma unroll
        for (int i = 0; i < 8; i++) {
            int flat = i * 1024 + tid * 4;
            float4 v = *(const float4*)&pv[flat];
            int p = flat >> 7, n = flat & 127;
            *(uint*)&PR[p * 136 + n]     = pk2(v.x, v.y);
            *(uint*)&PR[p * 136 + n + 2] = pk2(v.z, v.w);
        }
    }
    __syncthreads();

    int w = tid >> 6, lane = tid & 63, g = lane >> 4, c = lane & 15;
    int wbase = w * 64;
    const ushort* Crow0 = &convout[(size_t)(rowbase + wbase + c) * CONVDIM + ccol + 8 * g];

    // ---- Y_off = C . prev^T ----
    f32x4 yac[4][4] = {};
    #pragma unroll
    for (int kb = 0; kb < 4; kb++) {
        bf16x8 pb[4];
        #pragma unroll
        for (int np = 0; np < 4; np++)
            pb[np] = *(const bf16x8*)&PR[(16 * np + c) * 136 + kb * 32 + 8 * g];
        #pragma unroll
        for (int m = 0; m < 4; m++) {
            bf16x8 cf = *(const bf16x8*)&Crow0[(size_t)(m * 16) * CONVDIM + kb * 32];
            #pragma unroll
            for (int np = 0; np < 4; np++)
                yac[m][np] = MFMA_OP(cf, pb[np], yac[m][np], 0, 0, 0);
        }
    }
    float al[4][4];
    float Sw = sdA[wbase];
    float eSw = __expf(Sw);
    #pragma unroll
    for (int m = 0; m < 4; m++)
        #pragma unroll
        for (int r = 0; r < 4; r++) {
            float dAl = sdA[wbase + m * 16 + 4 * g + r];
            al[m][r] = __expf(dAl - Sw);
            float el = al[m][r] * eSw;
            #pragma unroll
            for (int np = 0; np < 4; np++) yac[m][np][r] *= el;
        }

    // ---- s-tiles ----
    ushort* pvs = &PV[w * 1152];
    for (int T = 0; T <= w; T++) {
        f32x4 sac[4][4] = {};
        #pragma unroll
        for (int kb = 0; kb < 4; kb++) {
            bf16x8 bb[4];
            #pragma unroll
            for (int np = 0; np < 4; np++)
                bb[np] = *(const bf16x8*)&convout[(size_t)(rowbase + T * 64 + 16 * np + c) * CONVDIM + bcol + kb * 32 + 8 * g];
            #pragma unroll
            for (int m = 0; m < 4; m++) {
                bf16x8 cf = *(const bf16x8*)&Crow0[(size_t)(m * 16) * CONVDIM + kb * 32];
                #pragma unroll
                for (int np = 0; np < 4; np++)
                    sac[m][np] = MFMA_OP(cf, bb[np], sac[m][np], 0, 0, 0);
            }
        }
        bf16x8 xb[4][2];
        #pragma unroll
        for (int np = 0; np < 4; np++)
            #pragma unroll
            for (int k2 = 0; k2 < 2; k2++)
                xb[np][k2] = *(const bf16x8*)&XT[(16 * np + c) * 264 + T * 64 + k2 * 32 + 8 * g];
        if (T < w) {
            float ET = sdA[T * 64 + 63];
            float cT = __expf(Sw - ET);
            float bc[4];
            #pragma unroll
            for (int np = 0; np < 4; np++)
                bc[np] = __expf(ET - sdA[T * 64 + 16 * np + c]) * cT;
            #pragma unroll
            for (int m = 0; m < 4; m++) {
                #pragma unroll
                for (int np = 0; np < 4; np++) {
                    float s0 = bc[np];
                    #pragma unroll
                    for (int r = 0; r < 4; r++)
                        pvs[(4 * g + r) * 72 + 16 * np + c] = f2bf(sac[m][np][r] * (al[m][r] * s0));
                }
                bf16x8 pa0 = *(const bf16x8*)&pvs[c * 72 + 8 * g];
                bf16x8 pa1 = *(const bf16x8*)&pvs[c * 72 + 32 + 8 * g];
                #pragma unroll
                for (int np = 0; np < 4; np++) {
                    yac[m][np] = MFMA_OP(pa0, xb[np][0], yac[m][np], 0, 0, 0);
                    yac[m][np] = MFMA_OP(pa1, xb[np][1], yac[m][np], 0, 0, 0);
                }
            }
        } else {
            #pragma unroll
            for (int m = 0; m < 4; m++) {
                float dal[4];
                #pragma unroll
                for (int r = 0; r < 4; r++) dal[r] = sdA[wbase + m * 16 + 4 * g + r];
                #pragma unroll
                for (int np = 0; np < 4; np++) {
                    int s_loc = w * 64 + 16 * np + c;
                    float dAs = sdA[s_loc];
                    #pragma unroll
                    for (int r = 0; r < 4; r++) {
                        int l_loc = wbase + m * 16 + 4 * g + r;
                        float v = (s_loc <= l_loc) ? sac[m][np][r] * __expf(dal[r] - dAs) : 0.f;
                        pvs[(4 * g + r) * 72 + 16 * np + c] = f2bf(v);
                    }
                }
                bf16x8 pa0 = *(const bf16x8*)&pvs[c * 72 + 8 * g];
                bf16x8 pa1 = *(const bf16x8*)&pvs[c * 72 + 32 + 8 * g];
                #pragma unroll
                for (int np = 0; np < 4; np++) {
                    yac[m][np] = MFMA_OP(pa0, xb[np][0], yac[m][np], 0, 0, 0);
                    yac[m][np] = MFMA_OP(pa1, xb[np][1], yac[m][np], 0, 0, 0);
                }
            }
        }
    }
    #pragma unroll
    for (int m = 0; m < 4; m++)
        #pragma unroll
        for (int np = 0; np < 4; np++)
            #pragma unroll
            for (int r = 0; r < 4; r++) {
                int l = wbase + m * 16 + 4 * g + r;
                y[(size_t)(rowbase + l) * DINNER + h * 64 + 16 * np + c] = f2bf(yac[m][np][r]);
            }
}

// ============================================================
// gated grouped RMSNorm (in place over y), adds D*x first.
// ============================================================
__global__ void norm_kernel(ushort* __restrict__ y, const ushort* __restrict__ zbuf,
                            const ushort* __restrict__ convout, const float* __restrict__ Dvec,
                            const float* __restrict__ nw) {
    int row = blockIdx.x;                         // token
    int g = blockIdx.y * 4 + (threadIdx.x >> 6);  // group 0..31
    int lane = threadIdx.x & 63;
    int cbase = g * 128 + lane * 2;
    int h = cbase >> 6;
    int p = cbase & 63;
    int xc = ((h >> 3) << 7) + ((h & 1) << 6) + p;
    uint yv = *(const uint*)&y[(size_t)row * DINNER + cbase];
    uint zv = *(const uint*)&zbuf[(size_t)row * DINNER + cbase];
    uint xv = *(const uint*)&convout[(size_t)row * CONVDIM + xc];
    float Dh = Dvec[h];
    float y0 = bflo(yv) + Dh * bflo(xv), y1 = bfhi(yv) + Dh * bfhi(xv);
    float z0 = bflo(zv), z1 = bfhi(zv);
    float v0 = y0 * (z0 / (1.f + __expf(-z0)));
    float v1 = y1 * (z1 / (1.f + __expf(-z1)));
    float ss = v0 * v0 + v1 * v1;
    #pragma unroll
    for (int off = 32; off; off >>= 1) ss += __shfl_xor(ss, off, 64);
    float rstd = rsqrtf(ss * (1.f / 128.f) + 1e-5f);
    v0 *= rstd * nw[cbase];
    v1 *= rstd * nw[cbase + 1];
    *(uint*)&y[(size_t)row * DINNER + cbase] = pk2(v0, v1);
}

// ============================================================
extern "C" void kernel_launch(void* const* d_in, const int* in_sizes, int n_in,
                              void* d_out, int out_size, void* d_ws, size_t ws_size,
                              hipStream_t stream) {
    const float* u       = (const float*)d_in[0];
    const float* W_in    = (const float*)d_in[1];
    const float* conv_w  = (const float*)d_in[2];
    const float* conv_b  = (const float*)d_in[3];
    const float* dt_bias = (const float*)d_in[4];
    const float* A_log   = (const float*)d_in[5];
    const float* Dvec    = (const float*)d_in[6];
    const float* nw      = (const float*)d_in[7];
    const float* W_out   = (const float*)d_in[8];

    // ---- workspace layout (aliased bf16 staging) ----
    char* ws = (char*)d_ws;
    size_t off = 0;
    auto alloc = [&](size_t bytes) { void* p = ws + off; off += (bytes + 255) & ~(size_t)255; return p; };
    ushort* zbuf    = (ushort*)alloc((size_t)LTOT * DINNER * 2);          // 32 MiB
    // shreg: xbc (48 MiB) -> states (32 MiB) -> Wout_bf (16.8 MiB)
    void*   shreg   = alloc((size_t)LTOT * CONVDIM * 2);                  // 48 MiB
    ushort* xbc     = (ushort*)shreg;
    float*  states  = (float*)shreg;
    ushort* Wout_bf = (ushort*)shreg;
    float*  dtbuf   = (float*) alloc((size_t)LTOT * 64 * 4);              // 1 MiB
    // conv region: Win_bf (padded to 10496 rows, 43 MiB) -> convout (48 MiB)
    void*   convreg = alloc((size_t)LTOT * CONVDIM * 2);                  // 48 MiB
    ushort* Win_bf  = (ushort*)convreg;
    ushort* convout = (ushort*)convreg;
    float*  dAcs    = (float*) alloc((size_t)1024 * 256 * 4);             // 1 MiB
    // ybuf region: u_bf (16.8 MiB) -> ybuf (32 MiB)
    void*   ybreg   = alloc((size_t)LTOT * DINNER * 2);                   // 32 MiB
    ushort* u_bf    = (ushort*)ybreg;
    ushort* ybuf    = (ushort*)ybreg;

    // bf16 conversions (aliased into dead regions)
    cvt_kernel<<<dim3(8192),  dim3(256), 0, stream>>>(u, u_bf, 2097152);
    cvt_kernel<<<dim3(20608), dim3(256), 0, stream>>>(W_in, Win_bf, 5275648);
    // in_proj: 256^2 8-phase kernel; grid 16 bm x 41 bn = 656 (%8==0)
    gemm256_in<<<dim3(656), dim3(512), 0, stream>>>(u_bf, Win_bf, zbuf, xbc, dtbuf);
    // conv + silu (4 rows/thread; overwrites Win_bf region — dead)
    conv_kernel<<<dim3(3, 1024), dim3(256), 0, stream>>>(xbc, conv_w, conv_b, convout);
    // fused softplus + cumsum (grid 16 chunks x 64 heads = 1024)
    cumsum_kernel<<<dim3(1024), dim3(256), 0, stream>>>(dtbuf, dt_bias, A_log, dAcs);
    // chunked scan (states overwrites xbc region — dead after conv)
    states_mfma<<<dim3(1024), dim3(256), 0, stream>>>(convout, dtbuf, dAcs, states);
    recur_kernel<<<dim3(1024), dim3(256), 0, stream>>>(dAcs, states);
    yscan_mfma<<<dim3(1024), dim3(256), 0, stream>>>(convout, dtbuf, dAcs, states, ybuf);
    // W_out -> bf16 (states dead after yscan)
    cvt_kernel<<<dim3(8192), dim3(256), 0, stream>>>(W_out, Wout_bf, 2097152);
    // gated group RMSNorm (in place, adds D*x)
    norm_kernel<<<dim3(4096, 8), dim3(256), 0, stream>>>(ybuf, zbuf, convout, Dvec, nw);
    // out_proj (grid 16*4=... 16 bm x 16 bn = 512, %8==0)
    gemm_bf16_out<<<dim3(512), dim3(256), 0, stream>>>(
        ybuf, Wout_bf, (float*)d_out, LTOT, DMODEL, DINNER, 16);
}

// Round 10
// 498.728 us; speedup vs baseline: 10.6393x; 1.0399x over previous
//
#include <hip/hip_runtime.h>
#include <cstdint>
#include <cstddef>

typedef unsigned int uint;
typedef unsigned short ushort;

typedef __bf16 bf16x8 __attribute__((ext_vector_type(8)));
typedef float f32x4 __attribute__((ext_vector_type(4)));

// ---------- bf16 helpers (bit-level) ----------
__device__ __forceinline__ float bflo(uint u) { return __uint_as_float(u << 16); }
__device__ __forceinline__ float bfhi(uint u) { return __uint_as_float(u & 0xffff0000u); }
__device__ __forceinline__ float bf2f(ushort s) { return __uint_as_float(((uint)s) << 16); }
__device__ __forceinline__ ushort f2bf(float f) {
    uint u = __float_as_uint(f);
    u += 0x7fffu + ((u >> 16) & 1u);   // round-to-nearest-even
    return (ushort)(u >> 16);
}
__device__ __forceinline__ uint pk2(float lo, float hi) {
    return (uint)f2bf(lo) | ((uint)f2bf(hi) << 16);
}
__device__ __forceinline__ void unpack8(uint4 v, float* f) {
    f[0] = bflo(v.x); f[1] = bfhi(v.x); f[2] = bflo(v.y); f[3] = bfhi(v.y);
    f[4] = bflo(v.z); f[5] = bfhi(v.z); f[6] = bflo(v.w); f[7] = bfhi(v.w);
}

// async global->LDS, 16B per lane, wave-uniform LDS base (linear dest)
typedef __attribute__((address_space(1))) const unsigned int* as1_cuptr;
typedef __attribute__((address_space(3))) unsigned int* as3_uptr;
__device__ __forceinline__ void gload_lds16(const void* g, void* l) {
    __builtin_amdgcn_global_load_lds((as1_cuptr)g, (as3_uptr)l, 16, 0, 0);
}

// ---------- constants ----------
#define LTOT 4096           // b*l tokens (2 batches x 2048)
#define DMODEL 2048
#define DINNER 4096
#define DSTATE 128
#define NHEADS 64
#define CONVDIM 6144
#define DPROJ 10304
#define CHUNK 256
#define NCHUNK 16           // GLOBAL chunks (8 per batch x 2 batches)

// ============================================================
// fp32 -> bf16 conversion (vectorized)
// ============================================================
__global__ void cvt_kernel(const float* __restrict__ in, ushort* __restrict__ out, int n4) {
    int i = blockIdx.x * 256 + threadIdx.x;
    if (i < n4) {
        float4 v = ((const float4*)in)[i];
        ushort4 o;
        o.x = f2bf(v.x); o.y = f2bf(v.y); o.z = f2bf(v.z); o.w = f2bf(v.w);
        ((ushort4*)out)[i] = o;
    }
}

// ============================================================
// in_proj: 256x256-tile 8-phase GEMM (T2+T3+T4+T5), BK=64 (2 k-panels).
// (unchanged from round 9 — verified: 0 bank conflicts, absmax 0.039)
// ============================================================
#define MFMA_OP __builtin_amdgcn_mfma_f32_16x16x32_bf16
#define MM16(MB) do { \
  acc[(MB)+0][0]=MFMA_OP(a0,b0,acc[(MB)+0][0],0,0,0); acc[(MB)+0][1]=MFMA_OP(a0,b1,acc[(MB)+0][1],0,0,0); \
  acc[(MB)+0][2]=MFMA_OP(a0,b2,acc[(MB)+0][2],0,0,0); acc[(MB)+0][3]=MFMA_OP(a0,b3,acc[(MB)+0][3],0,0,0); \
  acc[(MB)+1][0]=MFMA_OP(a1,b0,acc[(MB)+1][0],0,0,0); acc[(MB)+1][1]=MFMA_OP(a1,b1,acc[(MB)+1][1],0,0,0); \
  acc[(MB)+1][2]=MFMA_OP(a1,b2,acc[(MB)+1][2],0,0,0); acc[(MB)+1][3]=MFMA_OP(a1,b3,acc[(MB)+1][3],0,0,0); \
  acc[(MB)+2][0]=MFMA_OP(a2,b0,acc[(MB)+2][0],0,0,0); acc[(MB)+2][1]=MFMA_OP(a2,b1,acc[(MB)+2][1],0,0,0); \
  acc[(MB)+2][2]=MFMA_OP(a2,b2,acc[(MB)+2][2],0,0,0); acc[(MB)+2][3]=MFMA_OP(a2,b3,acc[(MB)+2][3],0,0,0); \
  acc[(MB)+3][0]=MFMA_OP(a3,b0,acc[(MB)+3][0],0,0,0); acc[(MB)+3][1]=MFMA_OP(a3,b1,acc[(MB)+3][1],0,0,0); \
  acc[(MB)+3][2]=MFMA_OP(a3,b2,acc[(MB)+3][2],0,0,0); acc[(MB)+3][3]=MFMA_OP(a3,b3,acc[(MB)+3][3],0,0,0); \
} while (0)

#define RD8(BASE, OFF) (*(const bf16x8*)((BASE) + (OFF)))

__global__ __launch_bounds__(512, 2) void gemm256_in(
    const ushort* __restrict__ X, const ushort* __restrict__ W,
    ushort* __restrict__ zbuf, ushort* __restrict__ xbc, float* __restrict__ dtraw) {
    __shared__ ushort AL[2][16384];   // [buf][2 panels x 8192 elems]
    __shared__ ushort BL[2][16384];
    const int NBN = 41;
    int q = gridDim.x >> 3;                 // 82
    int wg = blockIdx.x;
    int swz = (wg & 7) * q + (wg >> 3);
    int per = NBN * 4;                      // 164
    int sg = swz / per, rr = swz % per;
    int bm = sg * 4 + (rr & 3);
    int bn = rr >> 2;
    int tid = threadIdx.x;
    int lane = tid & 63, w = tid >> 6;
    int wr = w >> 2, wc = w & 3;
    int lr = lane & 15, g = lane >> 4;
    int y00 = ((lr >> 1) << 7) | ((lr & 1) << 6) | (g << 4);
    int z00 = y00 ^ (((y00 >> 7) & 7) << 4);
    int aBase = wr * 8192 + z00;
    int bBase = wc * 4096 + z00;
    int z0 = tid * 16, z1 = z0 + 8192;
    int y0 = z0 ^ (((z0 >> 7) & 7) << 4);
    int y1 = z1 ^ (((z1 >> 7) & 7) << 4);
    int row0s = ((y0 >> 7) << 1) | ((y0 >> 6) & 1), kbe0 = (y0 & 63) >> 1;
    int row1s = ((y1 >> 7) << 1) | ((y1 >> 6) & 1), kbe1 = (y1 & 63) >> 1;
    const ushort* gA0 = &X[(size_t)(bm * 256 + row0s) * 2048 + kbe0];
    const ushort* gA1 = &X[(size_t)(bm * 256 + row1s) * 2048 + kbe1];
    const ushort* gB0 = &W[(size_t)(bn * 256 + row0s) * 2048 + kbe0];
    const ushort* gB1 = &W[(size_t)(bn * 256 + row1s) * 2048 + kbe1];
    int wOff = w * 1024;

#define STAGE(DB, ARR, KP, P0, P1, KO) do { \
    gload_lds16((P0) + (KO) + (KP) * 32, (char*)(ARR) + (DB) * 32768 + (KP) * 16384 + wOff); \
    gload_lds16((P1) + (KO) + (KP) * 32, (char*)(ARR) + (DB) * 32768 + (KP) * 16384 + wOff + 8192); \
} while (0)

    f32x4 acc[8][4] = {};
    STAGE(0, AL, 0, gA0, gA1, 0);
    STAGE(0, BL, 0, gB0, gB1, 0);
    STAGE(0, AL, 1, gA0, gA1, 0);
    STAGE(0, BL, 1, gB0, gB1, 0);

    for (int t = 0; t < 32; ++t) {
        int buf = t & 1, nb = buf ^ 1;
        int ko = ((t + 1) & 31) * 64;
        const char* Ab = (const char*)AL + buf * 32768;
        const char* Bb = (const char*)BL + buf * 32768;
        bf16x8 a0, a1, a2, a3, b0, b1, b2, b3;
        // ---- phase (kh0, mh0) ----
        asm volatile("s_waitcnt vmcnt(4)" ::: "memory");
        __builtin_amdgcn_s_barrier();
        __builtin_amdgcn_sched_barrier(0);
        b0 = RD8(Bb, bBase);        b1 = RD8(Bb, bBase + 1024);
        b2 = RD8(Bb, bBase + 2048); b3 = RD8(Bb, bBase + 3072);
        a0 = RD8(Ab, aBase);        a1 = RD8(Ab, aBase + 1024);
        a2 = RD8(Ab, aBase + 2048); a3 = RD8(Ab, aBase + 3072);
        STAGE(nb, AL, 0, gA0, gA1, ko);
        __builtin_amdgcn_s_setprio(1);
        MM16(0);
        __builtin_amdgcn_s_setprio(0);
        __builtin_amdgcn_sched_barrier(0);
        __builtin_amdgcn_s_barrier();
        __builtin_amdgcn_sched_barrier(0);
        // ---- phase (kh0, mh1) ----
        a0 = RD8(Ab, aBase + 4096);        a1 = RD8(Ab, aBase + 4096 + 1024);
        a2 = RD8(Ab, aBase + 4096 + 2048); a3 = RD8(Ab, aBase + 4096 + 3072);
        STAGE(nb, BL, 0, gB0, gB1, ko);
        __builtin_amdgcn_s_setprio(1);
        MM16(4);
        __builtin_amdgcn_s_setprio(0);
        // ---- phase (kh1, mh0) ----
        asm volatile("s_waitcnt vmcnt(4)" ::: "memory");
        __builtin_amdgcn_s_barrier();
        __builtin_amdgcn_sched_barrier(0);
        b0 = RD8(Bb, bBase + 16384);        b1 = RD8(Bb, bBase + 16384 + 1024);
        b2 = RD8(Bb, bBase + 16384 + 2048); b3 = RD8(Bb, bBase + 16384 + 3072);
        a0 = RD8(Ab, aBase + 16384);        a1 = RD8(Ab, aBase + 16384 + 1024);
        a2 = RD8(Ab, aBase + 16384 + 2048); a3 = RD8(Ab, aBase + 16384 + 3072);
        STAGE(nb, AL, 1, gA0, gA1, ko);
        __builtin_amdgcn_s_setprio(1);
        MM16(0);
        __builtin_amdgcn_s_setprio(0);
        __builtin_amdgcn_sched_barrier(0);
        __builtin_amdgcn_s_barrier();
        __builtin_amdgcn_sched_barrier(0);
        // ---- phase (kh1, mh1) ----
        a0 = RD8(Ab, aBase + 16384 + 4096);        a1 = RD8(Ab, aBase + 16384 + 4096 + 1024);
        a2 = RD8(Ab, aBase + 16384 + 4096 + 2048); a3 = RD8(Ab, aBase + 16384 + 4096 + 3072);
        STAGE(nb, BL, 1, gB0, gB1, ko);
        __builtin_amdgcn_s_setprio(1);
        MM16(4);
        __builtin_amdgcn_s_setprio(0);
    }
    asm volatile("s_waitcnt vmcnt(0)" ::: "memory");

    int rq = g * 4;
    #pragma unroll
    for (int mf = 0; mf < 8; mf++) {
        int row0 = bm * 256 + wr * 128 + mf * 16 + rq;
        #pragma unroll
        for (int n = 0; n < 4; n++) {
            int cb0 = bn * 256 + wc * 64 + n * 16;
            int col = cb0 + lr;
            if (cb0 < 4096) {
                #pragma unroll
                for (int r = 0; r < 4; r++)
                    zbuf[(size_t)(row0 + r) * DINNER + col] = f2bf(acc[mf][n][r]);
            } else if (cb0 < 10240) {
                #pragma unroll
                for (int r = 0; r < 4; r++)
                    xbc[(size_t)(row0 + r) * CONVDIM + (col - 4096)] = f2bf(acc[mf][n][r]);
            } else if (cb0 < 10304) {
                #pragma unroll
                for (int r = 0; r < 4; r++)
                    dtraw[(size_t)(row0 + r) * 64 + (col - 10240)] = acc[mf][n][r];
            }
        }
    }
}
#undef STAGE

// ============================================================
// out_proj: 256x128-tile pipelined GEMM, BK=64, 2 phases/tile.
// Out[4096][2048] = X[4096][4096] * W[2048][4096]^T, fp32 out.
// Grid 16x16 = 256 blocks = EXACTLY 1/CU (no tail quantization).
// 8 waves (4 wr x 2 wc), wave output 64x64 (acc[4][4]).
// LDS 96 KiB: A 2bufs x 2 kh-panels x 16KB; B 2 x 2 x 8KB.
// Same st-swizzle as gemm256_in; vmcnt(3) per phase entry (counted).
// ============================================================
__global__ __launch_bounds__(512, 2) void gemm256_out(
    const ushort* __restrict__ X, const ushort* __restrict__ W,
    float* __restrict__ outF) {
    __shared__ ushort AL[2][16384];   // 2 bufs x 32768 B (2 kh panels x 16 KB)
    __shared__ ushort BL[2][8192];    // 2 bufs x 16384 B (2 kh panels x 8 KB)
    int q = gridDim.x >> 3;                 // 32
    int wg = blockIdx.x;
    int swz = (wg & 7) * q + (wg >> 3);
    int per = 16 * 4;                       // NBN=16 supertile
    int sg = swz / per, rr = swz % per;
    int bm = sg * 4 + (rr & 3);             // 0..15
    int bn = rr >> 2;                       // 0..15
    int tid = threadIdx.x;
    int lane = tid & 63, w = tid >> 6;
    int wr = w >> 1, wc = w & 1;
    int lr = lane & 15, g = lane >> 4;
    int y00 = ((lr >> 1) << 7) | ((lr & 1) << 6) | (g << 4);
    int z00 = y00 ^ (((y00 >> 7) & 7) << 4);
    int aBase = wr * 4096 + z00;            // + buf*32768 + kh*16384 + mf*1024
    int bBase = wc * 4096 + z00;            // + buf*16384 + kh*8192  + nf*1024
    // staging decode (same involution): A = 2 slices, B = 1 slice
    int z0 = tid * 16, z1 = z0 + 8192;
    int y0 = z0 ^ (((z0 >> 7) & 7) << 4);
    int y1 = z1 ^ (((z1 >> 7) & 7) << 4);
    int rowA0 = ((y0 >> 7) << 1) | ((y0 >> 6) & 1), kA0 = (y0 & 63) >> 1;  // 0..127
    int rowA1 = ((y1 >> 7) << 1) | ((y1 >> 6) & 1), kA1 = (y1 & 63) >> 1;  // 128..255
    const ushort* gA0 = &X[(size_t)(bm * 256 + rowA0) * 4096 + kA0];
    const ushort* gA1 = &X[(size_t)(bm * 256 + rowA1) * 4096 + kA1];
    const ushort* gB  = &W[(size_t)(bn * 128 + rowA0) * 4096 + kA0];
    int wOff = w * 1024;

#define STAGEA(DB, KP, KO) do { \
    gload_lds16(gA0 + (KO) + (KP) * 32, (char*)AL + (DB) * 32768 + (KP) * 16384 + wOff); \
    gload_lds16(gA1 + (KO) + (KP) * 32, (char*)AL + (DB) * 32768 + (KP) * 16384 + wOff + 8192); \
} while (0)
#define STAGEB(DB, KP, KO) \
    gload_lds16(gB + (KO) + (KP) * 32, (char*)BL + (DB) * 16384 + (KP) * 8192 + wOff)

    f32x4 acc[4][4] = {};
    // prologue: tile 0 (order fixes vmcnt ages: Ak0,Bk0,Ak1,Bk1)
    STAGEA(0, 0, 0); STAGEB(0, 0, 0);
    STAGEA(0, 1, 0); STAGEB(0, 1, 0);

    for (int t = 0; t < 64; ++t) {
        int buf = t & 1, nb = buf ^ 1;
        int ko = ((t + 1) & 63) * 64;       // tail: dummy re-stage of tile 0
        const char* Ab = (const char*)AL + buf * 32768;
        const char* Bb = (const char*)BL + buf * 16384;
        bf16x8 a0, a1, a2, a3, b0, b1, b2, b3;
        // ---- phase kh0 ----
        asm volatile("s_waitcnt vmcnt(3)" ::: "memory");
        __builtin_amdgcn_s_barrier();
        __builtin_amdgcn_sched_barrier(0);
        b0 = RD8(Bb, bBase);        b1 = RD8(Bb, bBase + 1024);
        b2 = RD8(Bb, bBase + 2048); b3 = RD8(Bb, bBase + 3072);
        a0 = RD8(Ab, aBase);        a1 = RD8(Ab, aBase + 1024);
        a2 = RD8(Ab, aBase + 2048); a3 = RD8(Ab, aBase + 3072);
        STAGEA(nb, 0, ko); STAGEB(nb, 0, ko);
        __builtin_amdgcn_s_setprio(1);
        MM16(0);
        __builtin_amdgcn_s_setprio(0);
        __builtin_amdgcn_sched_barrier(0);
        // ---- phase kh1 ----
        asm volatile("s_waitcnt vmcnt(3)" ::: "memory");
        __builtin_amdgcn_s_barrier();
        __builtin_amdgcn_sched_barrier(0);
        b0 = RD8(Bb, bBase + 8192);        b1 = RD8(Bb, bBase + 8192 + 1024);
        b2 = RD8(Bb, bBase + 8192 + 2048); b3 = RD8(Bb, bBase + 8192 + 3072);
        a0 = RD8(Ab, aBase + 16384);        a1 = RD8(Ab, aBase + 16384 + 1024);
        a2 = RD8(Ab, aBase + 16384 + 2048); a3 = RD8(Ab, aBase + 16384 + 3072);
        STAGEA(nb, 1, ko); STAGEB(nb, 1, ko);
        __builtin_amdgcn_s_setprio(1);
        MM16(0);
        __builtin_amdgcn_s_setprio(0);
        __builtin_amdgcn_sched_barrier(0);
    }
    asm volatile("s_waitcnt vmcnt(0)" ::: "memory");

    int rq = g * 4;
    #pragma unroll
    for (int mf = 0; mf < 4; mf++) {
        int row0 = bm * 256 + wr * 64 + mf * 16 + rq;
        #pragma unroll
        for (int nf = 0; nf < 4; nf++) {
            int col = bn * 128 + wc * 64 + nf * 16 + lr;
            #pragma unroll
            for (int r = 0; r < 4; r++)
                outF[(size_t)(row0 + r) * DMODEL + col] = acc[mf][nf][r];
        }
    }
}
#undef STAGEA
#undef STAGEB

// ============================================================
// causal depthwise conv1d (K=4) + SiLU: 4 rows x 8 ch per thread
// ============================================================
__global__ void conv_kernel(const ushort* __restrict__ xbc, const float* __restrict__ cw,
                            const float* __restrict__ cb, ushort* __restrict__ convout) {
    int c8 = (blockIdx.x * 256 + threadIdx.x) * 8;   // channel base (grid.x=3 -> 6144 ch)
    int row0 = blockIdx.y * 4;                       // token base (grid.y=1024)
    int t0 = row0 & 2047;                            // within-batch position
    float bias[8];
    {
        float4 b0 = ((const float4*)cb)[c8 / 4];
        float4 b1 = ((const float4*)cb)[c8 / 4 + 1];
        bias[0] = b0.x; bias[1] = b0.y; bias[2] = b0.z; bias[3] = b0.w;
        bias[4] = b1.x; bias[5] = b1.y; bias[6] = b1.z; bias[7] = b1.w;
    }
    float wk[8][4];
    #pragma unroll
    for (int e = 0; e < 8; e++) {
        float4 wv = ((const float4*)cw)[c8 + e];
        wk[e][0] = wv.x; wk[e][1] = wv.y; wk[e][2] = wv.z; wk[e][3] = wv.w;
    }
    float f[7][8];
    #pragma unroll
    for (int j = 0; j < 7; j++) {
        int tt = t0 - 3 + j;
        if (tt >= 0) {
            uint4 v = *(const uint4*)&xbc[(size_t)(row0 - 3 + j) * CONVDIM + c8];
            unpack8(v, f[j]);
        } else {
            #pragma unroll
            for (int e = 0; e < 8; e++) f[j][e] = 0.f;
        }
    }
    #pragma unroll
    for (int r = 0; r < 4; r++) {
        float a[8];
        #pragma unroll
        for (int e = 0; e < 8; e++) {
            a[e] = bias[e];
            #pragma unroll
            for (int k = 0; k < 4; k++) a[e] += f[r + k][e] * wk[e][k];
        }
        uint4 o;
        float s[8];
        #pragma unroll
        for (int e = 0; e < 8; e++) s[e] = a[e] / (1.f + __expf(-a[e]));
        o.x = pk2(s[0], s[1]); o.y = pk2(s[2], s[3]);
        o.z = pk2(s[4], s[5]); o.w = pk2(s[6], s[7]);
        *(uint4*)&convout[(size_t)(row0 + r) * CONVDIM + c8] = o;
    }
}

// ============================================================
// fused: softplus(dtraw+bias) (in place) + per-chunk cumsum of dt*A
// ============================================================
__global__ void cumsum_kernel(float* __restrict__ dtbuf, const float* __restrict__ dt_bias,
                              const float* __restrict__ A_log, float* __restrict__ dAcs) {
    int bi = blockIdx.x;
    int h = bi & 63, cg = bi >> 6;            // cg in [0,16)
    int t = threadIdx.x;
    size_t didx = (size_t)(cg * 256 + t) * 64 + h;
    float x = dtbuf[didx] + dt_bias[h];
    float sp = (x > 20.f) ? x : log1pf(__expf(x));
    dtbuf[didx] = sp;
    float A = -expf(A_log[h]);
    float v = sp * A;
    __shared__ float s[256];
    s[t] = v;
    __syncthreads();
    for (int off = 1; off < 256; off <<= 1) {
        float add = (t >= off) ? s[t - off] : 0.f;
        __syncthreads();
        s[t] += add;
        __syncthreads();
    }
    dAcs[(size_t)bi * 256 + t] = s[t];
}

// ============================================================
// MFMA states: per (cg,h), states[p][n] = sum_s xdt'[s,p] * B[s,n]
// ============================================================
__global__ __launch_bounds__(256) void states_mfma(
    const ushort* __restrict__ convout, const float* __restrict__ dtsp,
    const float* __restrict__ dAcs, float* __restrict__ states) {
    __shared__ ushort BT[128 * 72];   // 18 KB, stride 72 elems
    __shared__ ushort XT[64 * 72];    // 9 KB
    int bi = blockIdx.x;
    int h = bi & 63, cg = bi >> 6;
    int tid = threadIdx.x;
    int rowbase = cg * 256;
    int bcol = 1024 + ((h >> 3) << 7);
    int xcol = ((h >> 3) << 7) + ((h & 1) << 6);
    float dAlast = dAcs[(size_t)bi * 256 + 255];
    int w = tid >> 6, lane = tid & 63, g = lane >> 4, cc = lane & 15;
    f32x4 acc[4][2] = {};
    for (int T = 0; T < 4; T++) {
        __syncthreads();   // previous tile's reads done
        int s = lane;
        int srow = rowbase + T * 64 + s;
        #pragma unroll
        for (int i = 0; i < 4; i++) {
            int n0 = (w + i * 4) * 8;
            uint4 v = *(const uint4*)&convout[(size_t)srow * CONVDIM + bcol + n0];
            ushort us[8];
            us[0] = (ushort)v.x; us[1] = (ushort)(v.x >> 16);
            us[2] = (ushort)v.y; us[3] = (ushort)(v.y >> 16);
            us[4] = (ushort)v.z; us[5] = (ushort)(v.z >> 16);
            us[6] = (ushort)v.w; us[7] = (ushort)(v.w >> 16);
            #pragma unroll
            for (int e = 0; e < 8; e++) BT[(n0 + e) * 72 + s] = us[e];
        }
        float wgt = dtsp[(size_t)srow * 64 + h] * __expf(dAlast - dAcs[(size_t)bi * 256 + T * 64 + s]);
        #pragma unroll
        for (int j = 0; j < 2; j++) {
            int p0 = (w * 2 + j) * 8;
            uint4 v = *(const uint4*)&convout[(size_t)srow * CONVDIM + xcol + p0];
            float f[8]; unpack8(v, f);
            #pragma unroll
            for (int e = 0; e < 8; e++) XT[(p0 + e) * 72 + s] = f2bf(f[e] * wgt);
        }
        __syncthreads();
        bf16x8 af[4][2], bw[2][2];
        #pragma unroll
        for (int m = 0; m < 4; m++)
            #pragma unroll
            for (int kb = 0; kb < 2; kb++)
                af[m][kb] = *(const bf16x8*)&XT[(m * 16 + cc) * 72 + kb * 32 + 8 * g];
        #pragma unroll
        for (int np = 0; np < 2; np++)
            #pragma unroll
            for (int kb = 0; kb < 2; kb++)
                bw[np][kb] = *(const bf16x8*)&BT[(w * 32 + np * 16 + cc) * 72 + kb * 32 + 8 * g];
        #pragma unroll
        for (int m = 0; m < 4; m++)
            #pragma unroll
            for (int np = 0; np < 2; np++) {
                acc[m][np] = MFMA_OP(af[m][0], bw[np][0], acc[m][np], 0, 0, 0);
                acc[m][np] = MFMA_OP(af[m][1], bw[np][1], acc[m][np], 0, 0, 0);
            }
    }
    size_t base = (size_t)bi * 8192;
    #pragma unroll
    for (int m = 0; m < 4; m++)
        #pragma unroll
        for (int np = 0; np < 2; np++)
            #pragma unroll
            for (int r = 0; r < 4; r++) {
                int p = m * 16 + 4 * g + r;
                int n = w * 32 + np * 16 + cc;
                states[base + (size_t)p * 128 + n] = acc[m][np][r];
            }
}

// ============================================================
// inter-chunk recurrence: 8 chunks PER BATCH, carry resets per batch
// grid 1024 = 128 bh x 8 p-slices; full 64x128 state covered
// ============================================================
__global__ void recur_kernel(const float* __restrict__ dAcs, float* __restrict__ states) {
    int blk = blockIdx.x;                 // (b*64+h)*8 + pq
    int pq = blk & 7, bh = blk >> 3;
    int h = bh & 63, b = bh >> 6;
    int tid = threadIdx.x;
    int p = pq * 8 + (tid >> 5);          // [0,64)
    int n0 = (tid & 31) * 4;              // [0,128)
    float4 carry = make_float4(0.f, 0.f, 0.f, 0.f);
    for (int c = 0; c < 8; c++) {
        int bi = (b * 8 + c) * 64 + h;
        float decay = __expf(dAcs[(size_t)bi * 256 + 255]);
        size_t idx = (size_t)bi * 8192 + (size_t)p * 128 + n0;
        float4 tmp = *(const float4*)&states[idx];
        *(float4*)&states[idx] = carry;
        carry.x = carry.x * decay + tmp.x;
        carry.y = carry.y * decay + tmp.y;
        carry.z = carry.z * decay + tmp.z;
        carry.w = carry.w * decay + tmp.w;
    }
}

// ============================================================
// MFMA yscan: per (cg,h) block, Y = Y_diag + Y_off (D*x added in norm).
// ============================================================
__global__ __launch_bounds__(256, 2) void yscan_mfma(
    const ushort* __restrict__ convout, const float* __restrict__ dtsp,
    const float* __restrict__ dAcs, const float* __restrict__ states,
    ushort* __restrict__ y) {
    __shared__ ushort XT[64 * 264];   // xdt^T: XT[p][s], stride 264
    __shared__ ushort PR[64 * 136];   // prev bf16 [p][n], stride 136
    __shared__ ushort PV[4 * 16 * 72];// per-wave P strip
    __shared__ float sdA[256];
    int bi = blockIdx.x;
    int h = bi & 63, cg = bi >> 6;
    int tid = threadIdx.x;
    int rowbase = cg * 256;
    int bcol = 1024 + ((h >> 3) << 7);
    int ccol = 2048 + ((h >> 1) << 7);
    int xcol = ((h >> 3) << 7) + ((h & 1) << 6);

    sdA[tid] = dAcs[(size_t)bi * 256 + tid];
    #pragma unroll
    for (int i = 0; i < 4; i++) {
        int s = i * 64 + (tid & 63);
        float dtv = dtsp[(size_t)(rowbase + s) * 64 + h];
        #pragma unroll
        for (int j = 0; j < 2; j++) {
            int p0 = (((tid >> 6) << 1) + j) << 3;
            uint4 v = *(const uint4*)&convout[(size_t)(rowbase + s) * CONVDIM + xcol + p0];
            float f[8]; unpack8(v, f);
            #pragma unroll
            for (int e = 0; e < 8; e++) XT[(p0 + e) * 264 + s] = f2bf(f[e] * dtv);
        }
    }
    {
        const float* pv = &states[(size_t)bi * 8192];
        #pragma unroll
        for (int i = 0; i < 8; i++) {
            int flat = i * 1024 + tid * 4;
            float4 v = *(const float4*)&pv[flat];
            int p = flat >> 7, n = flat & 127;
            *(uint*)&PR[p * 136 + n]     = pk2(v.x, v.y);
            *(uint*)&PR[p * 136 + n + 2] = pk2(v.z, v.w);
        }
    }
    __syncthreads();

    int w = tid >> 6, lane = tid & 63, g = lane >> 4, c = lane & 15;
    int wbase = w * 64;
    const ushort* Crow0 = &convout[(size_t)(rowbase + wbase + c) * CONVDIM + ccol + 8 * g];

    // ---- Y_off = C . prev^T ----
    f32x4 yac[4][4] = {};
    #pragma unroll
    for (int kb = 0; kb < 4; kb++) {
        bf16x8 pb[4];
        #pragma unroll
        for (int np = 0; np < 4; np++)
            pb[np] = *(const bf16x8*)&PR[(16 * np + c) * 136 + kb * 32 + 8 * g];
        #pragma unroll
        for (int m = 0; m < 4; m++) {
            bf16x8 cf = *(const bf16x8*)&Crow0[(size_t)(m * 16) * CONVDIM + kb * 32];
            #pragma unroll
            for (int np = 0; np < 4; np++)
                yac[m][np] = MFMA_OP(cf, pb[np], yac[m][np], 0, 0, 0);
        }
    }
    float al[4][4];
    float Sw = sdA[wbase];
    float eSw = __expf(Sw);
    #pragma unroll
    for (int m = 0; m < 4; m++)
        #pragma unroll
        for (int r = 0; r < 4; r++) {
            float dAl = sdA[wbase + m * 16 + 4 * g + r];
            al[m][r] = __expf(dAl - Sw);
            float el = al[m][r] * eSw;
            #pragma unroll
            for (int np = 0; np < 4; np++) yac[m][np][r] *= el;
        }

    // ---- s-tiles ----
    ushort* pvs = &PV[w * 1152];
    for (int T = 0; T <= w; T++) {
        f32x4 sac[4][4] = {};
        #pragma unroll
        for (int kb = 0; kb < 4; kb++) {
            bf16x8 bb[4];
            #pragma unroll
            for (int np = 0; np < 4; np++)
                bb[np] = *(const bf16x8*)&convout[(size_t)(rowbase + T * 64 + 16 * np + c) * CONVDIM + bcol + kb * 32 + 8 * g];
            #pragma unroll
            for (int m = 0; m < 4; m++) {
                bf16x8 cf = *(const bf16x8*)&Crow0[(size_t)(m * 16) * CONVDIM + kb * 32];
                #pragma unroll
                for (int np = 0; np < 4; np++)
                    sac[m][np] = MFMA_OP(cf, bb[np], sac[m][np], 0, 0, 0);
            }
        }
        bf16x8 xb[4][2];
        #pragma unroll
        for (int np = 0; np < 4; np++)
            #pragma unroll
            for (int k2 = 0; k2 < 2; k2++)
                xb[np][k2] = *(const bf16x8*)&XT[(16 * np + c) * 264 + T * 64 + k2 * 32 + 8 * g];
        if (T < w) {
            float ET = sdA[T * 64 + 63];
            float cT = __expf(Sw - ET);
            float bc[4];
            #pragma unroll
            for (int np = 0; np < 4; np++)
                bc[np] = __expf(ET - sdA[T * 64 + 16 * np + c]) * cT;
            #pragma unroll
            for (int m = 0; m < 4; m++) {
                #pragma unroll
                for (int np = 0; np < 4; np++) {
                    float s0 = bc[np];
                    #pragma unroll
                    for (int r = 0; r < 4; r++)
                        pvs[(4 * g + r) * 72 + 16 * np + c] = f2bf(sac[m][np][r] * (al[m][r] * s0));
                }
                bf16x8 pa0 = *(const bf16x8*)&pvs[c * 72 + 8 * g];
                bf16x8 pa1 = *(const bf16x8*)&pvs[c * 72 + 32 + 8 * g];
                #pragma unroll
                for (int np = 0; np < 4; np++) {
                    yac[m][np] = MFMA_OP(pa0, xb[np][0], yac[m][np], 0, 0, 0);
                    yac[m][np] = MFMA_OP(pa1, xb[np][1], yac[m][np], 0, 0, 0);
                }
            }
        } else {
            #pragma unroll
            for (int m = 0; m < 4; m++) {
                float dal[4];
                #pragma unroll
                for (int r = 0; r < 4; r++) dal[r] = sdA[wbase + m * 16 + 4 * g + r];
                #pragma unroll
                for (int np = 0; np < 4; np++) {
                    int s_loc = w * 64 + 16 * np + c;
                    float dAs = sdA[s_loc];
                    #pragma unroll
                    for (int r = 0; r < 4; r++) {
                        int l_loc = wbase + m * 16 + 4 * g + r;
                        float v = (s_loc <= l_loc) ? sac[m][np][r] * __expf(dal[r] - dAs) : 0.f;
                        pvs[(4 * g + r) * 72 + 16 * np + c] = f2bf(v);
                    }
                }
                bf16x8 pa0 = *(const bf16x8*)&pvs[c * 72 + 8 * g];
                bf16x8 pa1 = *(const bf16x8*)&pvs[c * 72 + 32 + 8 * g];
                #pragma unroll
                for (int np = 0; np < 4; np++) {
                    yac[m][np] = MFMA_OP(pa0, xb[np][0], yac[m][np], 0, 0, 0);
                    yac[m][np] = MFMA_OP(pa1, xb[np][1], yac[m][np], 0, 0, 0);
                }
            }
        }
    }
    #pragma unroll
    for (int m = 0; m < 4; m++)
        #pragma unroll
        for (int np = 0; np < 4; np++)
            #pragma unroll
            for (int r = 0; r < 4; r++) {
                int l = wbase + m * 16 + 4 * g + r;
                y[(size_t)(rowbase + l) * DINNER + h * 64 + 16 * np + c] = f2bf(yac[m][np][r]);
            }
}

// ============================================================
// gated grouped RMSNorm (in place over y), adds D*x first.
// ============================================================
__global__ void norm_kernel(ushort* __restrict__ y, const ushort* __restrict__ zbuf,
                            const ushort* __restrict__ convout, const float* __restrict__ Dvec,
                            const float* __restrict__ nw) {
    int row = blockIdx.x;                         // token
    int g = blockIdx.y * 4 + (threadIdx.x >> 6);  // group 0..31
    int lane = threadIdx.x & 63;
    int cbase = g * 128 + lane * 2;
    int h = cbase >> 6;
    int p = cbase & 63;
    int xc = ((h >> 3) << 7) + ((h & 1) << 6) + p;
    uint yv = *(const uint*)&y[(size_t)row * DINNER + cbase];
    uint zv = *(const uint*)&zbuf[(size_t)row * DINNER + cbase];
    uint xv = *(const uint*)&convout[(size_t)row * CONVDIM + xc];
    float Dh = Dvec[h];
    float y0 = bflo(yv) + Dh * bflo(xv), y1 = bfhi(yv) + Dh * bfhi(xv);
    float z0 = bflo(zv), z1 = bfhi(zv);
    float v0 = y0 * (z0 / (1.f + __expf(-z0)));
    float v1 = y1 * (z1 / (1.f + __expf(-z1)));
    float ss = v0 * v0 + v1 * v1;
    #pragma unroll
    for (int off = 32; off; off >>= 1) ss += __shfl_xor(ss, off, 64);
    float rstd = rsqrtf(ss * (1.f / 128.f) + 1e-5f);
    v0 *= rstd * nw[cbase];
    v1 *= rstd * nw[cbase + 1];
    *(uint*)&y[(size_t)row * DINNER + cbase] = pk2(v0, v1);
}

// ============================================================
extern "C" void kernel_launch(void* const* d_in, const int* in_sizes, int n_in,
                              void* d_out, int out_size, void* d_ws, size_t ws_size,
                              hipStream_t stream) {
    const float* u       = (const float*)d_in[0];
    const float* W_in    = (const float*)d_in[1];
    const float* conv_w  = (const float*)d_in[2];
    const float* conv_b  = (const float*)d_in[3];
    const float* dt_bias = (const float*)d_in[4];
    const float* A_log   = (const float*)d_in[5];
    const float* Dvec    = (const float*)d_in[6];
    const float* nw      = (const float*)d_in[7];
    const float* W_out   = (const float*)d_in[8];

    // ---- workspace layout (aliased bf16 staging) ----
    char* ws = (char*)d_ws;
    size_t off = 0;
    auto alloc = [&](size_t bytes) { void* p = ws + off; off += (bytes + 255) & ~(size_t)255; return p; };
    ushort* zbuf    = (ushort*)alloc((size_t)LTOT * DINNER * 2);          // 32 MiB
    // shreg: xbc (48 MiB) -> states (32 MiB) -> Wout_bf (16.8 MiB)
    void*   shreg   = alloc((size_t)LTOT * CONVDIM * 2);                  // 48 MiB
    ushort* xbc     = (ushort*)shreg;
    float*  states  = (float*)shreg;
    ushort* Wout_bf = (ushort*)shreg;
    float*  dtbuf   = (float*) alloc((size_t)LTOT * 64 * 4);              // 1 MiB
    // conv region: Win_bf (padded to 10496 rows, 43 MiB) -> convout (48 MiB)
    void*   convreg = alloc((size_t)LTOT * CONVDIM * 2);                  // 48 MiB
    ushort* Win_bf  = (ushort*)convreg;
    ushort* convout = (ushort*)convreg;
    float*  dAcs    = (float*) alloc((size_t)1024 * 256 * 4);             // 1 MiB
    // ybuf region: u_bf (16.8 MiB) -> ybuf (32 MiB)
    void*   ybreg   = alloc((size_t)LTOT * DINNER * 2);                   // 32 MiB
    ushort* u_bf    = (ushort*)ybreg;
    ushort* ybuf    = (ushort*)ybreg;

    // bf16 conversions (aliased into dead regions)
    cvt_kernel<<<dim3(8192),  dim3(256), 0, stream>>>(u, u_bf, 2097152);
    cvt_kernel<<<dim3(20608), dim3(256), 0, stream>>>(W_in, Win_bf, 5275648);
    // in_proj: 256^2 8-phase kernel; grid 16 bm x 41 bn = 656 (%8==0)
    gemm256_in<<<dim3(656), dim3(512), 0, stream>>>(u_bf, Win_bf, zbuf, xbc, dtbuf);
    // conv + silu (4 rows/thread; overwrites Win_bf region — dead)
    conv_kernel<<<dim3(3, 1024), dim3(256), 0, stream>>>(xbc, conv_w, conv_b, convout);
    // fused softplus + cumsum (grid 16 chunks x 64 heads = 1024)
    cumsum_kernel<<<dim3(1024), dim3(256), 0, stream>>>(dtbuf, dt_bias, A_log, dAcs);
    // chunked scan (states overwrites xbc region — dead after conv)
    states_mfma<<<dim3(1024), dim3(256), 0, stream>>>(convout, dtbuf, dAcs, states);
    recur_kernel<<<dim3(1024), dim3(256), 0, stream>>>(dAcs, states);
    yscan_mfma<<<dim3(1024), dim3(256), 0, stream>>>(convout, dtbuf, dAcs, states, ybuf);
    // W_out -> bf16 (states dead after yscan)
    cvt_kernel<<<dim3(8192), dim3(256), 0, stream>>>(W_out, Wout_bf, 2097152);
    // gated group RMSNorm (in place, adds D*x)
    norm_kernel<<<dim3(4096, 8), dim3(256), 0, stream>>>(ybuf, zbuf, convout, Dvec, nw);
    // out_proj: 256x128 pipelined kernel; grid 16 bm x 16 bn = 256 (1/CU exact)
    gemm256_out<<<dim3(256), dim3(512), 0, stream>>>(ybuf, Wout_bf, (float*)d_out);
}

// Round 11
// 468.201 us; speedup vs baseline: 11.3330x; 1.0652x over previous
//
#include <hip/hip_runtime.h>
#include <cstdint>
#include <cstddef>

typedef unsigned int uint;
typedef unsigned short ushort;

typedef __bf16 bf16x8 __attribute__((ext_vector_type(8)));
typedef float f32x4 __attribute__((ext_vector_type(4)));

// ---------- bf16 helpers (bit-level) ----------
__device__ __forceinline__ float bflo(uint u) { return __uint_as_float(u << 16); }
__device__ __forceinline__ float bfhi(uint u) { return __uint_as_float(u & 0xffff0000u); }
__device__ __forceinline__ float bf2f(ushort s) { return __uint_as_float(((uint)s) << 16); }
__device__ __forceinline__ ushort f2bf(float f) {
    uint u = __float_as_uint(f);
    u += 0x7fffu + ((u >> 16) & 1u);   // round-to-nearest-even
    return (ushort)(u >> 16);
}
__device__ __forceinline__ uint pk2(float lo, float hi) {
    return (uint)f2bf(lo) | ((uint)f2bf(hi) << 16);
}
__device__ __forceinline__ void unpack8(uint4 v, float* f) {
    f[0] = bflo(v.x); f[1] = bfhi(v.x); f[2] = bflo(v.y); f[3] = bfhi(v.y);
    f[4] = bflo(v.z); f[5] = bfhi(v.z); f[6] = bflo(v.w); f[7] = bfhi(v.w);
}

// async global->LDS, 16B per lane, wave-uniform LDS base (linear dest)
typedef __attribute__((address_space(1))) const unsigned int* as1_cuptr;
typedef __attribute__((address_space(3))) unsigned int* as3_uptr;
__device__ __forceinline__ void gload_lds16(const void* g, void* l) {
    __builtin_amdgcn_global_load_lds((as1_cuptr)g, (as3_uptr)l, 16, 0, 0);
}

// ---------- constants ----------
#define LTOT 4096           // b*l tokens (2 batches x 2048)
#define DMODEL 2048
#define DINNER 4096
#define DSTATE 128
#define NHEADS 64
#define CONVDIM 6144
#define DPROJ 10304
#define CHUNK 256
#define NCHUNK 16           // GLOBAL chunks (8 per batch x 2 batches)

// ============================================================
// fp32 -> bf16 conversion (vectorized)
// ============================================================
__global__ void cvt_kernel(const float* __restrict__ in, ushort* __restrict__ out, int n4) {
    int i = blockIdx.x * 256 + threadIdx.x;
    if (i < n4) {
        float4 v = ((const float4*)in)[i];
        ushort4 o;
        o.x = f2bf(v.x); o.y = f2bf(v.y); o.z = f2bf(v.z); o.w = f2bf(v.w);
        ((ushort4*)out)[i] = o;
    }
}

// ============================================================
// in_proj: 256x256-tile 8-phase GEMM, BK=64, with ONE-PHASE-AHEAD
// LDS->reg pre-read (m196 interleave: ds_read || gload || MFMA).
// Phase A: MFMA(kh0,mh0)[regs from (t-1)D], read kh0-mh1, stage Akh0(t+1)
// Phase B: vmcnt(2)+bar; MFMA(kh0,mh1), read kh1 B+A-mh0, stage Bkh0(t+1)
// Phase C: MFMA(kh1,mh0), read kh1-mh1, stage Akh1(t+1)
// Phase D: vmcnt(2)+bar; MFMA(kh1,mh1), read NEXT tile kh0 (other buf),
//          stage Bkh1(t+1)
// Visibility: panels confirmed at B/D entries (outstanding 6, vmcnt(2)
// pops exactly the 2 needed panels); all staging writes >=2 barriers
// after last read of the overwritten region.
// ============================================================
#define MFMA_OP __builtin_amdgcn_mfma_f32_16x16x32_bf16
#define MMX(MB, AV, BV) do { \
  _Pragma("unroll") \
  for (int _m = 0; _m < 4; _m++) \
    _Pragma("unroll") \
    for (int _n = 0; _n < 4; _n++) \
      acc[(MB)+_m][_n] = MFMA_OP(AV[_m], BV[_n], acc[(MB)+_m][_n], 0, 0, 0); \
} while (0)

#define RD8(BASE, OFF) (*(const bf16x8*)((BASE) + (OFF)))

__global__ __launch_bounds__(512, 2) void gemm256_in(
    const ushort* __restrict__ X, const ushort* __restrict__ W,
    ushort* __restrict__ zbuf, ushort* __restrict__ xbc, float* __restrict__ dtraw) {
    __shared__ ushort AL[2][16384];   // [buf][2 panels x 8192 elems]
    __shared__ ushort BL[2][16384];
    const int NBN = 41;
    int q = gridDim.x >> 3;                 // 82
    int wg = blockIdx.x;
    int swz = (wg & 7) * q + (wg >> 3);
    int per = NBN * 4;                      // 164
    int sg = swz / per, rr = swz % per;
    int bm = sg * 4 + (rr & 3);
    int bn = rr >> 2;
    int tid = threadIdx.x;
    int lane = tid & 63, w = tid >> 6;
    int wr = w >> 2, wc = w & 3;
    int lr = lane & 15, g = lane >> 4;
    int y00 = ((lr >> 1) << 7) | ((lr & 1) << 6) | (g << 4);
    int z00 = y00 ^ (((y00 >> 7) & 7) << 4);
    int aBase = wr * 8192 + z00;
    int bBase = wc * 4096 + z00;
    int z0 = tid * 16, z1 = z0 + 8192;
    int y0 = z0 ^ (((z0 >> 7) & 7) << 4);
    int y1 = z1 ^ (((z1 >> 7) & 7) << 4);
    int row0s = ((y0 >> 7) << 1) | ((y0 >> 6) & 1), kbe0 = (y0 & 63) >> 1;
    int row1s = ((y1 >> 7) << 1) | ((y1 >> 6) & 1), kbe1 = (y1 & 63) >> 1;
    const ushort* gA0 = &X[(size_t)(bm * 256 + row0s) * 2048 + kbe0];
    const ushort* gA1 = &X[(size_t)(bm * 256 + row1s) * 2048 + kbe1];
    const ushort* gB0 = &W[(size_t)(bn * 256 + row0s) * 2048 + kbe0];
    const ushort* gB1 = &W[(size_t)(bn * 256 + row1s) * 2048 + kbe1];
    int wOff = w * 1024;

#define STAGE(DB, ARR, KP, P0, P1, KO) do { \
    gload_lds16((P0) + (KO) + (KP) * 32, (char*)(ARR) + (DB) * 32768 + (KP) * 16384 + wOff); \
    gload_lds16((P1) + (KO) + (KP) * 32, (char*)(ARR) + (DB) * 32768 + (KP) * 16384 + wOff + 8192); \
} while (0)

    f32x4 acc[8][4] = {};
    bf16x8 bLo[4], bHi[4], aE[4], aO[4];
    // prologue: stage tile 0's four panels (order fixes vmcnt ages)
    STAGE(0, AL, 0, gA0, gA1, 0);
    STAGE(0, BL, 0, gB0, gB1, 0);
    STAGE(0, AL, 1, gA0, gA1, 0);
    STAGE(0, BL, 1, gB0, gB1, 0);
    asm volatile("s_waitcnt vmcnt(4)" ::: "memory");   // Akh0(0),Bkh0(0) done
    __builtin_amdgcn_s_barrier();
    __builtin_amdgcn_sched_barrier(0);
    {   // pre-read tile 0 phase A fragments (buf 0, kh0)
        const char* Ab = (const char*)AL;
        const char* Bb = (const char*)BL;
        #pragma unroll
        for (int i = 0; i < 4; i++) {
            bLo[i] = RD8(Bb, bBase + i * 1024);
            aE[i]  = RD8(Ab, aBase + i * 1024);
        }
    }

    for (int t = 0; t < 32; ++t) {
        int buf = t & 1, nb = buf ^ 1;
        int ko = ((t + 1) & 31) * 64;       // tail: dummy re-stage of tile 0
        const char* Ab  = (const char*)AL + buf * 32768;
        const char* Bb  = (const char*)BL + buf * 32768;
        const char* AbN = (const char*)AL + nb * 32768;
        const char* BbN = (const char*)BL + nb * 32768;
        // ---- phase A: MFMA(kh0,mh0); read kh0-mh1; stage Akh0(t+1) ----
        #pragma unroll
        for (int i = 0; i < 4; i++) aO[i] = RD8(Ab, aBase + 4096 + i * 1024);
        STAGE(nb, AL, 0, gA0, gA1, ko);
        __builtin_amdgcn_s_setprio(1);
        MMX(0, aE, bLo);
        __builtin_amdgcn_s_setprio(0);
        __builtin_amdgcn_sched_barrier(0);
        // ---- phase B: vis(Akh1,Bkh1); MFMA(kh0,mh1); read kh1; stage Bkh0(t+1) ----
        asm volatile("s_waitcnt vmcnt(2)" ::: "memory");
        __builtin_amdgcn_s_barrier();
        __builtin_amdgcn_sched_barrier(0);
        #pragma unroll
        for (int i = 0; i < 4; i++) {
            bHi[i] = RD8(Bb, bBase + 16384 + i * 1024);
            aE[i]  = RD8(Ab, aBase + 16384 + i * 1024);
        }
        STAGE(nb, BL, 0, gB0, gB1, ko);
        __builtin_amdgcn_s_setprio(1);
        MMX(4, aO, bLo);
        __builtin_amdgcn_s_setprio(0);
        __builtin_amdgcn_sched_barrier(0);
        // ---- phase C: MFMA(kh1,mh0); read kh1-mh1; stage Akh1(t+1) ----
        #pragma unroll
        for (int i = 0; i < 4; i++) aO[i] = RD8(Ab, aBase + 16384 + 4096 + i * 1024);
        STAGE(nb, AL, 1, gA0, gA1, ko);
        __builtin_amdgcn_s_setprio(1);
        MMX(0, aE, bHi);
        __builtin_amdgcn_s_setprio(0);
        __builtin_amdgcn_sched_barrier(0);
        // ---- phase D: vis(Akh0,Bkh0 of t+1); MFMA(kh1,mh1); read next-tile kh0; stage Bkh1(t+1) ----
        asm volatile("s_waitcnt vmcnt(2)" ::: "memory");
        __builtin_amdgcn_s_barrier();
        __builtin_amdgcn_sched_barrier(0);
        #pragma unroll
        for (int i = 0; i < 4; i++) {
            bLo[i] = RD8(BbN, bBase + i * 1024);
            aE[i]  = RD8(AbN, aBase + i * 1024);
        }
        STAGE(nb, BL, 1, gB0, gB1, ko);
        __builtin_amdgcn_s_setprio(1);
        MMX(4, aO, bHi);
        __builtin_amdgcn_s_setprio(0);
        __builtin_amdgcn_sched_barrier(0);
    }
    asm volatile("s_waitcnt vmcnt(0)" ::: "memory");

    // ---- scatter epilogue ----
    int rq = g * 4;
    #pragma unroll
    for (int mf = 0; mf < 8; mf++) {
        int row0 = bm * 256 + wr * 128 + mf * 16 + rq;
        #pragma unroll
        for (int n = 0; n < 4; n++) {
            int cb0 = bn * 256 + wc * 64 + n * 16;
            int col = cb0 + lr;
            if (cb0 < 4096) {
                #pragma unroll
                for (int r = 0; r < 4; r++)
                    zbuf[(size_t)(row0 + r) * DINNER + col] = f2bf(acc[mf][n][r]);
            } else if (cb0 < 10240) {
                #pragma unroll
                for (int r = 0; r < 4; r++)
                    xbc[(size_t)(row0 + r) * CONVDIM + (col - 4096)] = f2bf(acc[mf][n][r]);
            } else if (cb0 < 10304) {
                #pragma unroll
                for (int r = 0; r < 4; r++)
                    dtraw[(size_t)(row0 + r) * 64 + (col - 10240)] = acc[mf][n][r];
            }
        }
    }
}
#undef STAGE

// ============================================================
// out_proj: 256x128-tile pipelined GEMM, BK=64, 2 phases/tile.
// (unchanged from round 10 — verified)
// ============================================================
#define MM16(MB) do { \
  acc[(MB)+0][0]=MFMA_OP(a0,b0,acc[(MB)+0][0],0,0,0); acc[(MB)+0][1]=MFMA_OP(a0,b1,acc[(MB)+0][1],0,0,0); \
  acc[(MB)+0][2]=MFMA_OP(a0,b2,acc[(MB)+0][2],0,0,0); acc[(MB)+0][3]=MFMA_OP(a0,b3,acc[(MB)+0][3],0,0,0); \
  acc[(MB)+1][0]=MFMA_OP(a1,b0,acc[(MB)+1][0],0,0,0); acc[(MB)+1][1]=MFMA_OP(a1,b1,acc[(MB)+1][1],0,0,0); \
  acc[(MB)+1][2]=MFMA_OP(a1,b2,acc[(MB)+1][2],0,0,0); acc[(MB)+1][3]=MFMA_OP(a1,b3,acc[(MB)+1][3],0,0,0); \
  acc[(MB)+2][0]=MFMA_OP(a2,b0,acc[(MB)+2][0],0,0,0); acc[(MB)+2][1]=MFMA_OP(a2,b1,acc[(MB)+2][1],0,0,0); \
  acc[(MB)+2][2]=MFMA_OP(a2,b2,acc[(MB)+2][2],0,0,0); acc[(MB)+2][3]=MFMA_OP(a2,b3,acc[(MB)+2][3],0,0,0); \
  acc[(MB)+3][0]=MFMA_OP(a3,b0,acc[(MB)+3][0],0,0,0); acc[(MB)+3][1]=MFMA_OP(a3,b1,acc[(MB)+3][1],0,0,0); \
  acc[(MB)+3][2]=MFMA_OP(a3,b2,acc[(MB)+3][2],0,0,0); acc[(MB)+3][3]=MFMA_OP(a3,b3,acc[(MB)+3][3],0,0,0); \
} while (0)

__global__ __launch_bounds__(512, 2) void gemm256_out(
    const ushort* __restrict__ X, const ushort* __restrict__ W,
    float* __restrict__ outF) {
    __shared__ ushort AL[2][16384];   // 2 bufs x 32768 B (2 kh panels x 16 KB)
    __shared__ ushort BL[2][8192];    // 2 bufs x 16384 B (2 kh panels x 8 KB)
    int q = gridDim.x >> 3;                 // 32
    int wg = blockIdx.x;
    int swz = (wg & 7) * q + (wg >> 3);
    int per = 16 * 4;
    int sg = swz / per, rr = swz % per;
    int bm = sg * 4 + (rr & 3);
    int bn = rr >> 2;
    int tid = threadIdx.x;
    int lane = tid & 63, w = tid >> 6;
    int wr = w >> 1, wc = w & 1;
    int lr = lane & 15, g = lane >> 4;
    int y00 = ((lr >> 1) << 7) | ((lr & 1) << 6) | (g << 4);
    int z00 = y00 ^ (((y00 >> 7) & 7) << 4);
    int aBase = wr * 4096 + z00;
    int bBase = wc * 4096 + z00;
    int z0 = tid * 16, z1 = z0 + 8192;
    int y0 = z0 ^ (((z0 >> 7) & 7) << 4);
    int y1 = z1 ^ (((z1 >> 7) & 7) << 4);
    int rowA0 = ((y0 >> 7) << 1) | ((y0 >> 6) & 1), kA0 = (y0 & 63) >> 1;
    int rowA1 = ((y1 >> 7) << 1) | ((y1 >> 6) & 1), kA1 = (y1 & 63) >> 1;
    const ushort* gA0 = &X[(size_t)(bm * 256 + rowA0) * 4096 + kA0];
    const ushort* gA1 = &X[(size_t)(bm * 256 + rowA1) * 4096 + kA1];
    const ushort* gB  = &W[(size_t)(bn * 128 + rowA0) * 4096 + kA0];
    int wOff = w * 1024;

#define STAGEA(DB, KP, KO) do { \
    gload_lds16(gA0 + (KO) + (KP) * 32, (char*)AL + (DB) * 32768 + (KP) * 16384 + wOff); \
    gload_lds16(gA1 + (KO) + (KP) * 32, (char*)AL + (DB) * 32768 + (KP) * 16384 + wOff + 8192); \
} while (0)
#define STAGEB(DB, KP, KO) \
    gload_lds16(gB + (KO) + (KP) * 32, (char*)BL + (DB) * 16384 + (KP) * 8192 + wOff)

    f32x4 acc[4][4] = {};
    STAGEA(0, 0, 0); STAGEB(0, 0, 0);
    STAGEA(0, 1, 0); STAGEB(0, 1, 0);

    for (int t = 0; t < 64; ++t) {
        int buf = t & 1, nb = buf ^ 1;
        int ko = ((t + 1) & 63) * 64;
        const char* Ab = (const char*)AL + buf * 32768;
        const char* Bb = (const char*)BL + buf * 16384;
        bf16x8 a0, a1, a2, a3, b0, b1, b2, b3;
        // ---- phase kh0 ----
        asm volatile("s_waitcnt vmcnt(3)" ::: "memory");
        __builtin_amdgcn_s_barrier();
        __builtin_amdgcn_sched_barrier(0);
        b0 = RD8(Bb, bBase);        b1 = RD8(Bb, bBase + 1024);
        b2 = RD8(Bb, bBase + 2048); b3 = RD8(Bb, bBase + 3072);
        a0 = RD8(Ab, aBase);        a1 = RD8(Ab, aBase + 1024);
        a2 = RD8(Ab, aBase + 2048); a3 = RD8(Ab, aBase + 3072);
        STAGEA(nb, 0, ko); STAGEB(nb, 0, ko);
        __builtin_amdgcn_s_setprio(1);
        MM16(0);
        __builtin_amdgcn_s_setprio(0);
        __builtin_amdgcn_sched_barrier(0);
        // ---- phase kh1 ----
        asm volatile("s_waitcnt vmcnt(3)" ::: "memory");
        __builtin_amdgcn_s_barrier();
        __builtin_amdgcn_sched_barrier(0);
        b0 = RD8(Bb, bBase + 8192);        b1 = RD8(Bb, bBase + 8192 + 1024);
        b2 = RD8(Bb, bBase + 8192 + 2048); b3 = RD8(Bb, bBase + 8192 + 3072);
        a0 = RD8(Ab, aBase + 16384);        a1 = RD8(Ab, aBase + 16384 + 1024);
        a2 = RD8(Ab, aBase + 16384 + 2048); a3 = RD8(Ab, aBase + 16384 + 3072);
        STAGEA(nb, 1, ko); STAGEB(nb, 1, ko);
        __builtin_amdgcn_s_setprio(1);
        MM16(0);
        __builtin_amdgcn_s_setprio(0);
        __builtin_amdgcn_sched_barrier(0);
    }
    asm volatile("s_waitcnt vmcnt(0)" ::: "memory");

    int rq = g * 4;
    #pragma unroll
    for (int mf = 0; mf < 4; mf++) {
        int row0 = bm * 256 + wr * 64 + mf * 16 + rq;
        #pragma unroll
        for (int nf = 0; nf < 4; nf++) {
            int col = bn * 128 + wc * 64 + nf * 16 + lr;
            #pragma unroll
            for (int r = 0; r < 4; r++)
                outF[(size_t)(row0 + r) * DMODEL + col] = acc[mf][nf][r];
        }
    }
}
#undef STAGEA
#undef STAGEB

// ============================================================
// causal depthwise conv1d (K=4) + SiLU: 4 rows x 8 ch per thread
// ============================================================
__global__ void conv_kernel(const ushort* __restrict__ xbc, const float* __restrict__ cw,
                            const float* __restrict__ cb, ushort* __restrict__ convout) {
    int c8 = (blockIdx.x * 256 + threadIdx.x) * 8;
    int row0 = blockIdx.y * 4;
    int t0 = row0 & 2047;
    float bias[8];
    {
        float4 b0 = ((const float4*)cb)[c8 / 4];
        float4 b1 = ((const float4*)cb)[c8 / 4 + 1];
        bias[0] = b0.x; bias[1] = b0.y; bias[2] = b0.z; bias[3] = b0.w;
        bias[4] = b1.x; bias[5] = b1.y; bias[6] = b1.z; bias[7] = b1.w;
    }
    float wk[8][4];
    #pragma unroll
    for (int e = 0; e < 8; e++) {
        float4 wv = ((const float4*)cw)[c8 + e];
        wk[e][0] = wv.x; wk[e][1] = wv.y; wk[e][2] = wv.z; wk[e][3] = wv.w;
    }
    float f[7][8];
    #pragma unroll
    for (int j = 0; j < 7; j++) {
        int tt = t0 - 3 + j;
        if (tt >= 0) {
            uint4 v = *(const uint4*)&xbc[(size_t)(row0 - 3 + j) * CONVDIM + c8];
            unpack8(v, f[j]);
        } else {
            #pragma unroll
            for (int e = 0; e < 8; e++) f[j][e] = 0.f;
        }
    }
    #pragma unroll
    for (int r = 0; r < 4; r++) {
        float a[8];
        #pragma unroll
        for (int e = 0; e < 8; e++) {
            a[e] = bias[e];
            #pragma unroll
            for (int k = 0; k < 4; k++) a[e] += f[r + k][e] * wk[e][k];
        }
        uint4 o;
        float s[8];
        #pragma unroll
        for (int e = 0; e < 8; e++) s[e] = a[e] / (1.f + __expf(-a[e]));
        o.x = pk2(s[0], s[1]); o.y = pk2(s[2], s[3]);
        o.z = pk2(s[4], s[5]); o.w = pk2(s[6], s[7]);
        *(uint4*)&convout[(size_t)(row0 + r) * CONVDIM + c8] = o;
    }
}

// ============================================================
// fused: softplus(dtraw+bias) (in place) + per-chunk cumsum of dt*A
// ============================================================
__global__ void cumsum_kernel(float* __restrict__ dtbuf, const float* __restrict__ dt_bias,
                              const float* __restrict__ A_log, float* __restrict__ dAcs) {
    int bi = blockIdx.x;
    int h = bi & 63, cg = bi >> 6;
    int t = threadIdx.x;
    size_t didx = (size_t)(cg * 256 + t) * 64 + h;
    float x = dtbuf[didx] + dt_bias[h];
    float sp = (x > 20.f) ? x : log1pf(__expf(x));
    dtbuf[didx] = sp;
    float A = -expf(A_log[h]);
    float v = sp * A;
    __shared__ float s[256];
    s[t] = v;
    __syncthreads();
    for (int off = 1; off < 256; off <<= 1) {
        float add = (t >= off) ? s[t - off] : 0.f;
        __syncthreads();
        s[t] += add;
        __syncthreads();
    }
    dAcs[(size_t)bi * 256 + t] = s[t];
}

// ============================================================
// MFMA states: per (cg,h), states[p][n] = sum_s xdt'[s,p] * B[s,n]
// ============================================================
__global__ __launch_bounds__(256) void states_mfma(
    const ushort* __restrict__ convout, const float* __restrict__ dtsp,
    const float* __restrict__ dAcs, float* __restrict__ states) {
    __shared__ ushort BT[128 * 72];
    __shared__ ushort XT[64 * 72];
    int bi = blockIdx.x;
    int h = bi & 63, cg = bi >> 6;
    int tid = threadIdx.x;
    int rowbase = cg * 256;
    int bcol = 1024 + ((h >> 3) << 7);
    int xcol = ((h >> 3) << 7) + ((h & 1) << 6);
    float dAlast = dAcs[(size_t)bi * 256 + 255];
    int w = tid >> 6, lane = tid & 63, g = lane >> 4, cc = lane & 15;
    f32x4 acc[4][2] = {};
    for (int T = 0; T < 4; T++) {
        __syncthreads();
        int s = lane;
        int srow = rowbase + T * 64 + s;
        #pragma unroll
        for (int i = 0; i < 4; i++) {
            int n0 = (w + i * 4) * 8;
            uint4 v = *(const uint4*)&convout[(size_t)srow * CONVDIM + bcol + n0];
            ushort us[8];
            us[0] = (ushort)v.x; us[1] = (ushort)(v.x >> 16);
            us[2] = (ushort)v.y; us[3] = (ushort)(v.y >> 16);
            us[4] = (ushort)v.z; us[5] = (ushort)(v.z >> 16);
            us[6] = (ushort)v.w; us[7] = (ushort)(v.w >> 16);
            #pragma unroll
            for (int e = 0; e < 8; e++) BT[(n0 + e) * 72 + s] = us[e];
        }
        float wgt = dtsp[(size_t)srow * 64 + h] * __expf(dAlast - dAcs[(size_t)bi * 256 + T * 64 + s]);
        #pragma unroll
        for (int j = 0; j < 2; j++) {
            int p0 = (w * 2 + j) * 8;
            uint4 v = *(const uint4*)&convout[(size_t)srow * CONVDIM + xcol + p0];
            float f[8]; unpack8(v, f);
            #pragma unroll
            for (int e = 0; e < 8; e++) XT[(p0 + e) * 72 + s] = f2bf(f[e] * wgt);
        }
        __syncthreads();
        bf16x8 af[4][2], bw[2][2];
        #pragma unroll
        for (int m = 0; m < 4; m++)
            #pragma unroll
            for (int kb = 0; kb < 2; kb++)
                af[m][kb] = *(const bf16x8*)&XT[(m * 16 + cc) * 72 + kb * 32 + 8 * g];
        #pragma unroll
        for (int np = 0; np < 2; np++)
            #pragma unroll
            for (int kb = 0; kb < 2; kb++)
                bw[np][kb] = *(const bf16x8*)&BT[(w * 32 + np * 16 + cc) * 72 + kb * 32 + 8 * g];
        #pragma unroll
        for (int m = 0; m < 4; m++)
            #pragma unroll
            for (int np = 0; np < 2; np++) {
                acc[m][np] = MFMA_OP(af[m][0], bw[np][0], acc[m][np], 0, 0, 0);
                acc[m][np] = MFMA_OP(af[m][1], bw[np][1], acc[m][np], 0, 0, 0);
            }
    }
    size_t base = (size_t)bi * 8192;
    #pragma unroll
    for (int m = 0; m < 4; m++)
        #pragma unroll
        for (int np = 0; np < 2; np++)
            #pragma unroll
            for (int r = 0; r < 4; r++) {
                int p = m * 16 + 4 * g + r;
                int n = w * 32 + np * 16 + cc;
                states[base + (size_t)p * 128 + n] = acc[m][np][r];
            }
}

// ============================================================
// inter-chunk recurrence: 8 chunks PER BATCH, carry resets per batch
// ============================================================
__global__ void recur_kernel(const float* __restrict__ dAcs, float* __restrict__ states) {
    int blk = blockIdx.x;
    int pq = blk & 7, bh = blk >> 3;
    int h = bh & 63, b = bh >> 6;
    int tid = threadIdx.x;
    int p = pq * 8 + (tid >> 5);
    int n0 = (tid & 31) * 4;
    float4 carry = make_float4(0.f, 0.f, 0.f, 0.f);
    for (int c = 0; c < 8; c++) {
        int bi = (b * 8 + c) * 64 + h;
        float decay = __expf(dAcs[(size_t)bi * 256 + 255]);
        size_t idx = (size_t)bi * 8192 + (size_t)p * 128 + n0;
        float4 tmp = *(const float4*)&states[idx];
        *(float4*)&states[idx] = carry;
        carry.x = carry.x * decay + tmp.x;
        carry.y = carry.y * decay + tmp.y;
        carry.z = carry.z * decay + tmp.z;
        carry.w = carry.w * decay + tmp.w;
    }
}

// ============================================================
// MFMA yscan: per (cg,h) block, Y = Y_diag + Y_off (D*x added in norm).
// ============================================================
__global__ __launch_bounds__(256, 2) void yscan_mfma(
    const ushort* __restrict__ convout, const float* __restrict__ dtsp,
    const float* __restrict__ dAcs, const float* __restrict__ states,
    ushort* __restrict__ y) {
    __shared__ ushort XT[64 * 264];
    __shared__ ushort PR[64 * 136];
    __shared__ ushort PV[4 * 16 * 72];
    __shared__ float sdA[256];
    int bi = blockIdx.x;
    int h = bi & 63, cg = bi >> 6;
    int tid = threadIdx.x;
    int rowbase = cg * 256;
    int bcol = 1024 + ((h >> 3) << 7);
    int ccol = 2048 + ((h >> 1) << 7);
    int xcol = ((h >> 3) << 7) + ((h & 1) << 6);

    sdA[tid] = dAcs[(size_t)bi * 256 + tid];
    #pragma unroll
    for (int i = 0; i < 4; i++) {
        int s = i * 64 + (tid & 63);
        float dtv = dtsp[(size_t)(rowbase + s) * 64 + h];
        #pragma unroll
        for (int j = 0; j < 2; j++) {
            int p0 = (((tid >> 6) << 1) + j) << 3;
            uint4 v = *(const uint4*)&convout[(size_t)(rowbase + s) * CONVDIM + xcol + p0];
            float f[8]; unpack8(v, f);
            #pragma unroll
            for (int e = 0; e < 8; e++) XT[(p0 + e) * 264 + s] = f2bf(f[e] * dtv);
        }
    }
    {
        const float* pv = &states[(size_t)bi * 8192];
        #pragma unroll
        for (int i = 0; i < 8; i++) {
            int flat = i * 1024 + tid * 4;
            float4 v = *(const float4*)&pv[flat];
            int p = flat >> 7, n = flat & 127;
            *(uint*)&PR[p * 136 + n]     = pk2(v.x, v.y);
            *(uint*)&PR[p * 136 + n + 2] = pk2(v.z, v.w);
        }
    }
    __syncthreads();

    int w = tid >> 6, lane = tid & 63, g = lane >> 4, c = lane & 15;
    int wbase = w * 64;
    const ushort* Crow0 = &convout[(size_t)(rowbase + wbase + c) * CONVDIM + ccol + 8 * g];

    // ---- Y_off = C . prev^T ----
    f32x4 yac[4][4] = {};
    #pragma unroll
    for (int kb = 0; kb < 4; kb++) {
        bf16x8 pb[4];
        #pragma unroll
        for (int np = 0; np < 4; np++)
            pb[np] = *(const bf16x8*)&PR[(16 * np + c) * 136 + kb * 32 + 8 * g];
        #pragma unroll
        for (int m = 0; m < 4; m++) {
            bf16x8 cf = *(const bf16x8*)&Crow0[(size_t)(m * 16) * CONVDIM + kb * 32];
            #pragma unroll
            for (int np = 0; np < 4; np++)
                yac[m][np] = MFMA_OP(cf, pb[np], yac[m][np], 0, 0, 0);
        }
    }
    float al[4][4];
    float Sw = sdA[wbase];
    float eSw = __expf(Sw);
    #pragma unroll
    for (int m = 0; m < 4; m++)
        #pragma unroll
        for (int r = 0; r < 4; r++) {
            float dAl = sdA[wbase + m * 16 + 4 * g + r];
            al[m][r] = __expf(dAl - Sw);
            float el = al[m][r] * eSw;
            #pragma unroll
            for (int np = 0; np < 4; np++) yac[m][np][r] *= el;
        }

    // ---- s-tiles ----
    ushort* pvs = &PV[w * 1152];
    for (int T = 0; T <= w; T++) {
        f32x4 sac[4][4] = {};
        #pragma unroll
        for (int kb = 0; kb < 4; kb++) {
            bf16x8 bb[4];
            #pragma unroll
            for (int np = 0; np < 4; np++)
                bb[np] = *(const bf16x8*)&convout[(size_t)(rowbase + T * 64 + 16 * np + c) * CONVDIM + bcol + kb * 32 + 8 * g];
            #pragma unroll
            for (int m = 0; m < 4; m++) {
                bf16x8 cf = *(const bf16x8*)&Crow0[(size_t)(m * 16) * CONVDIM + kb * 32];
                #pragma unroll
                for (int np = 0; np < 4; np++)
                    sac[m][np] = MFMA_OP(cf, bb[np], sac[m][np], 0, 0, 0);
            }
        }
        bf16x8 xb[4][2];
        #pragma unroll
        for (int np = 0; np < 4; np++)
            #pragma unroll
            for (int k2 = 0; k2 < 2; k2++)
                xb[np][k2] = *(const bf16x8*)&XT[(16 * np + c) * 264 + T * 64 + k2 * 32 + 8 * g];
        if (T < w) {
            float ET = sdA[T * 64 + 63];
            float cT = __expf(Sw - ET);
            float bc[4];
            #pragma unroll
            for (int np = 0; np < 4; np++)
                bc[np] = __expf(ET - sdA[T * 64 + 16 * np + c]) * cT;
            #pragma unroll
            for (int m = 0; m < 4; m++) {
                #pragma unroll
                for (int np = 0; np < 4; np++) {
                    float s0 = bc[np];
                    #pragma unroll
                    for (int r = 0; r < 4; r++)
                        pvs[(4 * g + r) * 72 + 16 * np + c] = f2bf(sac[m][np][r] * (al[m][r] * s0));
                }
                bf16x8 pa0 = *(const bf16x8*)&pvs[c * 72 + 8 * g];
                bf16x8 pa1 = *(const bf16x8*)&pvs[c * 72 + 32 + 8 * g];
                #pragma unroll
                for (int np = 0; np < 4; np++) {
                    yac[m][np] = MFMA_OP(pa0, xb[np][0], yac[m][np], 0, 0, 0);
                    yac[m][np] = MFMA_OP(pa1, xb[np][1], yac[m][np], 0, 0, 0);
                }
            }
        } else {
            #pragma unroll
            for (int m = 0; m < 4; m++) {
                float dal[4];
                #pragma unroll
                for (int r = 0; r < 4; r++) dal[r] = sdA[wbase + m * 16 + 4 * g + r];
                #pragma unroll
                for (int np = 0; np < 4; np++) {
                    int s_loc = w * 64 + 16 * np + c;
                    float dAs = sdA[s_loc];
                    #pragma unroll
                    for (int r = 0; r < 4; r++) {
                        int l_loc = wbase + m * 16 + 4 * g + r;
                        float v = (s_loc <= l_loc) ? sac[m][np][r] * __expf(dal[r] - dAs) : 0.f;
                        pvs[(4 * g + r) * 72 + 16 * np + c] = f2bf(v);
                    }
                }
                bf16x8 pa0 = *(const bf16x8*)&pvs[c * 72 + 8 * g];
                bf16x8 pa1 = *(const bf16x8*)&pvs[c * 72 + 32 + 8 * g];
                #pragma unroll
                for (int np = 0; np < 4; np++) {
                    yac[m][np] = MFMA_OP(pa0, xb[np][0], yac[m][np], 0, 0, 0);
                    yac[m][np] = MFMA_OP(pa1, xb[np][1], yac[m][np], 0, 0, 0);
                }
            }
        }
    }
    #pragma unroll
    for (int m = 0; m < 4; m++)
        #pragma unroll
        for (int np = 0; np < 4; np++)
            #pragma unroll
            for (int r = 0; r < 4; r++) {
                int l = wbase + m * 16 + 4 * g + r;
                y[(size_t)(rowbase + l) * DINNER + h * 64 + 16 * np + c] = f2bf(yac[m][np][r]);
            }
}

// ============================================================
// gated grouped RMSNorm (in place over y), adds D*x first.
// ============================================================
__global__ void norm_kernel(ushort* __restrict__ y, const ushort* __restrict__ zbuf,
                            const ushort* __restrict__ convout, const float* __restrict__ Dvec,
                            const float* __restrict__ nw) {
    int row = blockIdx.x;
    int g = blockIdx.y * 4 + (threadIdx.x >> 6);
    int lane = threadIdx.x & 63;
    int cbase = g * 128 + lane * 2;
    int h = cbase >> 6;
    int p = cbase & 63;
    int xc = ((h >> 3) << 7) + ((h & 1) << 6) + p;
    uint yv = *(const uint*)&y[(size_t)row * DINNER + cbase];
    uint zv = *(const uint*)&zbuf[(size_t)row * DINNER + cbase];
    uint xv = *(const uint*)&convout[(size_t)row * CONVDIM + xc];
    float Dh = Dvec[h];
    float y0 = bflo(yv) + Dh * bflo(xv), y1 = bfhi(yv) + Dh * bfhi(xv);
    float z0 = bflo(zv), z1 = bfhi(zv);
    float v0 = y0 * (z0 / (1.f + __expf(-z0)));
    float v1 = y1 * (z1 / (1.f + __expf(-z1)));
    float ss = v0 * v0 + v1 * v1;
    #pragma unroll
    for (int off = 32; off; off >>= 1) ss += __shfl_xor(ss, off, 64);
    float rstd = rsqrtf(ss * (1.f / 128.f) + 1e-5f);
    v0 *= rstd * nw[cbase];
    v1 *= rstd * nw[cbase + 1];
    *(uint*)&y[(size_t)row * DINNER + cbase] = pk2(v0, v1);
}

// ============================================================
extern "C" void kernel_launch(void* const* d_in, const int* in_sizes, int n_in,
                              void* d_out, int out_size, void* d_ws, size_t ws_size,
                              hipStream_t stream) {
    const float* u       = (const float*)d_in[0];
    const float* W_in    = (const float*)d_in[1];
    const float* conv_w  = (const float*)d_in[2];
    const float* conv_b  = (const float*)d_in[3];
    const float* dt_bias = (const float*)d_in[4];
    const float* A_log   = (const float*)d_in[5];
    const float* Dvec    = (const float*)d_in[6];
    const float* nw      = (const float*)d_in[7];
    const float* W_out   = (const float*)d_in[8];

    // ---- workspace layout (aliased bf16 staging) ----
    char* ws = (char*)d_ws;
    size_t off = 0;
    auto alloc = [&](size_t bytes) { void* p = ws + off; off += (bytes + 255) & ~(size_t)255; return p; };
    ushort* zbuf    = (ushort*)alloc((size_t)LTOT * DINNER * 2);          // 32 MiB
    void*   shreg   = alloc((size_t)LTOT * CONVDIM * 2);                  // 48 MiB
    ushort* xbc     = (ushort*)shreg;
    float*  states  = (float*)shreg;
    ushort* Wout_bf = (ushort*)shreg;
    float*  dtbuf   = (float*) alloc((size_t)LTOT * 64 * 4);              // 1 MiB
    void*   convreg = alloc((size_t)LTOT * CONVDIM * 2);                  // 48 MiB
    ushort* Win_bf  = (ushort*)convreg;
    ushort* convout = (ushort*)convreg;
    float*  dAcs    = (float*) alloc((size_t)1024 * 256 * 4);             // 1 MiB
    void*   ybreg   = alloc((size_t)LTOT * DINNER * 2);                   // 32 MiB
    ushort* u_bf    = (ushort*)ybreg;
    ushort* ybuf    = (ushort*)ybreg;

    // bf16 conversions (aliased into dead regions)
    cvt_kernel<<<dim3(8192),  dim3(256), 0, stream>>>(u, u_bf, 2097152);
    cvt_kernel<<<dim3(20608), dim3(256), 0, stream>>>(W_in, Win_bf, 5275648);
    // in_proj: 256^2 pre-read pipelined kernel; grid 16 bm x 41 bn = 656
    gemm256_in<<<dim3(656), dim3(512), 0, stream>>>(u_bf, Win_bf, zbuf, xbc, dtbuf);
    // conv + silu
    conv_kernel<<<dim3(3, 1024), dim3(256), 0, stream>>>(xbc, conv_w, conv_b, convout);
    // fused softplus + cumsum
    cumsum_kernel<<<dim3(1024), dim3(256), 0, stream>>>(dtbuf, dt_bias, A_log, dAcs);
    // chunked scan
    states_mfma<<<dim3(1024), dim3(256), 0, stream>>>(convout, dtbuf, dAcs, states);
    recur_kernel<<<dim3(1024), dim3(256), 0, stream>>>(dAcs, states);
    yscan_mfma<<<dim3(1024), dim3(256), 0, stream>>>(convout, dtbuf, dAcs, states, ybuf);
    // W_out -> bf16
    cvt_kernel<<<dim3(8192), dim3(256), 0, stream>>>(W_out, Wout_bf, 2097152);
    // gated group RMSNorm
    norm_kernel<<<dim3(4096, 8), dim3(256), 0, stream>>>(ybuf, zbuf, convout, Dvec, nw);
    // out_proj: 256x128 pipelined kernel; grid 256 (1/CU exact)
    gemm256_out<<<dim3(256), dim3(512), 0, stream>>>(ybuf, Wout_bf, (float*)d_out);
}